// Round 2
// baseline (2513.656 us; speedup 1.0000x reference)
//
#include <hip/hip_runtime.h>

// ---------------- types ----------------
typedef float f4 __attribute__((ext_vector_type(4)));
typedef float f32x4 __attribute__((ext_vector_type(4)));
typedef short short8 __attribute__((ext_vector_type(8)));
typedef unsigned short u16x4 __attribute__((ext_vector_type(4)));
typedef unsigned int u32x4 __attribute__((ext_vector_type(4)));

// ---------------- problem constants ----------------
#define S_LEN 1024
#define BATCH 16
#define DIM   512
#define NH    8
#define HDIM  64
#define NE    16
#define DFF   2048
#define T_TOK 16384   // S*B
#define CAP   34816   // 32768 assignments + per-expert padding to BM
#define BM    128

__device__ __forceinline__ unsigned short f2bf(float f) {
  union { float f; unsigned u; } v; v.f = f;
  unsigned r = v.u + 0x7fffu + ((v.u >> 16) & 1u);  // RTNE
  return (unsigned short)(r >> 16);
}

__device__ __forceinline__ void load_lds16(const void* g, void* l) {
  __builtin_amdgcn_global_load_lds(
      (__attribute__((address_space(1))) void*)(void*)g,
      (__attribute__((address_space(3))) void*)l, 16, 0, 0);
}

// ---------------- small utility kernels ----------------
__global__ __launch_bounds__(256) void k_cvt_bf16(const float* __restrict__ in,
                                                  unsigned short* __restrict__ outb,
                                                  size_t n) {
  size_t i = ((size_t)blockIdx.x * 256 + threadIdx.x) * 4;
  size_t stride = (size_t)gridDim.x * 1024;
  for (; i < n; i += stride) {
    f4 v = *(const f4*)&in[i];
    u16x4 o;
    o[0] = f2bf(v[0]); o[1] = f2bf(v[1]); o[2] = f2bf(v[2]); o[3] = f2bf(v[3]);
    *(u16x4*)&outb[i] = o;
  }
}

__global__ __launch_bounds__(256) void k_init(int* __restrict__ slotTok,
                                              float* __restrict__ slotW,
                                              int* __restrict__ counts) {
  int i = blockIdx.x * 256 + threadIdx.x;
  if (i < CAP) { slotTok[i] = -1; slotW[i] = 0.f; }
  if (i < NE) counts[i] = 0;
}

__global__ __launch_bounds__(256) void k_zero(u32x4* __restrict__ p, size_t n16) {
  size_t i = (size_t)blockIdx.x * 256 + threadIdx.x;
  size_t stride = (size_t)gridDim.x * 256;
  u32x4 z = {0u, 0u, 0u, 0u};
  for (; i < n16; i += stride) p[i] = z;
}

// ---------------- fp32 GEMM: C = (A [+ A2]) [M,K] * W[N,K]^T + bias ----------------
// 128x128 tile, 256 threads, 8x8 per thread, BK=16.
// epi 0: QK scatter (n<512 -> Q scaled 0.125 -> o0 [B,H,HD,S]; else K -> o1)
// epi 1: V scatter -> o0 [B,H,S,HD]
// epi 2: row-major fp32 -> o0 (N must be 512)
__global__ __launch_bounds__(256) void k_gemm_f32(
    const float* __restrict__ A, const float* __restrict__ A2,
    const float* __restrict__ W,
    const float* __restrict__ bias, int K, int epi,
    float* __restrict__ o0, float* __restrict__ o1) {
  __shared__ float Alt[16][132];
  __shared__ float Wlt[16][132];
  const int tid = threadIdx.x, tx = tid & 15, ty = tid >> 4;
  const int m0 = blockIdx.x * 128, n0 = blockIdx.y * 128;
  float acc[8][8];
#pragma unroll
  for (int i = 0; i < 8; i++) {
#pragma unroll
    for (int j = 0; j < 8; j++) acc[i][j] = 0.f;
  }
  for (int k0 = 0; k0 < K; k0 += 16) {
#pragma unroll
    for (int i = 0; i < 2; i++) {
      int c = tid + i * 256;         // [0,512)
      int r = c >> 2, jk = (c & 3) << 2;
      const size_t aoff = (size_t)(m0 + r) * K + k0 + jk;
      f4 va = *(const f4*)&A[aoff];
      if (A2) { f4 v2 = *(const f4*)&A2[aoff]; va = va + v2; }
      Alt[jk + 0][r] = va[0]; Alt[jk + 1][r] = va[1];
      Alt[jk + 2][r] = va[2]; Alt[jk + 3][r] = va[3];
      f4 vw = *(const f4*)&W[(size_t)(n0 + r) * K + k0 + jk];
      Wlt[jk + 0][r] = vw[0]; Wlt[jk + 1][r] = vw[1];
      Wlt[jk + 2][r] = vw[2]; Wlt[jk + 3][r] = vw[3];
    }
    __syncthreads();
#pragma unroll
    for (int kk = 0; kk < 16; kk++) {
      float a[8], w8[8];
      *(f4*)&a[0]  = *(const f4*)&Alt[kk][ty * 8];
      *(f4*)&a[4]  = *(const f4*)&Alt[kk][ty * 8 + 4];
      *(f4*)&w8[0] = *(const f4*)&Wlt[kk][tx * 8];
      *(f4*)&w8[4] = *(const f4*)&Wlt[kk][tx * 8 + 4];
#pragma unroll
      for (int mi = 0; mi < 8; mi++) {
#pragma unroll
        for (int ni = 0; ni < 8; ni++)
          acc[mi][ni] = fmaf(a[mi], w8[ni], acc[mi][ni]);
      }
    }
    __syncthreads();
  }
  if (epi == 2) {
#pragma unroll
    for (int mi = 0; mi < 8; mi++) {
      const size_t m = (size_t)(m0 + ty * 8 + mi);
#pragma unroll
      for (int nj = 0; nj < 2; nj++) {
        const int n = n0 + tx * 8 + nj * 4;
        f4 v;
        v[0] = acc[mi][nj * 4 + 0] + bias[n + 0];
        v[1] = acc[mi][nj * 4 + 1] + bias[n + 1];
        v[2] = acc[mi][nj * 4 + 2] + bias[n + 2];
        v[3] = acc[mi][nj * 4 + 3] + bias[n + 3];
        *(f4*)&o0[m * 512 + n] = v;
      }
    }
  } else {
#pragma unroll
    for (int mi = 0; mi < 8; mi++) {
      const int m = m0 + ty * 8 + mi;
      const int bidx = m & 15, ss = m >> 4;   // token = s*B + b
#pragma unroll
      for (int ni = 0; ni < 8; ni++) {
        const int n = n0 + tx * 8 + ni;
        float v = acc[mi][ni] + bias[n];
        if (epi == 0) {
          if (n < 512) {
            // Q, pre-scaled by 1/sqrt(HD): layout [B,H,HD,S]
            o0[((size_t)((bidx * NH + (n >> 6)) * HDIM + (n & 63))) * S_LEN + ss] = v * 0.125f;
          } else {
            const int n2 = n - 512;
            o1[((size_t)((bidx * NH + (n2 >> 6)) * HDIM + (n2 & 63))) * S_LEN + ss] = v;
          }
        } else {  // epi 1: V layout [B,H,S,HD]
          o0[((size_t)(bidx * NH + (n >> 6)) * S_LEN + ss) * HDIM + (n & 63)] = v;
        }
      }
    }
  }
}

// ---------------- fp32 flash attention ----------------
// grid (S/64, B*H); Qt/Kt: [B,H,HD,S]; Vf: [B,H,S,HD]; O: [S,B,D]
__global__ __launch_bounds__(256) void k_attn(const float* __restrict__ Qt,
                                              const float* __restrict__ Kt,
                                              const float* __restrict__ Vf,
                                              float* __restrict__ O) {
  const int q0 = blockIdx.x * 64;
  const int bh = blockIdx.y;
  const int b = bh >> 3, h = bh & 7;
  const float* Qh = Qt + (size_t)bh * (HDIM * S_LEN);
  const float* Kh = Kt + (size_t)bh * (HDIM * S_LEN);
  const float* Vh = Vf + (size_t)bh * (S_LEN * HDIM);
  __shared__ float Ql[64][64];   // [hd][q]
  __shared__ float Kl[64][64];   // [hd][k]
  __shared__ float Vl[64][64];   // [k][hd]
  __shared__ float Pl[64][68];   // [k][q], padded (16B-aligned rows)
  const int tid = threadIdx.x, tx = tid & 15, ty = tid >> 4;
#pragma unroll
  for (int i = 0; i < 4; i++) {
    int c = tid + i * 256;
    int r = c >> 4, j = (c & 15) << 2;
    *(f4*)&Ql[r][j] = *(const f4*)&Qh[(size_t)r * S_LEN + q0 + j];
  }
  float m_[4], l_[4], o_[4][4];
#pragma unroll
  for (int r = 0; r < 4; r++) {
    m_[r] = -1e30f; l_[r] = 0.f;
#pragma unroll
    for (int c = 0; c < 4; c++) o_[r][c] = 0.f;
  }
  for (int kt = 0; kt < 16; kt++) {
    const int s0 = kt * 64;
    __syncthreads();
#pragma unroll
    for (int i = 0; i < 4; i++) {
      int c = tid + i * 256;
      int r = c >> 4, j = (c & 15) << 2;
      *(f4*)&Kl[r][j] = *(const f4*)&Kh[(size_t)r * S_LEN + s0 + j];
      *(f4*)&Vl[r][j] = *(const f4*)&Vh[(size_t)(s0 + r) * HDIM + j];
    }
    __syncthreads();
    float sc[4][4];
#pragma unroll
    for (int r = 0; r < 4; r++) {
#pragma unroll
      for (int c = 0; c < 4; c++) sc[r][c] = 0.f;
    }
    for (int d = 0; d < 64; d++) {
      f4 aq = *(const f4*)&Ql[d][ty * 4];
      f4 bk = *(const f4*)&Kl[d][tx * 4];
#pragma unroll
      for (int r = 0; r < 4; r++) {
#pragma unroll
        for (int c = 0; c < 4; c++) sc[r][c] = fmaf(aq[r], bk[c], sc[r][c]);
      }
    }
    float esc[4], rs[4];
#pragma unroll
    for (int r = 0; r < 4; r++) {
      float tm = fmaxf(fmaxf(sc[r][0], sc[r][1]), fmaxf(sc[r][2], sc[r][3]));
#pragma unroll
      for (int d = 1; d < 16; d <<= 1) tm = fmaxf(tm, __shfl_xor(tm, d));
      float mn = fmaxf(m_[r], tm);
      esc[r] = __expf(m_[r] - mn);
      m_[r] = mn;
      rs[r] = 0.f;
    }
#pragma unroll
    for (int r = 0; r < 4; r++) {
#pragma unroll
      for (int c = 0; c < 4; c++) {
        float p = __expf(sc[r][c] - m_[r]);
        rs[r] += p;
        Pl[tx * 4 + c][ty * 4 + r] = p;
      }
    }
#pragma unroll
    for (int r = 0; r < 4; r++) {
#pragma unroll
      for (int d = 1; d < 16; d <<= 1) rs[r] += __shfl_xor(rs[r], d);
      l_[r] = l_[r] * esc[r] + rs[r];
#pragma unroll
      for (int c = 0; c < 4; c++) o_[r][c] *= esc[r];
    }
    __syncthreads();
    for (int k = 0; k < 64; k++) {
      f4 ap = *(const f4*)&Pl[k][ty * 4];
      f4 av = *(const f4*)&Vl[k][tx * 4];
#pragma unroll
      for (int r = 0; r < 4; r++) {
#pragma unroll
        for (int c = 0; c < 4; c++) o_[r][c] = fmaf(ap[r], av[c], o_[r][c]);
      }
    }
  }
#pragma unroll
  for (int r = 0; r < 4; r++) {
    const float inv = 1.f / l_[r];
    const int srow = q0 + ty * 4 + r;
    f4 v;
    v[0] = o_[r][0] * inv; v[1] = o_[r][1] * inv;
    v[2] = o_[r][2] * inv; v[3] = o_[r][3] * inv;
    *(f4*)&O[((size_t)srow * BATCH + b) * DIM + h * HDIM + tx * 4] = v;
  }
}

// ---------------- layernorm: x = LN(src + proj)*g + b -> out ----------------
__global__ __launch_bounds__(256) void k_ln(const float* __restrict__ src,
                                            const float* __restrict__ proj,
                                            const float* __restrict__ g,
                                            const float* __restrict__ bt,
                                            float* __restrict__ xout) {
  const int wid = threadIdx.x >> 6, lane = threadIdx.x & 63;
  const int tok = blockIdx.x * 4 + wid;
  const size_t base = (size_t)tok * DIM + lane * 8;
  f4 a0 = *(const f4*)&src[base],  a1 = *(const f4*)&src[base + 4];
  f4 p0 = *(const f4*)&proj[base], p1 = *(const f4*)&proj[base + 4];
  float x[8];
  x[0] = a0[0] + p0[0]; x[1] = a0[1] + p0[1]; x[2] = a0[2] + p0[2]; x[3] = a0[3] + p0[3];
  x[4] = a1[0] + p1[0]; x[5] = a1[1] + p1[1]; x[6] = a1[2] + p1[2]; x[7] = a1[3] + p1[3];
  float s = 0.f, sq = 0.f;
#pragma unroll
  for (int j = 0; j < 8; j++) { s += x[j]; sq = fmaf(x[j], x[j], sq); }
#pragma unroll
  for (int d = 1; d < 64; d <<= 1) { s += __shfl_xor(s, d); sq += __shfl_xor(sq, d); }
  const float mean = s * (1.f / 512.f);
  const float var = sq * (1.f / 512.f) - mean * mean;
  const float rstd = 1.f / sqrtf(var + 1e-5f);
  const int ci = lane * 8;
  f4 o0v, o1v;
#pragma unroll
  for (int j = 0; j < 4; j++) o0v[j] = (x[j] - mean) * rstd * g[ci + j] + bt[ci + j];
#pragma unroll
  for (int j = 0; j < 4; j++) o1v[j] = (x[4 + j] - mean) * rstd * g[ci + 4 + j] + bt[ci + 4 + j];
  *(f4*)&xout[base] = o0v;
  *(f4*)&xout[base + 4] = o1v;
}

// ---------------- gate: logits, top-2, softmax, counts ----------------
__global__ __launch_bounds__(256) void k_gate(const float* __restrict__ x,
                                              const float* __restrict__ gw,
                                              const float* __restrict__ gb,
                                              int* __restrict__ topi,
                                              float* __restrict__ topw,
                                              int* __restrict__ counts) {
  const int wid = threadIdx.x >> 6, lane = threadIdx.x & 63;
  const int tok = blockIdx.x * 4 + wid;
  const size_t base = (size_t)tok * DIM + lane * 8;
  f4 x0 = *(const f4*)&x[base], x1 = *(const f4*)&x[base + 4];
  float best = -1e30f, sec = -1e30f;
  int bi = 0, si = 0;
  for (int e = 0; e < NE; e++) {
    const float* w = gw + (size_t)e * DIM + lane * 8;
    f4 w0 = *(const f4*)&w[0], w1 = *(const f4*)&w[4];
    float d = x0[0] * w0[0];
    d = fmaf(x0[1], w0[1], d); d = fmaf(x0[2], w0[2], d); d = fmaf(x0[3], w0[3], d);
    d = fmaf(x1[0], w1[0], d); d = fmaf(x1[1], w1[1], d);
    d = fmaf(x1[2], w1[2], d); d = fmaf(x1[3], w1[3], d);
#pragma unroll
    for (int dd = 1; dd < 64; dd <<= 1) d += __shfl_xor(d, dd);
    d += gb[e];
    if (d > best) { sec = best; si = bi; best = d; bi = e; }
    else if (d > sec) { sec = d; si = e; }
  }
  if (lane == 0) {
    const float e1 = expf(sec - best);
    const float inv = 1.f / (1.f + e1);
    topi[2 * tok] = bi;  topi[2 * tok + 1] = si;
    topw[2 * tok] = inv; topw[2 * tok + 1] = e1 * inv;
    atomicAdd(&counts[bi], 1);
    atomicAdd(&counts[si], 1);
  }
}

__global__ void k_offsets(const int* __restrict__ counts,
                          int* __restrict__ off_pad, int* __restrict__ cursor) {
  if (threadIdx.x == 0) {
    int o = 0;
    off_pad[0] = 0;
    for (int e = 0; e < NE; e++) {
      cursor[e] = 0;
      o += ((counts[e] + BM - 1) / BM) * BM;
      off_pad[e + 1] = o;
    }
  }
}

// one wave per (token, k) assignment: claim slot + gather row as bf16
__global__ __launch_bounds__(256) void k_scatter(const float* __restrict__ x,
                                                 const int* __restrict__ topi,
                                                 const float* __restrict__ topw,
                                                 const int* __restrict__ off_pad,
                                                 int* __restrict__ cursor,
                                                 int* __restrict__ slotTok,
                                                 float* __restrict__ slotW,
                                                 unsigned short* __restrict__ Xg) {
  const int wid = threadIdx.x >> 6, lane = threadIdx.x & 63;
  const int a = blockIdx.x * 4 + wid;   // [0, 32768)
  const int t = a >> 1;
  const int e = topi[a];
  int pos = 0;
  if (lane == 0) {
    pos = off_pad[e] + atomicAdd(&cursor[e], 1);
    slotTok[pos] = t;
    slotW[pos] = topw[a];
  }
  pos = __shfl(pos, 0);
  const size_t sb = (size_t)t * DIM + lane * 8;
  f4 v0 = *(const f4*)&x[sb], v1 = *(const f4*)&x[sb + 4];
  u16x4 h0, h1;
  h0[0] = f2bf(v0[0]); h0[1] = f2bf(v0[1]); h0[2] = f2bf(v0[2]); h0[3] = f2bf(v0[3]);
  h1[0] = f2bf(v1[0]); h1[1] = f2bf(v1[1]); h1[2] = f2bf(v1[2]); h1[3] = f2bf(v1[3]);
  *(u16x4*)&Xg[(size_t)pos * DIM + lane * 8] = h0;
  *(u16x4*)&Xg[(size_t)pos * DIM + lane * 8 + 4] = h1;
}

// ---------------- grouped bf16 MFMA GEMM ----------------
// C = A[slot rows, K] * W_e[rows wrow0+n, ldw]^T ; expert from padded segment.
// epi 0: Hout[(m)*ldh + n] = bf16(relu(acc + bias)) ; epi 1: dout[tok*DIM+n] += slotW*(acc + bias)
__global__ __launch_bounds__(256) void k_gemm_bf16(
    const unsigned short* __restrict__ A, int lda,
    const unsigned short* __restrict__ Wb, size_t westride, int ldw, int wrow0,
    const float* __restrict__ bias, int bstride, int brow0,
    int K, int epi,
    unsigned short* __restrict__ Hout, int ldh,
    float* __restrict__ dout,
    const int* __restrict__ slotTok, const float* __restrict__ slotW,
    const int* __restrict__ off_pad) {
  const int m0 = blockIdx.x * BM;
  if (m0 >= off_pad[NE]) return;
  int e = 0;
  while (off_pad[e + 1] <= m0) e++;
  const unsigned short* W = Wb + (size_t)e * westride;
  const int n0 = blockIdx.y * 128;
  __shared__ unsigned short Al[128 * 64];
  __shared__ unsigned short Bl[128 * 64];
  const int tid = threadIdx.x, lane = tid & 63, wid = tid >> 6;
  const int wm = wid >> 1, wn = wid & 1;
  f32x4 acc[4][4] = {};
  const int srow = wid * 32 + (lane >> 3);
  const int scol = (lane & 7) * 8;
  for (int k0 = 0; k0 < K; k0 += 64) {
    const unsigned short* ga = A + (size_t)(m0 + srow) * lda + k0 + scol;
    const unsigned short* gw = W + (size_t)(wrow0 + n0 + srow) * ldw + k0 + scol;
#pragma unroll
    for (int i = 0; i < 4; i++) {
      load_lds16(ga + (size_t)i * 8 * lda, &Al[(wid * 32 + i * 8) * 64]);
      load_lds16(gw + (size_t)i * 8 * ldw, &Bl[(wid * 32 + i * 8) * 64]);
    }
    __syncthreads();
#pragma unroll
    for (int kk = 0; kk < 2; kk++) {
      short8 av[4], bv[4];
      const int ro = kk * 32 + (lane >> 4) * 8;
#pragma unroll
      for (int mi = 0; mi < 4; mi++)
        av[mi] = *(const short8*)&Al[(wm * 64 + mi * 16 + (lane & 15)) * 64 + ro];
#pragma unroll
      for (int ni = 0; ni < 4; ni++)
        bv[ni] = *(const short8*)&Bl[(wn * 64 + ni * 16 + (lane & 15)) * 64 + ro];
#pragma unroll
      for (int mi = 0; mi < 4; mi++) {
#pragma unroll
        for (int ni = 0; ni < 4; ni++)
          acc[mi][ni] = __builtin_amdgcn_mfma_f32_16x16x32_bf16(av[mi], bv[ni], acc[mi][ni], 0, 0, 0);
      }
    }
    __syncthreads();
  }
#pragma unroll
  for (int mi = 0; mi < 4; mi++) {
    const int rb = m0 + wm * 64 + mi * 16 + ((lane >> 4) << 2);
#pragma unroll
    for (int ni = 0; ni < 4; ni++) {
      const int n = n0 + wn * 64 + ni * 16 + (lane & 15);
      const float bn = bias ? bias[(size_t)e * bstride + brow0 + n] : 0.f;
      if (epi == 0) {
#pragma unroll
        for (int r = 0; r < 4; r++) {
          float v = acc[mi][ni][r] + bn;
          v = fmaxf(v, 0.f);
          Hout[(size_t)(rb + r) * ldh + n] = f2bf(v);
        }
      } else {
#pragma unroll
        for (int r = 0; r < 4; r++) {
          const int tok = slotTok[rb + r];
          if (tok >= 0) {
            const float v = (acc[mi][ni][r] + bn) * slotW[rb + r];
            atomicAdd(&dout[(size_t)tok * DIM + n], v);
          }
        }
      }
    }
  }
}

// ---------------- launch ----------------
extern "C" void kernel_launch(void* const* d_in, const int* in_sizes, int n_in,
                              void* d_out, int out_size, void* d_ws, size_t ws_size,
                              hipStream_t stream) {
  const float* src       = (const float*)d_in[0];
  const float* pos       = (const float*)d_in[1];
  const float* in_proj_w = (const float*)d_in[2];
  const float* in_proj_b = (const float*)d_in[3];
  const float* out_w     = (const float*)d_in[4];
  const float* out_b     = (const float*)d_in[5];
  const float* norm1_g   = (const float*)d_in[6];
  const float* norm1_b   = (const float*)d_in[7];
  const float* gate_w    = (const float*)d_in[8];
  const float* gate_b    = (const float*)d_in[9];
  const float* w1        = (const float*)d_in[10];
  const float* b1        = (const float*)d_in[11];
  const float* w2        = (const float*)d_in[12];
  const float* b2        = (const float*)d_in[13];
  float* out = (float*)d_out;
  char* wsb = (char*)d_ws;

  // ---- lifetime-packed arena (total 174,604,544 B ~= 166.5 MiB) ----
  // phase A (attention):
  float* Qt = (float*)(wsb + 0);           // [B,H,HD,S] 32 MiB, dead after attn
  float* Kt = (float*)(wsb + 33554432);    // 32 MiB, dead after attn
  float* Vf = (float*)(wsb + 67108864);    // [B,H,S,HD] 32 MiB, dead after attn
  float* ob = (float*)(wsb + 100663296);   // attn out [S,B,D] 32 MiB, dead after out-proj
  // phase A->B overlays:
  float* proj = (float*)(wsb + 0);                          // over Qt (after attn), dead after LN
  unsigned short* w1b = (unsigned short*)(wsb + 0);         // over proj (after LN), 32 MiB
  unsigned short* w2b = (unsigned short*)(wsb + 33554432);  // over Kt (after attn), 32 MiB
  unsigned short* Xg  = (unsigned short*)(wsb + 67108864);  // over Vf+ob-head (after out-proj), 34 MiB
  unsigned short* Hb  = (unsigned short*)(wsb + 102760448); // over ob-tail (after out-proj), 68 MiB
  // routing arrays:
  char* smallb = wsb + 174063616;
  int*   topi    = (int*)  (smallb + 0);        // 131072 B
  float* topw    = (float*)(smallb + 131072);   // 131072 B
  int*   slotTok = (int*)  (smallb + 262144);   // 139264 B
  float* slotW   = (float*)(smallb + 401408);   // 139264 B
  int*   counts  = (int*)  (smallb + 540672);   // 64 B
  int*   off_pad = (int*)  (smallb + 540736);   // 128 B
  int*   cursor  = (int*)  (smallb + 540864);   // 64 B

  // 1. routing init (no deps)
  k_init<<<(CAP + 255) / 256, 256, 0, stream>>>(slotTok, slotW, counts);
  // 2. Q/K projection (fp32, fused src+pos), scatter to [B,H,HD,S], Q pre-scaled
  k_gemm_f32<<<dim3(128, 8), 256, 0, stream>>>(src, pos, in_proj_w, in_proj_b, 512, 0, Qt, Kt);
  // 3. V projection (fp32) -> [B,H,S,HD]
  k_gemm_f32<<<dim3(128, 4), 256, 0, stream>>>(src, nullptr, in_proj_w + 1024 * 512,
                                               in_proj_b + 1024, 512, 1, Vf, nullptr);
  // 4. flash attention (fp32) -> ob [S,B,D]
  k_attn<<<dim3(16, 128), 256, 0, stream>>>(Qt, Kt, Vf, ob);
  // 5. w2 -> bf16 (Kt region dead now)
  k_cvt_bf16<<<2048, 256, 0, stream>>>(w2, w2b, (size_t)NE * DIM * DFF);
  // 6. output projection (fp32) -> proj (over Qt)
  k_gemm_f32<<<dim3(128, 4), 256, 0, stream>>>(ob, nullptr, out_w, out_b, 512, 2, proj, nullptr);
  // 7. layernorm(src + proj) -> d_out (= x)
  k_ln<<<4096, 256, 0, stream>>>(src, proj, norm1_g, norm1_b, out);
  // 8. w1 -> bf16 (proj region dead now)
  k_cvt_bf16<<<2048, 256, 0, stream>>>(w1, w1b, (size_t)NE * DFF * DIM);
  // 9. gate logits + top2 + counts
  k_gate<<<4096, 256, 0, stream>>>(out, gate_w, gate_b, topi, topw, counts);
  // 10. padded segment offsets
  k_offsets<<<1, 64, 0, stream>>>(counts, off_pad, cursor);
  // 11. zero gathered-token buffer (padding rows must be clean)
  k_zero<<<2048, 256, 0, stream>>>((u32x4*)Xg, (size_t)CAP * DIM * 2 / 16);
  // 12. scatter assignments to slots + gather token rows as bf16
  k_scatter<<<8192, 256, 0, stream>>>(out, topi, topw, off_pad, cursor, slotTok, slotW, Xg);
  // 13. MoE, DFF halved (Hb holds CAP x 1024 bf16 per pass)
  for (int p = 0; p < 2; ++p) {
    // GEMM1: Hb = relu(Xg @ W1_e[p*1024:(p+1)*1024, :]^T + b1)
    k_gemm_bf16<<<dim3(CAP / BM, 8), 256, 0, stream>>>(
        Xg, DIM, w1b, (size_t)DFF * DIM, DIM, p * 1024,
        b1, DFF, p * 1024, DIM, 0, Hb, 1024,
        nullptr, nullptr, nullptr, off_pad);
    // GEMM2: out[tok] += slotW * (Hb @ W2_e[:, p*1024:(p+1)*1024]^T + (p==0 ? b2 : 0))
    k_gemm_bf16<<<dim3(CAP / BM, 4), 256, 0, stream>>>(
        Hb, 1024, w2b + (size_t)p * 1024, (size_t)DIM * DFF, DFF, 0,
        (p == 0 ? b2 : nullptr), DIM, 0, 1024, 1, nullptr, 0,
        out, slotTok, slotW, off_pad);
  }
}

// Round 3
// 2385.634 us; speedup vs baseline: 1.0537x; 1.0537x over previous
//
#include <hip/hip_runtime.h>

// ---------------- types ----------------
typedef float f4 __attribute__((ext_vector_type(4)));
typedef float f32x4 __attribute__((ext_vector_type(4)));
typedef short short8 __attribute__((ext_vector_type(8)));
typedef unsigned short u16x4 __attribute__((ext_vector_type(4)));
typedef unsigned int u32x4 __attribute__((ext_vector_type(4)));

// ---------------- problem constants ----------------
#define S_LEN 1024
#define BATCH 16
#define DIM   512
#define NH    8
#define HDIM  64
#define NE    16
#define DFF   2048
#define T_TOK 16384   // S*B
#define CAP   34816   // 32768 assignments + per-expert padding to BM
#define BM    128

__device__ __forceinline__ unsigned short f2bf(float f) {
  union { float f; unsigned u; } v; v.f = f;
  unsigned r = v.u + 0x7fffu + ((v.u >> 16) & 1u);  // RTNE
  return (unsigned short)(r >> 16);
}

__device__ __forceinline__ void load_lds16(const void* g, void* l) {
  __builtin_amdgcn_global_load_lds(
      (__attribute__((address_space(1))) void*)(void*)g,
      (__attribute__((address_space(3))) void*)l, 16, 0, 0);
}

// ---------------- small utility kernels ----------------
__global__ __launch_bounds__(256) void k_cvt_bf16(const float* __restrict__ in,
                                                  unsigned short* __restrict__ outb,
                                                  size_t n) {
  size_t i = ((size_t)blockIdx.x * 256 + threadIdx.x) * 4;
  size_t stride = (size_t)gridDim.x * 1024;
  for (; i < n; i += stride) {
    f4 v = *(const f4*)&in[i];
    u16x4 o;
    o[0] = f2bf(v[0]); o[1] = f2bf(v[1]); o[2] = f2bf(v[2]); o[3] = f2bf(v[3]);
    *(u16x4*)&outb[i] = o;
  }
}

__global__ __launch_bounds__(256) void k_init(int* __restrict__ slotTok,
                                              float* __restrict__ slotW,
                                              int* __restrict__ counts) {
  int i = blockIdx.x * 256 + threadIdx.x;
  if (i < CAP) { slotTok[i] = -1; slotW[i] = 0.f; }
  if (i < NE) counts[i] = 0;
}

__global__ __launch_bounds__(256) void k_zero(u32x4* __restrict__ p, size_t n16) {
  size_t i = (size_t)blockIdx.x * 256 + threadIdx.x;
  size_t stride = (size_t)gridDim.x * 256;
  u32x4 z = {0u, 0u, 0u, 0u};
  for (; i < n16; i += stride) p[i] = z;
}

// ---------------- fp32 GEMM: C = (A [+ A2]) [M,K] * W[N,K]^T + bias ----------------
// 128x128 tile, 256 threads, 8x8 per thread, BK=32, register double-buffer (T14).
// epi 0: QK scatter (n<512 -> Q scaled 0.125 -> o0 [B,H,HD,S]; else K -> o1)
// epi 1: V scatter -> o0 [B,H,S,HD]
// epi 2: row-major fp32 -> o0 (N must be 512)
__global__ __launch_bounds__(256, 3) void k_gemm_f32(
    const float* __restrict__ A, const float* __restrict__ A2,
    const float* __restrict__ W,
    const float* __restrict__ bias, int K, int epi,
    float* __restrict__ o0, float* __restrict__ o1) {
  __shared__ float Alt[32][132];
  __shared__ float Wlt[32][132];
  const int tid = threadIdx.x, tx = tid & 15, ty = tid >> 4;
  const int m0 = blockIdx.x * 128, n0 = blockIdx.y * 128;
  float acc[8][8];
#pragma unroll
  for (int i = 0; i < 8; i++) {
#pragma unroll
    for (int j = 0; j < 8; j++) acc[i][j] = 0.f;
  }
  f4 ar[4], wr[4];
  // prologue: load k0 = 0 chunk (each thread: 4 f4 per operand; 128 rows x 32 cols)
#pragma unroll
  for (int i = 0; i < 4; i++) {
    const int c = tid + i * 256;               // 0..1023
    const int r = c >> 3, j = (c & 7) * 4;     // row 0..127, col 0..28
    const size_t aoff = (size_t)(m0 + r) * K + j;
    ar[i] = *(const f4*)&A[aoff];
    if (A2) { f4 v2 = *(const f4*)&A2[aoff]; ar[i] += v2; }
    wr[i] = *(const f4*)&W[(size_t)(n0 + r) * K + j];
  }
  for (int k0 = 0; k0 < K; k0 += 32) {
    __syncthreads();   // prior-iter LDS frag reads done
#pragma unroll
    for (int i = 0; i < 4; i++) {
      const int c = tid + i * 256;
      const int r = c >> 3, j = (c & 7) * 4;
      Alt[j + 0][r] = ar[i][0]; Alt[j + 1][r] = ar[i][1];
      Alt[j + 2][r] = ar[i][2]; Alt[j + 3][r] = ar[i][3];
      Wlt[j + 0][r] = wr[i][0]; Wlt[j + 1][r] = wr[i][1];
      Wlt[j + 2][r] = wr[i][2]; Wlt[j + 3][r] = wr[i][3];
    }
    __syncthreads();
    if (k0 + 32 < K) {   // T14: issue next chunk; lands during the FMA loop
#pragma unroll
      for (int i = 0; i < 4; i++) {
        const int c = tid + i * 256;
        const int r = c >> 3, j = (c & 7) * 4;
        const size_t aoff = (size_t)(m0 + r) * K + k0 + 32 + j;
        ar[i] = *(const f4*)&A[aoff];
        if (A2) { f4 v2 = *(const f4*)&A2[aoff]; ar[i] += v2; }
        wr[i] = *(const f4*)&W[(size_t)(n0 + r) * K + k0 + 32 + j];
      }
    }
#pragma unroll 4
    for (int kk = 0; kk < 32; kk++) {
      float a[8], w8[8];
      *(f4*)&a[0]  = *(const f4*)&Alt[kk][ty * 8];
      *(f4*)&a[4]  = *(const f4*)&Alt[kk][ty * 8 + 4];
      *(f4*)&w8[0] = *(const f4*)&Wlt[kk][tx * 8];
      *(f4*)&w8[4] = *(const f4*)&Wlt[kk][tx * 8 + 4];
#pragma unroll
      for (int mi = 0; mi < 8; mi++) {
#pragma unroll
        for (int ni = 0; ni < 8; ni++)
          acc[mi][ni] = fmaf(a[mi], w8[ni], acc[mi][ni]);
      }
    }
  }
  if (epi == 2) {
#pragma unroll
    for (int mi = 0; mi < 8; mi++) {
      const size_t m = (size_t)(m0 + ty * 8 + mi);
#pragma unroll
      for (int nj = 0; nj < 2; nj++) {
        const int n = n0 + tx * 8 + nj * 4;
        f4 v;
        v[0] = acc[mi][nj * 4 + 0] + bias[n + 0];
        v[1] = acc[mi][nj * 4 + 1] + bias[n + 1];
        v[2] = acc[mi][nj * 4 + 2] + bias[n + 2];
        v[3] = acc[mi][nj * 4 + 3] + bias[n + 3];
        *(f4*)&o0[m * 512 + n] = v;
      }
    }
  } else {
#pragma unroll
    for (int mi = 0; mi < 8; mi++) {
      const int m = m0 + ty * 8 + mi;
      const int bidx = m & 15, ss = m >> 4;   // token = s*B + b
#pragma unroll
      for (int ni = 0; ni < 8; ni++) {
        const int n = n0 + tx * 8 + ni;
        float v = acc[mi][ni] + bias[n];
        if (epi == 0) {
          if (n < 512) {
            // Q, pre-scaled by 1/sqrt(HD): layout [B,H,HD,S]
            o0[((size_t)((bidx * NH + (n >> 6)) * HDIM + (n & 63))) * S_LEN + ss] = v * 0.125f;
          } else {
            const int n2 = n - 512;
            o1[((size_t)((bidx * NH + (n2 >> 6)) * HDIM + (n2 & 63))) * S_LEN + ss] = v;
          }
        } else {  // epi 1: V layout [B,H,S,HD]
          o0[((size_t)(bidx * NH + (n >> 6)) * S_LEN + ss) * HDIM + (n & 63)] = v;
        }
      }
    }
  }
}

// ---------------- fp32 flash attention ----------------
// grid (S/64, B*H); Qt/Kt: [B,H,HD,S]; Vf: [B,H,S,HD]; O: [S,B,D]
// LDS 49 KB (P overlays K) -> 3 blocks/CU; T14 reg prefetch of next K/V tile.
__global__ __launch_bounds__(256, 3) void k_attn(const float* __restrict__ Qt,
                                                 const float* __restrict__ Kt,
                                                 const float* __restrict__ Vf,
                                                 float* __restrict__ O) {
  const int q0 = blockIdx.x * 64;
  const int bh = blockIdx.y;
  const int b = bh >> 3, h = bh & 7;
  const float* Qh = Qt + (size_t)bh * (HDIM * S_LEN);
  const float* Kh = Kt + (size_t)bh * (HDIM * S_LEN);
  const float* Vh = Vf + (size_t)bh * (S_LEN * HDIM);
  __shared__ float Ql[64][64];   // [hd][q] 16 KB, persistent
  __shared__ float KP[64][68];   // K as [hd][k] (cols 0..63) / P as [k][q] — overlay, 17 KB
  __shared__ float Vl[64][64];   // [k][hd] 16 KB
  const int tid = threadIdx.x, tx = tid & 15, ty = tid >> 4;
  // stage Q once
#pragma unroll
  for (int i = 0; i < 4; i++) {
    const int c = tid + i * 256;
    const int r = c >> 4, j = (c & 15) << 2;
    *(f4*)&Ql[r][j] = *(const f4*)&Qh[(size_t)r * S_LEN + q0 + j];
  }
  // prologue: first K/V tile into regs
  f4 kr[4], vr[4];
#pragma unroll
  for (int i = 0; i < 4; i++) {
    const int c = tid + i * 256;
    const int r = c >> 4, j = (c & 15) << 2;
    kr[i] = *(const f4*)&Kh[(size_t)r * S_LEN + j];
    vr[i] = *(const f4*)&Vh[(size_t)r * HDIM + j];
  }
  float m_[4], l_[4], o_[4][4];
#pragma unroll
  for (int r = 0; r < 4; r++) {
    m_[r] = -1e30f; l_[r] = 0.f;
#pragma unroll
    for (int c = 0; c < 4; c++) o_[r][c] = 0.f;
  }
  for (int kt = 0; kt < 16; kt++) {
    // write staged K/V regs -> LDS (prior iter's P/V reads finished at sync_d)
#pragma unroll
    for (int i = 0; i < 4; i++) {
      const int c = tid + i * 256;
      const int r = c >> 4, j = (c & 15) << 2;
      *(f4*)&KP[r][j] = kr[i];
      *(f4*)&Vl[r][j] = vr[i];
    }
    __syncthreads();               // sync_a: K,V (and Q on iter 0) visible
    // T14: issue next tile loads now; consumed at next loop-top ds_write
    if (kt < 15) {
      const int s0n = (kt + 1) * 64;
#pragma unroll
      for (int i = 0; i < 4; i++) {
        const int c = tid + i * 256;
        const int r = c >> 4, j = (c & 15) << 2;
        kr[i] = *(const f4*)&Kh[(size_t)r * S_LEN + s0n + j];
        vr[i] = *(const f4*)&Vh[(size_t)(s0n + r) * HDIM + j];
      }
    }
    // QK^T
    float sc[4][4];
#pragma unroll
    for (int r = 0; r < 4; r++) {
#pragma unroll
      for (int c = 0; c < 4; c++) sc[r][c] = 0.f;
    }
#pragma unroll 2
    for (int d = 0; d < 64; d += 2) {
      f4 aq0 = *(const f4*)&Ql[d][ty * 4];
      f4 bk0 = *(const f4*)&KP[d][tx * 4];
      f4 aq1 = *(const f4*)&Ql[d + 1][ty * 4];
      f4 bk1 = *(const f4*)&KP[d + 1][tx * 4];
#pragma unroll
      for (int r = 0; r < 4; r++) {
#pragma unroll
        for (int c = 0; c < 4; c++) {
          sc[r][c] = fmaf(aq0[r], bk0[c], sc[r][c]);
          sc[r][c] = fmaf(aq1[r], bk1[c], sc[r][c]);
        }
      }
    }
    // online softmax (stats in regs, no LDS)
    float esc[4], rs[4];
#pragma unroll
    for (int r = 0; r < 4; r++) {
      float tm = fmaxf(fmaxf(sc[r][0], sc[r][1]), fmaxf(sc[r][2], sc[r][3]));
#pragma unroll
      for (int d = 1; d < 16; d <<= 1) tm = fmaxf(tm, __shfl_xor(tm, d));
      const float mn = fmaxf(m_[r], tm);
      esc[r] = __expf(m_[r] - mn);
      m_[r] = mn;
      rs[r] = 0.f;
    }
#pragma unroll
    for (int r = 0; r < 4; r++) {
#pragma unroll
      for (int c = 0; c < 4; c++) {
        const float p = __expf(sc[r][c] - m_[r]);
        rs[r] += p;
        sc[r][c] = p;
      }
    }
#pragma unroll
    for (int r = 0; r < 4; r++) {
#pragma unroll
      for (int d = 1; d < 16; d <<= 1) rs[r] += __shfl_xor(rs[r], d);
      l_[r] = l_[r] * esc[r] + rs[r];
#pragma unroll
      for (int c = 0; c < 4; c++) o_[r][c] *= esc[r];
    }
    __syncthreads();               // sync_b: all K-reads done before P overwrites
#pragma unroll
    for (int r = 0; r < 4; r++) {
#pragma unroll
      for (int c = 0; c < 4; c++) KP[tx * 4 + c][ty * 4 + r] = sc[r][c];
    }
    __syncthreads();               // sync_c: P visible
    // PV
#pragma unroll 2
    for (int k = 0; k < 64; k += 2) {
      f4 ap0 = *(const f4*)&KP[k][ty * 4];
      f4 av0 = *(const f4*)&Vl[k][tx * 4];
      f4 ap1 = *(const f4*)&KP[k + 1][ty * 4];
      f4 av1 = *(const f4*)&Vl[k + 1][tx * 4];
#pragma unroll
      for (int r = 0; r < 4; r++) {
#pragma unroll
        for (int c = 0; c < 4; c++) {
          o_[r][c] = fmaf(ap0[r], av0[c], o_[r][c]);
          o_[r][c] = fmaf(ap1[r], av1[c], o_[r][c]);
        }
      }
    }
    __syncthreads();               // sync_d: P/V reads done -> next ds_write safe
  }
#pragma unroll
  for (int r = 0; r < 4; r++) {
    const float inv = 1.f / l_[r];
    const int srow = q0 + ty * 4 + r;
    f4 v;
    v[0] = o_[r][0] * inv; v[1] = o_[r][1] * inv;
    v[2] = o_[r][2] * inv; v[3] = o_[r][3] * inv;
    *(f4*)&O[((size_t)srow * BATCH + b) * DIM + h * HDIM + tx * 4] = v;
  }
}

// ---------------- layernorm: x = LN(src + proj)*g + b -> out ----------------
__global__ __launch_bounds__(256) void k_ln(const float* __restrict__ src,
                                            const float* __restrict__ proj,
                                            const float* __restrict__ g,
                                            const float* __restrict__ bt,
                                            float* __restrict__ xout) {
  const int wid = threadIdx.x >> 6, lane = threadIdx.x & 63;
  const int tok = blockIdx.x * 4 + wid;
  const size_t base = (size_t)tok * DIM + lane * 8;
  f4 a0 = *(const f4*)&src[base],  a1 = *(const f4*)&src[base + 4];
  f4 p0 = *(const f4*)&proj[base], p1 = *(const f4*)&proj[base + 4];
  float x[8];
  x[0] = a0[0] + p0[0]; x[1] = a0[1] + p0[1]; x[2] = a0[2] + p0[2]; x[3] = a0[3] + p0[3];
  x[4] = a1[0] + p1[0]; x[5] = a1[1] + p1[1]; x[6] = a1[2] + p1[2]; x[7] = a1[3] + p1[3];
  float s = 0.f, sq = 0.f;
#pragma unroll
  for (int j = 0; j < 8; j++) { s += x[j]; sq = fmaf(x[j], x[j], sq); }
#pragma unroll
  for (int d = 1; d < 64; d <<= 1) { s += __shfl_xor(s, d); sq += __shfl_xor(sq, d); }
  const float mean = s * (1.f / 512.f);
  const float var = sq * (1.f / 512.f) - mean * mean;
  const float rstd = 1.f / sqrtf(var + 1e-5f);
  const int ci = lane * 8;
  f4 o0v, o1v;
#pragma unroll
  for (int j = 0; j < 4; j++) o0v[j] = (x[j] - mean) * rstd * g[ci + j] + bt[ci + j];
#pragma unroll
  for (int j = 0; j < 4; j++) o1v[j] = (x[4 + j] - mean) * rstd * g[ci + 4 + j] + bt[ci + 4 + j];
  *(f4*)&xout[base] = o0v;
  *(f4*)&xout[base + 4] = o1v;
}

// ---------------- gate: logits, top-2, softmax, counts ----------------
__global__ __launch_bounds__(256) void k_gate(const float* __restrict__ x,
                                              const float* __restrict__ gw,
                                              const float* __restrict__ gb,
                                              int* __restrict__ topi,
                                              float* __restrict__ topw,
                                              int* __restrict__ counts) {
  const int wid = threadIdx.x >> 6, lane = threadIdx.x & 63;
  const int tok = blockIdx.x * 4 + wid;
  const size_t base = (size_t)tok * DIM + lane * 8;
  f4 x0 = *(const f4*)&x[base], x1 = *(const f4*)&x[base + 4];
  float best = -1e30f, sec = -1e30f;
  int bi = 0, si = 0;
  for (int e = 0; e < NE; e++) {
    const float* w = gw + (size_t)e * DIM + lane * 8;
    f4 w0 = *(const f4*)&w[0], w1 = *(const f4*)&w[4];
    float d = x0[0] * w0[0];
    d = fmaf(x0[1], w0[1], d); d = fmaf(x0[2], w0[2], d); d = fmaf(x0[3], w0[3], d);
    d = fmaf(x1[0], w1[0], d); d = fmaf(x1[1], w1[1], d);
    d = fmaf(x1[2], w1[2], d); d = fmaf(x1[3], w1[3], d);
#pragma unroll
    for (int dd = 1; dd < 64; dd <<= 1) d += __shfl_xor(d, dd);
    d += gb[e];
    if (d > best) { sec = best; si = bi; best = d; bi = e; }
    else if (d > sec) { sec = d; si = e; }
  }
  if (lane == 0) {
    const float e1 = expf(sec - best);
    const float inv = 1.f / (1.f + e1);
    topi[2 * tok] = bi;  topi[2 * tok + 1] = si;
    topw[2 * tok] = inv; topw[2 * tok + 1] = e1 * inv;
    atomicAdd(&counts[bi], 1);
    atomicAdd(&counts[si], 1);
  }
}

__global__ void k_offsets(const int* __restrict__ counts,
                          int* __restrict__ off_pad, int* __restrict__ cursor) {
  if (threadIdx.x == 0) {
    int o = 0;
    off_pad[0] = 0;
    for (int e = 0; e < NE; e++) {
      cursor[e] = 0;
      o += ((counts[e] + BM - 1) / BM) * BM;
      off_pad[e + 1] = o;
    }
  }
}

// one wave per (token, k) assignment: claim slot + gather row as bf16
__global__ __launch_bounds__(256) void k_scatter(const float* __restrict__ x,
                                                 const int* __restrict__ topi,
                                                 const float* __restrict__ topw,
                                                 const int* __restrict__ off_pad,
                                                 int* __restrict__ cursor,
                                                 int* __restrict__ slotTok,
                                                 float* __restrict__ slotW,
                                                 unsigned short* __restrict__ Xg) {
  const int wid = threadIdx.x >> 6, lane = threadIdx.x & 63;
  const int a = blockIdx.x * 4 + wid;   // [0, 32768)
  const int t = a >> 1;
  const int e = topi[a];
  int pos = 0;
  if (lane == 0) {
    pos = off_pad[e] + atomicAdd(&cursor[e], 1);
    slotTok[pos] = t;
    slotW[pos] = topw[a];
  }
  pos = __shfl(pos, 0);
  const size_t sb = (size_t)t * DIM + lane * 8;
  f4 v0 = *(const f4*)&x[sb], v1 = *(const f4*)&x[sb + 4];
  u16x4 h0, h1;
  h0[0] = f2bf(v0[0]); h0[1] = f2bf(v0[1]); h0[2] = f2bf(v0[2]); h0[3] = f2bf(v0[3]);
  h1[0] = f2bf(v1[0]); h1[1] = f2bf(v1[1]); h1[2] = f2bf(v1[2]); h1[3] = f2bf(v1[3]);
  *(u16x4*)&Xg[(size_t)pos * DIM + lane * 8] = h0;
  *(u16x4*)&Xg[(size_t)pos * DIM + lane * 8 + 4] = h1;
}

// ---------------- grouped bf16 MFMA GEMM ----------------
// C = A[slot rows, K] * W_e[rows wrow0+n, ldw]^T ; expert from padded segment.
// epi 0: Hout[(m)*ldh + n] = bf16(relu(acc + bias)) ; epi 1: dout[tok*DIM+n] += slotW*(acc + bias)
__global__ __launch_bounds__(256) void k_gemm_bf16(
    const unsigned short* __restrict__ A, int lda,
    const unsigned short* __restrict__ Wb, size_t westride, int ldw, int wrow0,
    const float* __restrict__ bias, int bstride, int brow0,
    int K, int epi,
    unsigned short* __restrict__ Hout, int ldh,
    float* __restrict__ dout,
    const int* __restrict__ slotTok, const float* __restrict__ slotW,
    const int* __restrict__ off_pad) {
  const int m0 = blockIdx.x * BM;
  if (m0 >= off_pad[NE]) return;
  int e = 0;
  while (off_pad[e + 1] <= m0) e++;
  const unsigned short* W = Wb + (size_t)e * westride;
  const int n0 = blockIdx.y * 128;
  __shared__ unsigned short Al[128 * 64];
  __shared__ unsigned short Bl[128 * 64];
  const int tid = threadIdx.x, lane = tid & 63, wid = tid >> 6;
  const int wm = wid >> 1, wn = wid & 1;
  f32x4 acc[4][4] = {};
  const int srow = wid * 32 + (lane >> 3);
  const int scol = (lane & 7) * 8;
  for (int k0 = 0; k0 < K; k0 += 64) {
    const unsigned short* ga = A + (size_t)(m0 + srow) * lda + k0 + scol;
    const unsigned short* gw = W + (size_t)(wrow0 + n0 + srow) * ldw + k0 + scol;
#pragma unroll
    for (int i = 0; i < 4; i++) {
      load_lds16(ga + (size_t)i * 8 * lda, &Al[(wid * 32 + i * 8) * 64]);
      load_lds16(gw + (size_t)i * 8 * ldw, &Bl[(wid * 32 + i * 8) * 64]);
    }
    __syncthreads();
#pragma unroll
    for (int kk = 0; kk < 2; kk++) {
      short8 av[4], bv[4];
      const int ro = kk * 32 + (lane >> 4) * 8;
#pragma unroll
      for (int mi = 0; mi < 4; mi++)
        av[mi] = *(const short8*)&Al[(wm * 64 + mi * 16 + (lane & 15)) * 64 + ro];
#pragma unroll
      for (int ni = 0; ni < 4; ni++)
        bv[ni] = *(const short8*)&Bl[(wn * 64 + ni * 16 + (lane & 15)) * 64 + ro];
#pragma unroll
      for (int mi = 0; mi < 4; mi++) {
#pragma unroll
        for (int ni = 0; ni < 4; ni++)
          acc[mi][ni] = __builtin_amdgcn_mfma_f32_16x16x32_bf16(av[mi], bv[ni], acc[mi][ni], 0, 0, 0);
      }
    }
    __syncthreads();
  }
#pragma unroll
  for (int mi = 0; mi < 4; mi++) {
    const int rb = m0 + wm * 64 + mi * 16 + ((lane >> 4) << 2);
#pragma unroll
    for (int ni = 0; ni < 4; ni++) {
      const int n = n0 + wn * 64 + ni * 16 + (lane & 15);
      const float bn = bias ? bias[(size_t)e * bstride + brow0 + n] : 0.f;
      if (epi == 0) {
#pragma unroll
        for (int r = 0; r < 4; r++) {
          float v = acc[mi][ni][r] + bn;
          v = fmaxf(v, 0.f);
          Hout[(size_t)(rb + r) * ldh + n] = f2bf(v);
        }
      } else {
#pragma unroll
        for (int r = 0; r < 4; r++) {
          const int tok = slotTok[rb + r];
          if (tok >= 0) {
            const float v = (acc[mi][ni][r] + bn) * slotW[rb + r];
            atomicAdd(&dout[(size_t)tok * DIM + n], v);
          }
        }
      }
    }
  }
}

// ---------------- launch ----------------
extern "C" void kernel_launch(void* const* d_in, const int* in_sizes, int n_in,
                              void* d_out, int out_size, void* d_ws, size_t ws_size,
                              hipStream_t stream) {
  const float* src       = (const float*)d_in[0];
  const float* pos       = (const float*)d_in[1];
  const float* in_proj_w = (const float*)d_in[2];
  const float* in_proj_b = (const float*)d_in[3];
  const float* out_w     = (const float*)d_in[4];
  const float* out_b     = (const float*)d_in[5];
  const float* norm1_g   = (const float*)d_in[6];
  const float* norm1_b   = (const float*)d_in[7];
  const float* gate_w    = (const float*)d_in[8];
  const float* gate_b    = (const float*)d_in[9];
  const float* w1        = (const float*)d_in[10];
  const float* b1        = (const float*)d_in[11];
  const float* w2        = (const float*)d_in[12];
  const float* b2        = (const float*)d_in[13];
  float* out = (float*)d_out;
  char* wsb = (char*)d_ws;

  // ---- lifetime-packed arena (total ~166.5 MiB) ----
  float* Qt = (float*)(wsb + 0);           // [B,H,HD,S] 32 MiB, dead after attn
  float* Kt = (float*)(wsb + 33554432);    // 32 MiB, dead after attn
  float* Vf = (float*)(wsb + 67108864);    // [B,H,S,HD] 32 MiB, dead after attn
  float* ob = (float*)(wsb + 100663296);   // attn out [S,B,D] 32 MiB, dead after out-proj
  float* proj = (float*)(wsb + 0);                          // over Qt (after attn), dead after LN
  unsigned short* w1b = (unsigned short*)(wsb + 0);         // over proj (after LN), 32 MiB
  unsigned short* w2b = (unsigned short*)(wsb + 33554432);  // over Kt (after attn), 32 MiB
  unsigned short* Xg  = (unsigned short*)(wsb + 67108864);  // over Vf+ob-head, 34 MiB
  unsigned short* Hb  = (unsigned short*)(wsb + 102760448); // over ob-tail, 68 MiB
  char* smallb = wsb + 174063616;
  int*   topi    = (int*)  (smallb + 0);
  float* topw    = (float*)(smallb + 131072);
  int*   slotTok = (int*)  (smallb + 262144);
  float* slotW   = (float*)(smallb + 401408);
  int*   counts  = (int*)  (smallb + 540672);
  int*   off_pad = (int*)  (smallb + 540736);
  int*   cursor  = (int*)  (smallb + 540864);

  // 1. routing init
  k_init<<<(CAP + 255) / 256, 256, 0, stream>>>(slotTok, slotW, counts);
  // 2. Q/K projection (fp32, fused src+pos), scatter to [B,H,HD,S], Q pre-scaled
  k_gemm_f32<<<dim3(128, 8), 256, 0, stream>>>(src, pos, in_proj_w, in_proj_b, 512, 0, Qt, Kt);
  // 3. V projection (fp32) -> [B,H,S,HD]
  k_gemm_f32<<<dim3(128, 4), 256, 0, stream>>>(src, nullptr, in_proj_w + 1024 * 512,
                                               in_proj_b + 1024, 512, 1, Vf, nullptr);
  // 4. flash attention (fp32) -> ob [S,B,D]
  k_attn<<<dim3(16, 128), 256, 0, stream>>>(Qt, Kt, Vf, ob);
  // 5. w2 -> bf16 (Kt dead)
  k_cvt_bf16<<<2048, 256, 0, stream>>>(w2, w2b, (size_t)NE * DIM * DFF);
  // 6. output projection (fp32) -> proj (over Qt)
  k_gemm_f32<<<dim3(128, 4), 256, 0, stream>>>(ob, nullptr, out_w, out_b, 512, 2, proj, nullptr);
  // 7. layernorm(src + proj) -> d_out (= x)
  k_ln<<<4096, 256, 0, stream>>>(src, proj, norm1_g, norm1_b, out);
  // 8. w1 -> bf16 (proj dead)
  k_cvt_bf16<<<2048, 256, 0, stream>>>(w1, w1b, (size_t)NE * DFF * DIM);
  // 9. gate logits + top2 + counts
  k_gate<<<4096, 256, 0, stream>>>(out, gate_w, gate_b, topi, topw, counts);
  // 10. padded segment offsets
  k_offsets<<<1, 64, 0, stream>>>(counts, off_pad, cursor);
  // 11. zero gathered-token buffer
  k_zero<<<2048, 256, 0, stream>>>((u32x4*)Xg, (size_t)CAP * DIM * 2 / 16);
  // 12. scatter assignments + gather token rows as bf16
  k_scatter<<<8192, 256, 0, stream>>>(out, topi, topw, off_pad, cursor, slotTok, slotW, Xg);
  // 13. MoE, DFF halved
  for (int p = 0; p < 2; ++p) {
    k_gemm_bf16<<<dim3(CAP / BM, 8), 256, 0, stream>>>(
        Xg, DIM, w1b, (size_t)DFF * DIM, DIM, p * 1024,
        b1, DFF, p * 1024, DIM, 0, Hb, 1024,
        nullptr, nullptr, nullptr, off_pad);
    k_gemm_bf16<<<dim3(CAP / BM, 4), 256, 0, stream>>>(
        Hb, 1024, w2b + (size_t)p * 1024, (size_t)DIM * DFF, DFF, 0,
        (p == 0 ? b2 : nullptr), DIM, 0, 1024, 1, nullptr, 0,
        out, slotTok, slotW, off_pad);
  }
}

// Round 4
// 2103.730 us; speedup vs baseline: 1.1949x; 1.1340x over previous
//
#include <hip/hip_runtime.h>

// ---------------- types ----------------
typedef float f4 __attribute__((ext_vector_type(4)));
typedef float f32x4 __attribute__((ext_vector_type(4)));
typedef short short8 __attribute__((ext_vector_type(8)));
typedef unsigned short u16x4 __attribute__((ext_vector_type(4)));
typedef unsigned short u16x8 __attribute__((ext_vector_type(8)));
typedef unsigned int u32x4 __attribute__((ext_vector_type(4)));

// ---------------- problem constants ----------------
#define S_LEN 1024
#define BATCH 16
#define DIM   512
#define NH    8
#define HDIM  64
#define NE    16
#define DFF   2048
#define T_TOK 16384   // S*B
#define CAP   34816   // 32768 assignments + per-expert padding to BM
#define BM    128

__device__ __forceinline__ unsigned short f2bf(float f) {
  union { float f; unsigned u; } v; v.f = f;
  unsigned r = v.u + 0x7fffu + ((v.u >> 16) & 1u);  // RTNE
  return (unsigned short)(r >> 16);
}
__device__ __forceinline__ float bf2f(unsigned short h) {
  union { unsigned u; float f; } v; v.u = ((unsigned)h) << 16;
  return v.f;
}

__device__ __forceinline__ void load_lds16(const void* g, void* l) {
  __builtin_amdgcn_global_load_lds(
      (__attribute__((address_space(1))) void*)(void*)g,
      (__attribute__((address_space(3))) void*)l, 16, 0, 0);
}

// ---------------- small utility kernels ----------------
__global__ __launch_bounds__(256) void k_cvt_bf16(const float* __restrict__ in,
                                                  unsigned short* __restrict__ outb,
                                                  size_t n) {
  size_t i = ((size_t)blockIdx.x * 256 + threadIdx.x) * 4;
  size_t stride = (size_t)gridDim.x * 1024;
  for (; i < n; i += stride) {
    f4 v = *(const f4*)&in[i];
    u16x4 o;
    o[0] = f2bf(v[0]); o[1] = f2bf(v[1]); o[2] = f2bf(v[2]); o[3] = f2bf(v[3]);
    *(u16x4*)&outb[i] = o;
  }
}

// split fp32 -> bf16 hi + bf16 lo (lo = round(x - hi))
__global__ __launch_bounds__(256) void k_split_w(const float* __restrict__ in,
                                                 unsigned short* __restrict__ hi,
                                                 unsigned short* __restrict__ lo,
                                                 size_t n) {
  size_t i = ((size_t)blockIdx.x * 256 + threadIdx.x) * 4;
  size_t stride = (size_t)gridDim.x * 1024;
  for (; i < n; i += stride) {
    f4 v = *(const f4*)&in[i];
    u16x4 h, l;
#pragma unroll
    for (int j = 0; j < 4; j++) {
      unsigned short hh = f2bf(v[j]);
      h[j] = hh;
      l[j] = f2bf(v[j] - bf2f(hh));
    }
    *(u16x4*)&hi[i] = h;
    *(u16x4*)&lo[i] = l;
  }
}

__global__ __launch_bounds__(256) void k_init(int* __restrict__ slotTok,
                                              float* __restrict__ slotW,
                                              int* __restrict__ counts) {
  int i = blockIdx.x * 256 + threadIdx.x;
  if (i < CAP) { slotTok[i] = -1; slotW[i] = 0.f; }
  if (i < NE) counts[i] = 0;
}

__global__ __launch_bounds__(256) void k_zero(u32x4* __restrict__ p, size_t n16) {
  size_t i = (size_t)blockIdx.x * 256 + threadIdx.x;
  size_t stride = (size_t)gridDim.x * 256;
  u32x4 z = {0u, 0u, 0u, 0u};
  for (; i < n16; i += stride) p[i] = z;
}

// ---------------- split-bf16 MFMA GEMM (fp32-accurate via hi/lo) ----------------
// C = (A [+A2])[M,512] * W[N,512]^T + bias, W pre-split into Wh/Wl bf16.
// 128x128 tile, BK=32, 2x2 waves, 4x4 16x16x32 frags, 3 MFMAs per frag (hh+hl+lh).
// epi 0: QK scatter (n<512 -> Q*0.125 -> o0 [B,H,HD,S]; else K -> o1)
// epi 1: V scatter -> o0 [B,H,S,HD]
__global__ __launch_bounds__(256, 2) void k_gemm_split(
    const float* __restrict__ A, const float* __restrict__ A2,
    const unsigned short* __restrict__ Wh, const unsigned short* __restrict__ Wl,
    const float* __restrict__ bias, int epi,
    float* __restrict__ o0, float* __restrict__ o1) {
  __shared__ unsigned short AhL[128 * 32];
  __shared__ unsigned short AlL[128 * 32];
  __shared__ unsigned short WhL[128 * 32];
  __shared__ unsigned short WlL[128 * 32];
  const int tid = threadIdx.x, lane = tid & 63, wid = tid >> 6;
  const int wm = wid >> 1, wn = wid & 1;
  const int m0 = blockIdx.x * 128, n0 = blockIdx.y * 128;
  const int row = tid >> 1, half = tid & 1;      // A staging: 2 threads/row
  const int xr = (row >> 1) & 3;                 // A-side write swizzle
  f32x4 acc[4][4] = {};
  f4 ar[4];
  // prologue: A chunk k0=0
#pragma unroll
  for (int j = 0; j < 4; j++) {
    const size_t aoff = (size_t)(m0 + row) * 512 + half * 16 + j * 4;
    ar[j] = *(const f4*)&A[aoff];
    if (A2) { f4 v2 = *(const f4*)&A2[aoff]; ar[j] += v2; }
  }
  for (int k0 = 0; k0 < 512; k0 += 32) {
    __syncthreads();                             // prior frag reads done
    // convert staged A regs -> hi/lo, swizzled ds_write
    u16x8 hi8[2], lo8[2];
#pragma unroll
    for (int j = 0; j < 16; j++) {
      const float x = ar[j >> 2][j & 3];
      const unsigned short h = f2bf(x);
      hi8[j >> 3][j & 7] = h;
      lo8[j >> 3][j & 7] = f2bf(x - bf2f(h));
    }
    const int c0 = half * 2;
    *(u16x8*)&AhL[row * 32 + (((c0 + 0) ^ xr) << 3)] = hi8[0];
    *(u16x8*)&AhL[row * 32 + (((c0 + 1) ^ xr) << 3)] = hi8[1];
    *(u16x8*)&AlL[row * 32 + (((c0 + 0) ^ xr) << 3)] = lo8[0];
    *(u16x8*)&AlL[row * 32 + (((c0 + 1) ^ xr) << 3)] = lo8[1];
    // W async stage: linear LDS dest + inverse-swizzled global source (G21)
#pragma unroll
    for (int i = 0; i < 2; i++) {
      const int rowW = i * 64 + wid * 16 + (lane >> 2);
      const int clog = (lane & 3) ^ ((rowW >> 1) & 3);
      const size_t woff = (size_t)(n0 + rowW) * 512 + k0 + (clog << 3);
      load_lds16(Wh + woff, &WhL[i * 2048 + wid * 512]);
      load_lds16(Wl + woff, &WlL[i * 2048 + wid * 512]);
    }
    __syncthreads();                             // drains ds_write + global_load_lds
    // T14: prefetch next A chunk into regs during MFMA phase
    if (k0 + 32 < 512) {
#pragma unroll
      for (int j = 0; j < 4; j++) {
        const size_t aoff = (size_t)(m0 + row) * 512 + k0 + 32 + half * 16 + j * 4;
        ar[j] = *(const f4*)&A[aoff];
        if (A2) { f4 v2 = *(const f4*)&A2[aoff]; ar[j] += v2; }
      }
    }
    // fragments (swizzled reads) + 3-term MFMA
    const int l15 = lane & 15, lk = lane >> 4;
    const int xa = (l15 >> 1) & 3;
    short8 avh[4], avl[4], bvh[4], bvl[4];
#pragma unroll
    for (int mi = 0; mi < 4; mi++) {
      const int mr = wm * 64 + mi * 16 + l15;
      avh[mi] = *(const short8*)&AhL[mr * 32 + ((lk ^ xa) << 3)];
      avl[mi] = *(const short8*)&AlL[mr * 32 + ((lk ^ xa) << 3)];
    }
#pragma unroll
    for (int ni = 0; ni < 4; ni++) {
      const int nr = wn * 64 + ni * 16 + l15;
      bvh[ni] = *(const short8*)&WhL[nr * 32 + ((lk ^ xa) << 3)];
      bvl[ni] = *(const short8*)&WlL[nr * 32 + ((lk ^ xa) << 3)];
    }
#pragma unroll
    for (int mi = 0; mi < 4; mi++) {
#pragma unroll
      for (int ni = 0; ni < 4; ni++) {
        acc[mi][ni] = __builtin_amdgcn_mfma_f32_16x16x32_bf16(avh[mi], bvh[ni], acc[mi][ni], 0, 0, 0);
        acc[mi][ni] = __builtin_amdgcn_mfma_f32_16x16x32_bf16(avh[mi], bvl[ni], acc[mi][ni], 0, 0, 0);
        acc[mi][ni] = __builtin_amdgcn_mfma_f32_16x16x32_bf16(avl[mi], bvh[ni], acc[mi][ni], 0, 0, 0);
      }
    }
  }
  // epilogue: scatter (acc row = M token, col = N feature)
#pragma unroll
  for (int mi = 0; mi < 4; mi++) {
    const int rb = m0 + wm * 64 + mi * 16 + ((lane >> 4) << 2);
#pragma unroll
    for (int ni = 0; ni < 4; ni++) {
      const int n = n0 + wn * 64 + ni * 16 + (lane & 15);
      const float bn = bias[n];
#pragma unroll
      for (int r = 0; r < 4; r++) {
        const int m = rb + r;
        const int bidx = m & 15, ss = m >> 4;    // token = s*B + b
        const float v = acc[mi][ni][r] + bn;
        if (epi == 0) {
          if (n < 512) {
            o0[((size_t)((bidx * NH + (n >> 6)) * HDIM + (n & 63))) * S_LEN + ss] = v * 0.125f;
          } else {
            const int n2 = n - 512;
            o1[((size_t)((bidx * NH + (n2 >> 6)) * HDIM + (n2 & 63))) * S_LEN + ss] = v;
          }
        } else {  // epi 1: V layout [B,H,S,HD]
          o0[((size_t)(bidx * NH + (n >> 6)) * S_LEN + ss) * HDIM + (n & 63)] = v;
        }
      }
    }
  }
}

// ---------------- fp32 GEMM (out-proj only): C = A[M,K]*W[N,K]^T + bias ----------------
__global__ __launch_bounds__(256, 3) void k_gemm_f32(
    const float* __restrict__ A, const float* __restrict__ W,
    const float* __restrict__ bias, int K,
    float* __restrict__ o0) {
  __shared__ float Alt[32][132];
  __shared__ float Wlt[32][132];
  const int tid = threadIdx.x, tx = tid & 15, ty = tid >> 4;
  const int m0 = blockIdx.x * 128, n0 = blockIdx.y * 128;
  float acc[8][8];
#pragma unroll
  for (int i = 0; i < 8; i++) {
#pragma unroll
    for (int j = 0; j < 8; j++) acc[i][j] = 0.f;
  }
  f4 ar[4], wr[4];
#pragma unroll
  for (int i = 0; i < 4; i++) {
    const int c = tid + i * 256;
    const int r = c >> 3, j = (c & 7) * 4;
    ar[i] = *(const f4*)&A[(size_t)(m0 + r) * K + j];
    wr[i] = *(const f4*)&W[(size_t)(n0 + r) * K + j];
  }
  for (int k0 = 0; k0 < K; k0 += 32) {
    __syncthreads();
#pragma unroll
    for (int i = 0; i < 4; i++) {
      const int c = tid + i * 256;
      const int r = c >> 3, j = (c & 7) * 4;
      Alt[j + 0][r] = ar[i][0]; Alt[j + 1][r] = ar[i][1];
      Alt[j + 2][r] = ar[i][2]; Alt[j + 3][r] = ar[i][3];
      Wlt[j + 0][r] = wr[i][0]; Wlt[j + 1][r] = wr[i][1];
      Wlt[j + 2][r] = wr[i][2]; Wlt[j + 3][r] = wr[i][3];
    }
    __syncthreads();
    if (k0 + 32 < K) {
#pragma unroll
      for (int i = 0; i < 4; i++) {
        const int c = tid + i * 256;
        const int r = c >> 3, j = (c & 7) * 4;
        ar[i] = *(const f4*)&A[(size_t)(m0 + r) * K + k0 + 32 + j];
        wr[i] = *(const f4*)&W[(size_t)(n0 + r) * K + k0 + 32 + j];
      }
    }
#pragma unroll 4
    for (int kk = 0; kk < 32; kk++) {
      float a[8], w8[8];
      *(f4*)&a[0]  = *(const f4*)&Alt[kk][ty * 8];
      *(f4*)&a[4]  = *(const f4*)&Alt[kk][ty * 8 + 4];
      *(f4*)&w8[0] = *(const f4*)&Wlt[kk][tx * 8];
      *(f4*)&w8[4] = *(const f4*)&Wlt[kk][tx * 8 + 4];
#pragma unroll
      for (int mi = 0; mi < 8; mi++) {
#pragma unroll
        for (int ni = 0; ni < 8; ni++)
          acc[mi][ni] = fmaf(a[mi], w8[ni], acc[mi][ni]);
      }
    }
  }
#pragma unroll
  for (int mi = 0; mi < 8; mi++) {
    const size_t m = (size_t)(m0 + ty * 8 + mi);
#pragma unroll
    for (int nj = 0; nj < 2; nj++) {
      const int n = n0 + tx * 8 + nj * 4;
      f4 v;
      v[0] = acc[mi][nj * 4 + 0] + bias[n + 0];
      v[1] = acc[mi][nj * 4 + 1] + bias[n + 1];
      v[2] = acc[mi][nj * 4 + 2] + bias[n + 2];
      v[3] = acc[mi][nj * 4 + 3] + bias[n + 3];
      *(f4*)&o0[m * 512 + n] = v;
    }
  }
}

// ---------------- fp32 flash attention ----------------
// grid (S/64, B*H); Qt/Kt: [B,H,HD,S]; Vf: [B,H,S,HD]; O: [S,B,D]
__global__ __launch_bounds__(256, 3) void k_attn(const float* __restrict__ Qt,
                                                 const float* __restrict__ Kt,
                                                 const float* __restrict__ Vf,
                                                 float* __restrict__ O) {
  const int q0 = blockIdx.x * 64;
  const int bh = blockIdx.y;
  const int b = bh >> 3, h = bh & 7;
  const float* Qh = Qt + (size_t)bh * (HDIM * S_LEN);
  const float* Kh = Kt + (size_t)bh * (HDIM * S_LEN);
  const float* Vh = Vf + (size_t)bh * (S_LEN * HDIM);
  __shared__ float Ql[64][64];
  __shared__ float KP[64][68];   // K [hd][k] / P [k][q] overlay
  __shared__ float Vl[64][64];
  const int tid = threadIdx.x, tx = tid & 15, ty = tid >> 4;
#pragma unroll
  for (int i = 0; i < 4; i++) {
    const int c = tid + i * 256;
    const int r = c >> 4, j = (c & 15) << 2;
    *(f4*)&Ql[r][j] = *(const f4*)&Qh[(size_t)r * S_LEN + q0 + j];
  }
  f4 kr[4], vr[4];
#pragma unroll
  for (int i = 0; i < 4; i++) {
    const int c = tid + i * 256;
    const int r = c >> 4, j = (c & 15) << 2;
    kr[i] = *(const f4*)&Kh[(size_t)r * S_LEN + j];
    vr[i] = *(const f4*)&Vh[(size_t)r * HDIM + j];
  }
  float m_[4], l_[4], o_[4][4];
#pragma unroll
  for (int r = 0; r < 4; r++) {
    m_[r] = -1e30f; l_[r] = 0.f;
#pragma unroll
    for (int c = 0; c < 4; c++) o_[r][c] = 0.f;
  }
  for (int kt = 0; kt < 16; kt++) {
#pragma unroll
    for (int i = 0; i < 4; i++) {
      const int c = tid + i * 256;
      const int r = c >> 4, j = (c & 15) << 2;
      *(f4*)&KP[r][j] = kr[i];
      *(f4*)&Vl[r][j] = vr[i];
    }
    __syncthreads();
    if (kt < 15) {
      const int s0n = (kt + 1) * 64;
#pragma unroll
      for (int i = 0; i < 4; i++) {
        const int c = tid + i * 256;
        const int r = c >> 4, j = (c & 15) << 2;
        kr[i] = *(const f4*)&Kh[(size_t)r * S_LEN + s0n + j];
        vr[i] = *(const f4*)&Vh[(size_t)(s0n + r) * HDIM + j];
      }
    }
    float sc[4][4];
#pragma unroll
    for (int r = 0; r < 4; r++) {
#pragma unroll
      for (int c = 0; c < 4; c++) sc[r][c] = 0.f;
    }
#pragma unroll 2
    for (int d = 0; d < 64; d += 2) {
      f4 aq0 = *(const f4*)&Ql[d][ty * 4];
      f4 bk0 = *(const f4*)&KP[d][tx * 4];
      f4 aq1 = *(const f4*)&Ql[d + 1][ty * 4];
      f4 bk1 = *(const f4*)&KP[d + 1][tx * 4];
#pragma unroll
      for (int r = 0; r < 4; r++) {
#pragma unroll
        for (int c = 0; c < 4; c++) {
          sc[r][c] = fmaf(aq0[r], bk0[c], sc[r][c]);
          sc[r][c] = fmaf(aq1[r], bk1[c], sc[r][c]);
        }
      }
    }
    float esc[4], rs[4];
#pragma unroll
    for (int r = 0; r < 4; r++) {
      float tm = fmaxf(fmaxf(sc[r][0], sc[r][1]), fmaxf(sc[r][2], sc[r][3]));
#pragma unroll
      for (int d = 1; d < 16; d <<= 1) tm = fmaxf(tm, __shfl_xor(tm, d));
      const float mn = fmaxf(m_[r], tm);
      esc[r] = __expf(m_[r] - mn);
      m_[r] = mn;
      rs[r] = 0.f;
    }
#pragma unroll
    for (int r = 0; r < 4; r++) {
#pragma unroll
      for (int c = 0; c < 4; c++) {
        const float p = __expf(sc[r][c] - m_[r]);
        rs[r] += p;
        sc[r][c] = p;
      }
    }
#pragma unroll
    for (int r = 0; r < 4; r++) {
#pragma unroll
      for (int d = 1; d < 16; d <<= 1) rs[r] += __shfl_xor(rs[r], d);
      l_[r] = l_[r] * esc[r] + rs[r];
#pragma unroll
      for (int c = 0; c < 4; c++) o_[r][c] *= esc[r];
    }
    __syncthreads();
#pragma unroll
    for (int r = 0; r < 4; r++) {
#pragma unroll
      for (int c = 0; c < 4; c++) KP[tx * 4 + c][ty * 4 + r] = sc[r][c];
    }
    __syncthreads();
#pragma unroll 2
    for (int k = 0; k < 64; k += 2) {
      f4 ap0 = *(const f4*)&KP[k][ty * 4];
      f4 av0 = *(const f4*)&Vl[k][tx * 4];
      f4 ap1 = *(const f4*)&KP[k + 1][ty * 4];
      f4 av1 = *(const f4*)&Vl[k + 1][tx * 4];
#pragma unroll
      for (int r = 0; r < 4; r++) {
#pragma unroll
        for (int c = 0; c < 4; c++) {
          o_[r][c] = fmaf(ap0[r], av0[c], o_[r][c]);
          o_[r][c] = fmaf(ap1[r], av1[c], o_[r][c]);
        }
      }
    }
    __syncthreads();
  }
#pragma unroll
  for (int r = 0; r < 4; r++) {
    const float inv = 1.f / l_[r];
    const int srow = q0 + ty * 4 + r;
    f4 v;
    v[0] = o_[r][0] * inv; v[1] = o_[r][1] * inv;
    v[2] = o_[r][2] * inv; v[3] = o_[r][3] * inv;
    *(f4*)&O[((size_t)srow * BATCH + b) * DIM + h * HDIM + tx * 4] = v;
  }
}

// ---------------- layernorm: x = LN(src + proj)*g + b -> out ----------------
__global__ __launch_bounds__(256) void k_ln(const float* __restrict__ src,
                                            const float* __restrict__ proj,
                                            const float* __restrict__ g,
                                            const float* __restrict__ bt,
                                            float* __restrict__ xout) {
  const int wid = threadIdx.x >> 6, lane = threadIdx.x & 63;
  const int tok = blockIdx.x * 4 + wid;
  const size_t base = (size_t)tok * DIM + lane * 8;
  f4 a0 = *(const f4*)&src[base],  a1 = *(const f4*)&src[base + 4];
  f4 p0 = *(const f4*)&proj[base], p1 = *(const f4*)&proj[base + 4];
  float x[8];
  x[0] = a0[0] + p0[0]; x[1] = a0[1] + p0[1]; x[2] = a0[2] + p0[2]; x[3] = a0[3] + p0[3];
  x[4] = a1[0] + p1[0]; x[5] = a1[1] + p1[1]; x[6] = a1[2] + p1[2]; x[7] = a1[3] + p1[3];
  float s = 0.f, sq = 0.f;
#pragma unroll
  for (int j = 0; j < 8; j++) { s += x[j]; sq = fmaf(x[j], x[j], sq); }
#pragma unroll
  for (int d = 1; d < 64; d <<= 1) { s += __shfl_xor(s, d); sq += __shfl_xor(sq, d); }
  const float mean = s * (1.f / 512.f);
  const float var = sq * (1.f / 512.f) - mean * mean;
  const float rstd = 1.f / sqrtf(var + 1e-5f);
  const int ci = lane * 8;
  f4 o0v, o1v;
#pragma unroll
  for (int j = 0; j < 4; j++) o0v[j] = (x[j] - mean) * rstd * g[ci + j] + bt[ci + j];
#pragma unroll
  for (int j = 0; j < 4; j++) o1v[j] = (x[4 + j] - mean) * rstd * g[ci + 4 + j] + bt[ci + 4 + j];
  *(f4*)&xout[base] = o0v;
  *(f4*)&xout[base + 4] = o1v;
}

// ---------------- gate: logits, top-2, softmax, counts ----------------
__global__ __launch_bounds__(256) void k_gate(const float* __restrict__ x,
                                              const float* __restrict__ gw,
                                              const float* __restrict__ gb,
                                              int* __restrict__ topi,
                                              float* __restrict__ topw,
                                              int* __restrict__ counts) {
  const int wid = threadIdx.x >> 6, lane = threadIdx.x & 63;
  const int tok = blockIdx.x * 4 + wid;
  const size_t base = (size_t)tok * DIM + lane * 8;
  f4 x0 = *(const f4*)&x[base], x1 = *(const f4*)&x[base + 4];
  float best = -1e30f, sec = -1e30f;
  int bi = 0, si = 0;
  for (int e = 0; e < NE; e++) {
    const float* w = gw + (size_t)e * DIM + lane * 8;
    f4 w0 = *(const f4*)&w[0], w1 = *(const f4*)&w[4];
    float d = x0[0] * w0[0];
    d = fmaf(x0[1], w0[1], d); d = fmaf(x0[2], w0[2], d); d = fmaf(x0[3], w0[3], d);
    d = fmaf(x1[0], w1[0], d); d = fmaf(x1[1], w1[1], d);
    d = fmaf(x1[2], w1[2], d); d = fmaf(x1[3], w1[3], d);
#pragma unroll
    for (int dd = 1; dd < 64; dd <<= 1) d += __shfl_xor(d, dd);
    d += gb[e];
    if (d > best) { sec = best; si = bi; best = d; bi = e; }
    else if (d > sec) { sec = d; si = e; }
  }
  if (lane == 0) {
    const float e1 = expf(sec - best);
    const float inv = 1.f / (1.f + e1);
    topi[2 * tok] = bi;  topi[2 * tok + 1] = si;
    topw[2 * tok] = inv; topw[2 * tok + 1] = e1 * inv;
    atomicAdd(&counts[bi], 1);
    atomicAdd(&counts[si], 1);
  }
}

__global__ void k_offsets(const int* __restrict__ counts,
                          int* __restrict__ off_pad, int* __restrict__ cursor) {
  if (threadIdx.x == 0) {
    int o = 0;
    off_pad[0] = 0;
    for (int e = 0; e < NE; e++) {
      cursor[e] = 0;
      o += ((counts[e] + BM - 1) / BM) * BM;
      off_pad[e + 1] = o;
    }
  }
}

// one wave per (token, k) assignment: claim slot + gather row as bf16
__global__ __launch_bounds__(256) void k_scatter(const float* __restrict__ x,
                                                 const int* __restrict__ topi,
                                                 const float* __restrict__ topw,
                                                 const int* __restrict__ off_pad,
                                                 int* __restrict__ cursor,
                                                 int* __restrict__ slotTok,
                                                 float* __restrict__ slotW,
                                                 unsigned short* __restrict__ Xg) {
  const int wid = threadIdx.x >> 6, lane = threadIdx.x & 63;
  const int a = blockIdx.x * 4 + wid;   // [0, 32768)
  const int t = a >> 1;
  const int e = topi[a];
  int pos = 0;
  if (lane == 0) {
    pos = off_pad[e] + atomicAdd(&cursor[e], 1);
    slotTok[pos] = t;
    slotW[pos] = topw[a];
  }
  pos = __shfl(pos, 0);
  const size_t sb = (size_t)t * DIM + lane * 8;
  f4 v0 = *(const f4*)&x[sb], v1 = *(const f4*)&x[sb + 4];
  u16x4 h0, h1;
  h0[0] = f2bf(v0[0]); h0[1] = f2bf(v0[1]); h0[2] = f2bf(v0[2]); h0[3] = f2bf(v0[3]);
  h1[0] = f2bf(v1[0]); h1[1] = f2bf(v1[1]); h1[2] = f2bf(v1[2]); h1[3] = f2bf(v1[3]);
  *(u16x4*)&Xg[(size_t)pos * DIM + lane * 8] = h0;
  *(u16x4*)&Xg[(size_t)pos * DIM + lane * 8 + 4] = h1;
}

// ---------------- grouped bf16 MFMA GEMM (MoE), T2-swizzled LDS ----------------
__global__ __launch_bounds__(256) void k_gemm_bf16(
    const unsigned short* __restrict__ A, int lda,
    const unsigned short* __restrict__ Wb, size_t westride, int ldw, int wrow0,
    const float* __restrict__ bias, int bstride, int brow0,
    int K, int epi,
    unsigned short* __restrict__ Hout, int ldh,
    float* __restrict__ dout,
    const int* __restrict__ slotTok, const float* __restrict__ slotW,
    const int* __restrict__ off_pad) {
  const int m0 = blockIdx.x * BM;
  if (m0 >= off_pad[NE]) return;
  int e = 0;
  while (off_pad[e + 1] <= m0) e++;
  const unsigned short* W = Wb + (size_t)e * westride;
  const int n0 = blockIdx.y * 128;
  __shared__ unsigned short Al[128 * 64];
  __shared__ unsigned short Bl[128 * 64];
  const int tid = threadIdx.x, lane = tid & 63, wid = tid >> 6;
  const int wm = wid >> 1, wn = wid & 1;
  f32x4 acc[4][4] = {};
  const int srow = wid * 32 + (lane >> 3);
  // G21: linear LDS dest, source col pre-swizzled by row&7 (involution)
  const int scol = (((lane & 7) ^ ((lane >> 3) & 7)) << 3);
  for (int k0 = 0; k0 < K; k0 += 64) {
    const unsigned short* ga = A + (size_t)(m0 + srow) * lda + k0 + scol;
    const unsigned short* gw = W + (size_t)(wrow0 + n0 + srow) * ldw + k0 + scol;
#pragma unroll
    for (int i = 0; i < 4; i++) {
      load_lds16(ga + (size_t)i * 8 * lda, &Al[(wid * 32 + i * 8) * 64]);
      load_lds16(gw + (size_t)i * 8 * ldw, &Bl[(wid * 32 + i * 8) * 64]);
    }
    __syncthreads();
#pragma unroll
    for (int kk = 0; kk < 2; kk++) {
      short8 av[4], bv[4];
      const int ckx = (kk * 4 + (lane >> 4)) ^ (lane & 7);  // swizzled chunk
#pragma unroll
      for (int mi = 0; mi < 4; mi++)
        av[mi] = *(const short8*)&Al[(wm * 64 + mi * 16 + (lane & 15)) * 64 + ckx * 8];
#pragma unroll
      for (int ni = 0; ni < 4; ni++)
        bv[ni] = *(const short8*)&Bl[(wn * 64 + ni * 16 + (lane & 15)) * 64 + ckx * 8];
#pragma unroll
      for (int mi = 0; mi < 4; mi++) {
#pragma unroll
        for (int ni = 0; ni < 4; ni++)
          acc[mi][ni] = __builtin_amdgcn_mfma_f32_16x16x32_bf16(av[mi], bv[ni], acc[mi][ni], 0, 0, 0);
      }
    }
    __syncthreads();
  }
#pragma unroll
  for (int mi = 0; mi < 4; mi++) {
    const int rb = m0 + wm * 64 + mi * 16 + ((lane >> 4) << 2);
#pragma unroll
    for (int ni = 0; ni < 4; ni++) {
      const int n = n0 + wn * 64 + ni * 16 + (lane & 15);
      const float bn = bias ? bias[(size_t)e * bstride + brow0 + n] : 0.f;
      if (epi == 0) {
#pragma unroll
        for (int r = 0; r < 4; r++) {
          float v = acc[mi][ni][r] + bn;
          v = fmaxf(v, 0.f);
          Hout[(size_t)(rb + r) * ldh + n] = f2bf(v);
        }
      } else {
#pragma unroll
        for (int r = 0; r < 4; r++) {
          const int tok = slotTok[rb + r];
          if (tok >= 0) {
            const float v = (acc[mi][ni][r] + bn) * slotW[rb + r];
            atomicAdd(&dout[(size_t)tok * DIM + n], v);
          }
        }
      }
    }
  }
}

// ---------------- launch ----------------
extern "C" void kernel_launch(void* const* d_in, const int* in_sizes, int n_in,
                              void* d_out, int out_size, void* d_ws, size_t ws_size,
                              hipStream_t stream) {
  const float* src       = (const float*)d_in[0];
  const float* pos       = (const float*)d_in[1];
  const float* in_proj_w = (const float*)d_in[2];
  const float* in_proj_b = (const float*)d_in[3];
  const float* out_w     = (const float*)d_in[4];
  const float* out_b     = (const float*)d_in[5];
  const float* norm1_g   = (const float*)d_in[6];
  const float* norm1_b   = (const float*)d_in[7];
  const float* gate_w    = (const float*)d_in[8];
  const float* gate_b    = (const float*)d_in[9];
  const float* w1        = (const float*)d_in[10];
  const float* b1        = (const float*)d_in[11];
  const float* w2        = (const float*)d_in[12];
  const float* b2        = (const float*)d_in[13];
  float* out = (float*)d_out;
  char* wsb = (char*)d_ws;

  // ---- lifetime-packed arena (total ~166.5 MiB, unchanged) ----
  float* Qt = (float*)(wsb + 0);           // [B,H,HD,S] 32 MiB, dead after attn
  float* Kt = (float*)(wsb + 33554432);    // 32 MiB, dead after attn
  float* Vf = (float*)(wsb + 67108864);    // [B,H,S,HD] 32 MiB, dead after attn
  float* ob = (float*)(wsb + 100663296);   // attn out [S,B,D] 32 MiB, dead after out-proj
  float* proj = (float*)(wsb + 0);                          // over Qt, dead after LN
  unsigned short* w1b = (unsigned short*)(wsb + 0);         // over proj, 32 MiB
  unsigned short* w2b = (unsigned short*)(wsb + 33554432);  // over Kt, 32 MiB
  unsigned short* Xg  = (unsigned short*)(wsb + 67108864);  // over Vf+ob-head, 34 MiB
  unsigned short* Hb  = (unsigned short*)(wsb + 102760448); // over ob-tail, 68 MiB
  // in_proj hi/lo splits: live only phase 1, placed in Hb-region hole past ob end
  unsigned short* wih = (unsigned short*)(wsb + 134217728); // 1.5 MiB
  unsigned short* wil = (unsigned short*)(wsb + 135790592); // 1.5 MiB
  char* smallb = wsb + 174063616;
  int*   topi    = (int*)  (smallb + 0);
  float* topw    = (float*)(smallb + 131072);
  int*   slotTok = (int*)  (smallb + 262144);
  float* slotW   = (float*)(smallb + 401408);
  int*   counts  = (int*)  (smallb + 540672);
  int*   off_pad = (int*)  (smallb + 540736);
  int*   cursor  = (int*)  (smallb + 540864);

  // 1. routing init + weight split
  k_init<<<(CAP + 255) / 256, 256, 0, stream>>>(slotTok, slotW, counts);
  k_split_w<<<768, 256, 0, stream>>>(in_proj_w, wih, wil, (size_t)1536 * 512);
  // 2. Q/K projection (split-bf16 MFMA, fused src+pos) -> Qt/Kt [B,H,HD,S]
  k_gemm_split<<<dim3(128, 8), 256, 0, stream>>>(src, pos, wih, wil, in_proj_b, 0, Qt, Kt);
  // 3. V projection -> Vf [B,H,S,HD]
  k_gemm_split<<<dim3(128, 4), 256, 0, stream>>>(src, nullptr, wih + (size_t)1024 * 512,
                                                 wil + (size_t)1024 * 512, in_proj_b + 1024,
                                                 1, Vf, nullptr);
  // 4. flash attention (fp32) -> ob [S,B,D]
  k_attn<<<dim3(16, 128), 256, 0, stream>>>(Qt, Kt, Vf, ob);
  // 5. w2 -> bf16 (Kt dead)
  k_cvt_bf16<<<2048, 256, 0, stream>>>(w2, w2b, (size_t)NE * DIM * DFF);
  // 6. output projection (fp32 vector — gate-critical path) -> proj (over Qt)
  k_gemm_f32<<<dim3(128, 4), 256, 0, stream>>>(ob, out_w, out_b, 512, proj);
  // 7. layernorm(src + proj) -> d_out (= x)
  k_ln<<<4096, 256, 0, stream>>>(src, proj, norm1_g, norm1_b, out);
  // 8. w1 -> bf16 (proj dead)
  k_cvt_bf16<<<2048, 256, 0, stream>>>(w1, w1b, (size_t)NE * DFF * DIM);
  // 9. gate logits + top2 + counts
  k_gate<<<4096, 256, 0, stream>>>(out, gate_w, gate_b, topi, topw, counts);
  // 10. padded segment offsets
  k_offsets<<<1, 64, 0, stream>>>(counts, off_pad, cursor);
  // 11. zero gathered-token buffer
  k_zero<<<2048, 256, 0, stream>>>((u32x4*)Xg, (size_t)CAP * DIM * 2 / 16);
  // 12. scatter assignments + gather token rows as bf16
  k_scatter<<<8192, 256, 0, stream>>>(out, topi, topw, off_pad, cursor, slotTok, slotW, Xg);
  // 13. MoE, DFF halved
  for (int p = 0; p < 2; ++p) {
    k_gemm_bf16<<<dim3(CAP / BM, 8), 256, 0, stream>>>(
        Xg, DIM, w1b, (size_t)DFF * DIM, DIM, p * 1024,
        b1, DFF, p * 1024, DIM, 0, Hb, 1024,
        nullptr, nullptr, nullptr, off_pad);
    k_gemm_bf16<<<dim3(CAP / BM, 4), 256, 0, stream>>>(
        Hb, 1024, w2b + (size_t)p * 1024, (size_t)DIM * DFF, DFF, 0,
        (p == 0 ? b2 : nullptr), DIM, 0, 1024, 1, nullptr, 0,
        out, slotTok, slotW, off_pad);
  }
}

// Round 5
// 1834.842 us; speedup vs baseline: 1.3700x; 1.1465x over previous
//
#include <hip/hip_runtime.h>
#include <hip/hip_bf16.h>

// ---------------- types ----------------
typedef float f4 __attribute__((ext_vector_type(4)));
typedef float f32x4 __attribute__((ext_vector_type(4)));
typedef short short8 __attribute__((ext_vector_type(8)));
typedef unsigned short u16x4 __attribute__((ext_vector_type(4)));
typedef unsigned short u16x8 __attribute__((ext_vector_type(8)));
typedef unsigned int u32x4 __attribute__((ext_vector_type(4)));

// ---------------- problem constants ----------------
#define S_LEN 1024
#define BATCH 16
#define DIM   512
#define NH    8
#define HDIM  64
#define NE    16
#define DFF   2048
#define T_TOK 16384   // S*B
#define CAP   34816   // 32768 assignments + per-expert padding to BM
#define BM    128

__device__ __forceinline__ unsigned short f2bf(float f) {
  union { float f; unsigned u; } v; v.f = f;
  unsigned r = v.u + 0x7fffu + ((v.u >> 16) & 1u);  // RTNE
  return (unsigned short)(r >> 16);
}
__device__ __forceinline__ float bf2f(unsigned short h) {
  union { unsigned u; float f; } v; v.u = ((unsigned)h) << 16;
  return v.f;
}

__device__ __forceinline__ void load_lds16(const void* g, void* l) {
  __builtin_amdgcn_global_load_lds(
      (__attribute__((address_space(1))) void*)(void*)g,
      (__attribute__((address_space(3))) void*)l, 16, 0, 0);
}

// ---------------- small utility kernels ----------------
__global__ __launch_bounds__(256) void k_cvt_bf16(const float* __restrict__ in,
                                                  unsigned short* __restrict__ outb,
                                                  size_t n) {
  size_t i = ((size_t)blockIdx.x * 256 + threadIdx.x) * 4;
  size_t stride = (size_t)gridDim.x * 1024;
  for (; i < n; i += stride) {
    f4 v = *(const f4*)&in[i];
    u16x4 o;
    o[0] = f2bf(v[0]); o[1] = f2bf(v[1]); o[2] = f2bf(v[2]); o[3] = f2bf(v[3]);
    *(u16x4*)&outb[i] = o;
  }
}

// split fp32 -> bf16 hi + bf16 lo (lo = round(x - hi))
__global__ __launch_bounds__(256) void k_split_w(const float* __restrict__ in,
                                                 unsigned short* __restrict__ hi,
                                                 unsigned short* __restrict__ lo,
                                                 size_t n) {
  size_t i = ((size_t)blockIdx.x * 256 + threadIdx.x) * 4;
  size_t stride = (size_t)gridDim.x * 1024;
  for (; i < n; i += stride) {
    f4 v = *(const f4*)&in[i];
    u16x4 h, l;
#pragma unroll
    for (int j = 0; j < 4; j++) {
      unsigned short hh = f2bf(v[j]);
      h[j] = hh;
      l[j] = f2bf(v[j] - bf2f(hh));
    }
    *(u16x4*)&hi[i] = h;
    *(u16x4*)&lo[i] = l;
  }
}

__global__ __launch_bounds__(256) void k_init(int* __restrict__ slotTok,
                                              float* __restrict__ slotW,
                                              int* __restrict__ counts) {
  int i = blockIdx.x * 256 + threadIdx.x;
  if (i < CAP) { slotTok[i] = -1; slotW[i] = 0.f; }
  if (i < NE) counts[i] = 0;
}

__global__ __launch_bounds__(256) void k_zero(u32x4* __restrict__ p, size_t n16) {
  size_t i = (size_t)blockIdx.x * 256 + threadIdx.x;
  size_t stride = (size_t)gridDim.x * 256;
  u32x4 z = {0u, 0u, 0u, 0u};
  for (; i < n16; i += stride) p[i] = z;
}

// ---------------- split-bf16 MFMA GEMM (fp32-accurate via hi/lo) ----------------
// C = (A [+A2])[M,512] * W[N,512]^T + bias, W pre-split into Wh/Wl bf16.
// 128x128 tile, BK=32, 2x2 waves, 4x4 16x16x32 frags, 3 MFMAs per frag.
// epi 0: n<512 -> Q*0.125 split-> (o0h,o0l) [B,H,S,HD]; n>=512 -> K split-> (o1h,o1l) [B,H,S,HD]
// epi 1: V split-> (o0h,o0l) [B,H,HD,S]
__global__ __launch_bounds__(256, 2) void k_gemm_split(
    const float* __restrict__ A, const float* __restrict__ A2,
    const unsigned short* __restrict__ Wh, const unsigned short* __restrict__ Wl,
    const float* __restrict__ bias, int epi,
    unsigned short* __restrict__ o0h, unsigned short* __restrict__ o0l,
    unsigned short* __restrict__ o1h, unsigned short* __restrict__ o1l) {
  __shared__ unsigned short AhL[128 * 32];
  __shared__ unsigned short AlL[128 * 32];
  __shared__ unsigned short WhL[128 * 32];
  __shared__ unsigned short WlL[128 * 32];
  const int tid = threadIdx.x, lane = tid & 63, wid = tid >> 6;
  const int wm = wid >> 1, wn = wid & 1;
  const int m0 = blockIdx.x * 128, n0 = blockIdx.y * 128;
  const int row = tid >> 1, half = tid & 1;      // A staging: 2 threads/row
  const int xr = (row >> 1) & 3;                 // A-side write swizzle
  f32x4 acc[4][4] = {};
  f4 ar[4];
#pragma unroll
  for (int j = 0; j < 4; j++) {
    const size_t aoff = (size_t)(m0 + row) * 512 + half * 16 + j * 4;
    ar[j] = *(const f4*)&A[aoff];
    if (A2) { f4 v2 = *(const f4*)&A2[aoff]; ar[j] += v2; }
  }
  for (int k0 = 0; k0 < 512; k0 += 32) {
    __syncthreads();
    u16x8 hi8[2], lo8[2];
#pragma unroll
    for (int j = 0; j < 16; j++) {
      const float x = ar[j >> 2][j & 3];
      const unsigned short h = f2bf(x);
      hi8[j >> 3][j & 7] = h;
      lo8[j >> 3][j & 7] = f2bf(x - bf2f(h));
    }
    const int c0 = half * 2;
    *(u16x8*)&AhL[row * 32 + (((c0 + 0) ^ xr) << 3)] = hi8[0];
    *(u16x8*)&AhL[row * 32 + (((c0 + 1) ^ xr) << 3)] = hi8[1];
    *(u16x8*)&AlL[row * 32 + (((c0 + 0) ^ xr) << 3)] = lo8[0];
    *(u16x8*)&AlL[row * 32 + (((c0 + 1) ^ xr) << 3)] = lo8[1];
#pragma unroll
    for (int i = 0; i < 2; i++) {
      const int rowW = i * 64 + wid * 16 + (lane >> 2);
      const int clog = (lane & 3) ^ ((rowW >> 1) & 3);
      const size_t woff = (size_t)(n0 + rowW) * 512 + k0 + (clog << 3);
      load_lds16(Wh + woff, &WhL[i * 2048 + wid * 512]);
      load_lds16(Wl + woff, &WlL[i * 2048 + wid * 512]);
    }
    __syncthreads();
    if (k0 + 32 < 512) {
#pragma unroll
      for (int j = 0; j < 4; j++) {
        const size_t aoff = (size_t)(m0 + row) * 512 + k0 + 32 + half * 16 + j * 4;
        ar[j] = *(const f4*)&A[aoff];
        if (A2) { f4 v2 = *(const f4*)&A2[aoff]; ar[j] += v2; }
      }
    }
    const int l15 = lane & 15, lk = lane >> 4;
    const int xa = (l15 >> 1) & 3;
    short8 avh[4], avl[4], bvh[4], bvl[4];
#pragma unroll
    for (int mi = 0; mi < 4; mi++) {
      const int mr = wm * 64 + mi * 16 + l15;
      avh[mi] = *(const short8*)&AhL[mr * 32 + ((lk ^ xa) << 3)];
      avl[mi] = *(const short8*)&AlL[mr * 32 + ((lk ^ xa) << 3)];
    }
#pragma unroll
    for (int ni = 0; ni < 4; ni++) {
      const int nr = wn * 64 + ni * 16 + l15;
      bvh[ni] = *(const short8*)&WhL[nr * 32 + ((lk ^ xa) << 3)];
      bvl[ni] = *(const short8*)&WlL[nr * 32 + ((lk ^ xa) << 3)];
    }
#pragma unroll
    for (int mi = 0; mi < 4; mi++) {
#pragma unroll
      for (int ni = 0; ni < 4; ni++) {
        acc[mi][ni] = __builtin_amdgcn_mfma_f32_16x16x32_bf16(avh[mi], bvh[ni], acc[mi][ni], 0, 0, 0);
        acc[mi][ni] = __builtin_amdgcn_mfma_f32_16x16x32_bf16(avh[mi], bvl[ni], acc[mi][ni], 0, 0, 0);
        acc[mi][ni] = __builtin_amdgcn_mfma_f32_16x16x32_bf16(avl[mi], bvh[ni], acc[mi][ni], 0, 0, 0);
      }
    }
  }
  // epilogue: split-store to hi/lo planes
#pragma unroll
  for (int mi = 0; mi < 4; mi++) {
    const int rb = m0 + wm * 64 + mi * 16 + ((lane >> 4) << 2);
#pragma unroll
    for (int ni = 0; ni < 4; ni++) {
      const int n = n0 + wn * 64 + ni * 16 + (lane & 15);
      const float bn = bias[n];
#pragma unroll
      for (int r = 0; r < 4; r++) {
        const int m = rb + r;
        const int bidx = m & 15, ss = m >> 4;    // token = s*B + b
        float v = acc[mi][ni][r] + bn;
        if (epi == 0) {
          if (n < 512) {
            v *= 0.125f;
            const size_t off = ((size_t)(bidx * NH + (n >> 6)) * S_LEN + ss) * HDIM + (n & 63);
            const unsigned short hh = f2bf(v);
            o0h[off] = hh; o0l[off] = f2bf(v - bf2f(hh));
          } else {
            const int n2 = n - 512;
            const size_t off = ((size_t)(bidx * NH + (n2 >> 6)) * S_LEN + ss) * HDIM + (n2 & 63);
            const unsigned short hh = f2bf(v);
            o1h[off] = hh; o1l[off] = f2bf(v - bf2f(hh));
          }
        } else {  // V: [B,H,HD,S]
          const size_t off = ((size_t)(bidx * NH + (n >> 6)) * HDIM + (n & 63)) * S_LEN + ss;
          const unsigned short hh = f2bf(v);
          o0h[off] = hh; o0l[off] = f2bf(v - bf2f(hh));
        }
      }
    }
  }
}

// ---------------- fp32 GEMM (out-proj only): C = A[M,K]*W[N,K]^T + bias ----------------
__global__ __launch_bounds__(256, 3) void k_gemm_f32(
    const float* __restrict__ A, const float* __restrict__ W,
    const float* __restrict__ bias, int K,
    float* __restrict__ o0) {
  __shared__ float Alt[32][132];
  __shared__ float Wlt[32][132];
  const int tid = threadIdx.x, tx = tid & 15, ty = tid >> 4;
  const int m0 = blockIdx.x * 128, n0 = blockIdx.y * 128;
  float acc[8][8];
#pragma unroll
  for (int i = 0; i < 8; i++) {
#pragma unroll
    for (int j = 0; j < 8; j++) acc[i][j] = 0.f;
  }
  f4 ar[4], wr[4];
#pragma unroll
  for (int i = 0; i < 4; i++) {
    const int c = tid + i * 256;
    const int r = c >> 3, j = (c & 7) * 4;
    ar[i] = *(const f4*)&A[(size_t)(m0 + r) * K + j];
    wr[i] = *(const f4*)&W[(size_t)(n0 + r) * K + j];
  }
  for (int k0 = 0; k0 < K; k0 += 32) {
    __syncthreads();
#pragma unroll
    for (int i = 0; i < 4; i++) {
      const int c = tid + i * 256;
      const int r = c >> 3, j = (c & 7) * 4;
      Alt[j + 0][r] = ar[i][0]; Alt[j + 1][r] = ar[i][1];
      Alt[j + 2][r] = ar[i][2]; Alt[j + 3][r] = ar[i][3];
      Wlt[j + 0][r] = wr[i][0]; Wlt[j + 1][r] = wr[i][1];
      Wlt[j + 2][r] = wr[i][2]; Wlt[j + 3][r] = wr[i][3];
    }
    __syncthreads();
    if (k0 + 32 < K) {
#pragma unroll
      for (int i = 0; i < 4; i++) {
        const int c = tid + i * 256;
        const int r = c >> 3, j = (c & 7) * 4;
        ar[i] = *(const f4*)&A[(size_t)(m0 + r) * K + k0 + 32 + j];
        wr[i] = *(const f4*)&W[(size_t)(n0 + r) * K + k0 + 32 + j];
      }
    }
#pragma unroll 4
    for (int kk = 0; kk < 32; kk++) {
      float a[8], w8[8];
      *(f4*)&a[0]  = *(const f4*)&Alt[kk][ty * 8];
      *(f4*)&a[4]  = *(const f4*)&Alt[kk][ty * 8 + 4];
      *(f4*)&w8[0] = *(const f4*)&Wlt[kk][tx * 8];
      *(f4*)&w8[4] = *(const f4*)&Wlt[kk][tx * 8 + 4];
#pragma unroll
      for (int mi = 0; mi < 8; mi++) {
#pragma unroll
        for (int ni = 0; ni < 8; ni++)
          acc[mi][ni] = fmaf(a[mi], w8[ni], acc[mi][ni]);
      }
    }
  }
#pragma unroll
  for (int mi = 0; mi < 8; mi++) {
    const size_t m = (size_t)(m0 + ty * 8 + mi);
#pragma unroll
    for (int nj = 0; nj < 2; nj++) {
      const int n = n0 + tx * 8 + nj * 4;
      f4 v;
      v[0] = acc[mi][nj * 4 + 0] + bias[n + 0];
      v[1] = acc[mi][nj * 4 + 1] + bias[n + 1];
      v[2] = acc[mi][nj * 4 + 2] + bias[n + 2];
      v[3] = acc[mi][nj * 4 + 3] + bias[n + 3];
      *(f4*)&o0[m * 512 + n] = v;
    }
  }
}

// ---------------- split-bf16 MFMA flash attention ----------------
// grid (S/64, B*H), 4 waves; Q,K: [B,H,S,HD] hi/lo planes; V: [B,H,HD,S] hi/lo.
// Wave w owns q-rows q0+16w..+15. QK^T and PV each 24 MFMAs/wave/tile (3-term split).
__global__ __launch_bounds__(256, 2) void k_attn(
    const unsigned short* __restrict__ Qhp, const unsigned short* __restrict__ Qlp,
    const unsigned short* __restrict__ Khp, const unsigned short* __restrict__ Klp,
    const unsigned short* __restrict__ Vhp, const unsigned short* __restrict__ Vlp,
    float* __restrict__ O) {
  const int q0 = blockIdx.x * 64;
  const int bh = blockIdx.y;
  const int b = bh >> 3, h = bh & 7;
  const size_t base = (size_t)bh * (S_LEN * HDIM);   // same extent for QK and V planes
  __shared__ unsigned short KhL[64][72], KlL[64][72];
  __shared__ unsigned short VhL[64][72], VlL[64][72];
  __shared__ float Pl[64][68];
  const int tid = threadIdx.x, lane = tid & 63, w = tid >> 6;
  const int l15 = lane & 15, lq = lane >> 4;
  // Q fragments (held across all tiles): rows q0+16w+l15, d-chunks {0,32}+lq*8
  short8 qh[2], ql[2];
  {
    const size_t qoff = base + (size_t)(q0 + 16 * w + l15) * HDIM + lq * 8;
    qh[0] = *(const short8*)&Qhp[qoff];
    ql[0] = *(const short8*)&Qlp[qoff];
    qh[1] = *(const short8*)&Qhp[qoff + 32];
    ql[1] = *(const short8*)&Qlp[qoff + 32];
  }
  // staging mapping: thread -> (row sr, col-quarter sq)
  const int sr = tid >> 2, sq = (tid & 3) * 16;
  u16x8 krh[2], krl[2], vrh[2], vrl[2];
  {
    const size_t ko = base + (size_t)sr * HDIM + sq;            // K row = key s0+sr
    krh[0] = *(const u16x8*)&Khp[ko]; krh[1] = *(const u16x8*)&Khp[ko + 8];
    krl[0] = *(const u16x8*)&Klp[ko]; krl[1] = *(const u16x8*)&Klp[ko + 8];
    const size_t vo = base + (size_t)sr * S_LEN + sq;           // V row = d, col = key
    vrh[0] = *(const u16x8*)&Vhp[vo]; vrh[1] = *(const u16x8*)&Vhp[vo + 8];
    vrl[0] = *(const u16x8*)&Vlp[vo]; vrl[1] = *(const u16x8*)&Vlp[vo + 8];
  }
  float m_[4], l_[4];
  f32x4 acc[4] = {};
#pragma unroll
  for (int r = 0; r < 4; r++) { m_[r] = -1e30f; l_[r] = 0.f; }

  for (int kt = 0; kt < 16; kt++) {
    // write staged tile (loaded last iter) to LDS
    *(u16x8*)&KhL[sr][sq + 0] = krh[0]; *(u16x8*)&KhL[sr][sq + 8] = krh[1];
    *(u16x8*)&KlL[sr][sq + 0] = krl[0]; *(u16x8*)&KlL[sr][sq + 8] = krl[1];
    *(u16x8*)&VhL[sr][sq + 0] = vrh[0]; *(u16x8*)&VhL[sr][sq + 8] = vrh[1];
    *(u16x8*)&VlL[sr][sq + 0] = vrl[0]; *(u16x8*)&VlL[sr][sq + 8] = vrl[1];
    __syncthreads();
    // T14: prefetch next tile (in flight across QK+softmax+PV)
    if (kt < 15) {
      const int s0n = (kt + 1) * 64;
      const size_t ko = base + (size_t)(s0n + sr) * HDIM + sq;
      krh[0] = *(const u16x8*)&Khp[ko]; krh[1] = *(const u16x8*)&Khp[ko + 8];
      krl[0] = *(const u16x8*)&Klp[ko]; krl[1] = *(const u16x8*)&Klp[ko + 8];
      const size_t vo = base + (size_t)sr * S_LEN + s0n + sq;
      vrh[0] = *(const u16x8*)&Vhp[vo]; vrh[1] = *(const u16x8*)&Vhp[vo + 8];
      vrl[0] = *(const u16x8*)&Vlp[vo]; vrl[1] = *(const u16x8*)&Vlp[vo + 8];
    }
    // ---- QK^T: sc[n][r] = S[16w+4lq+r][16n+l15] ----
    f32x4 sc[4] = {};
#pragma unroll
    for (int c = 0; c < 2; c++) {
      short8 kfh[4], kfl[4];
#pragma unroll
      for (int n = 0; n < 4; n++) {
        kfh[n] = *(const short8*)&KhL[16 * n + l15][c * 32 + lq * 8];
        kfl[n] = *(const short8*)&KlL[16 * n + l15][c * 32 + lq * 8];
      }
#pragma unroll
      for (int n = 0; n < 4; n++) {
        sc[n] = __builtin_amdgcn_mfma_f32_16x16x32_bf16(qh[c], kfh[n], sc[n], 0, 0, 0);
        sc[n] = __builtin_amdgcn_mfma_f32_16x16x32_bf16(qh[c], kfl[n], sc[n], 0, 0, 0);
        sc[n] = __builtin_amdgcn_mfma_f32_16x16x32_bf16(ql[c], kfh[n], sc[n], 0, 0, 0);
      }
    }
    // ---- online softmax (16-lane row groups) ----
    float esc[4], rs[4];
#pragma unroll
    for (int r = 0; r < 4; r++) {
      float t = fmaxf(fmaxf(sc[0][r], sc[1][r]), fmaxf(sc[2][r], sc[3][r]));
#pragma unroll
      for (int d = 1; d < 16; d <<= 1) t = fmaxf(t, __shfl_xor(t, d));
      const float mn = fmaxf(m_[r], t);
      esc[r] = __expf(m_[r] - mn);
      m_[r] = mn;
      rs[r] = 0.f;
    }
#pragma unroll
    for (int n = 0; n < 4; n++) {
#pragma unroll
      for (int r = 0; r < 4; r++) {
        const float p = __expf(sc[n][r] - m_[r]);
        rs[r] += p;
        sc[n][r] = p;
      }
    }
#pragma unroll
    for (int r = 0; r < 4; r++) {
#pragma unroll
      for (int d = 1; d < 16; d <<= 1) rs[r] += __shfl_xor(rs[r], d);
      l_[r] = l_[r] * esc[r] + rs[r];
      acc[0][r] *= esc[r]; acc[1][r] *= esc[r];
      acc[2][r] *= esc[r]; acc[3][r] *= esc[r];
    }
    // write P (wave-private rows 16w..16w+15; same-wave readback, compiler orders)
#pragma unroll
    for (int n = 0; n < 4; n++) {
#pragma unroll
      for (int r = 0; r < 4; r++)
        Pl[16 * w + 4 * lq + r][16 * n + l15] = sc[n][r];
    }
    // ---- PV: acc[n][r] += P[row][k] * V[16n+l15][k] ----
#pragma unroll
    for (int c = 0; c < 2; c++) {
      f4 p0 = *(const f4*)&Pl[16 * w + l15][c * 32 + lq * 8];
      f4 p1 = *(const f4*)&Pl[16 * w + l15][c * 32 + lq * 8 + 4];
      short8 ph, pl_;
#pragma unroll
      for (int j = 0; j < 8; j++) {
        const float x = (j < 4) ? p0[j] : p1[j - 4];
        const unsigned short hh = f2bf(x);
        ph[j] = (short)hh;
        pl_[j] = (short)f2bf(x - bf2f(hh));
      }
      short8 vfh[4], vfl[4];
#pragma unroll
      for (int n = 0; n < 4; n++) {
        vfh[n] = *(const short8*)&VhL[16 * n + l15][c * 32 + lq * 8];
        vfl[n] = *(const short8*)&VlL[16 * n + l15][c * 32 + lq * 8];
      }
#pragma unroll
      for (int n = 0; n < 4; n++) {
        acc[n] = __builtin_amdgcn_mfma_f32_16x16x32_bf16(ph, vfh[n], acc[n], 0, 0, 0);
        acc[n] = __builtin_amdgcn_mfma_f32_16x16x32_bf16(ph, vfl[n], acc[n], 0, 0, 0);
        acc[n] = __builtin_amdgcn_mfma_f32_16x16x32_bf16(pl_, vfh[n], acc[n], 0, 0, 0);
      }
    }
    __syncthreads();   // all K/V/P reads done -> next-iter LDS writes safe
  }
  // epilogue: O[S,B,D]
#pragma unroll
  for (int r = 0; r < 4; r++) {
    const float inv = 1.f / l_[r];
    const int srow = q0 + 16 * w + 4 * lq + r;
    float* orow = &O[((size_t)srow * BATCH + b) * DIM + h * HDIM];
#pragma unroll
    for (int n = 0; n < 4; n++) orow[16 * n + l15] = acc[n][r] * inv;
  }
}

// ---------------- layernorm: x = LN(src + proj)*g + b -> out ----------------
__global__ __launch_bounds__(256) void k_ln(const float* __restrict__ src,
                                            const float* __restrict__ proj,
                                            const float* __restrict__ g,
                                            const float* __restrict__ bt,
                                            float* __restrict__ xout) {
  const int wid = threadIdx.x >> 6, lane = threadIdx.x & 63;
  const int tok = blockIdx.x * 4 + wid;
  const size_t base = (size_t)tok * DIM + lane * 8;
  f4 a0 = *(const f4*)&src[base],  a1 = *(const f4*)&src[base + 4];
  f4 p0 = *(const f4*)&proj[base], p1 = *(const f4*)&proj[base + 4];
  float x[8];
  x[0] = a0[0] + p0[0]; x[1] = a0[1] + p0[1]; x[2] = a0[2] + p0[2]; x[3] = a0[3] + p0[3];
  x[4] = a1[0] + p1[0]; x[5] = a1[1] + p1[1]; x[6] = a1[2] + p1[2]; x[7] = a1[3] + p1[3];
  float s = 0.f, sq = 0.f;
#pragma unroll
  for (int j = 0; j < 8; j++) { s += x[j]; sq = fmaf(x[j], x[j], sq); }
#pragma unroll
  for (int d = 1; d < 64; d <<= 1) { s += __shfl_xor(s, d); sq += __shfl_xor(sq, d); }
  const float mean = s * (1.f / 512.f);
  const float var = sq * (1.f / 512.f) - mean * mean;
  const float rstd = 1.f / sqrtf(var + 1e-5f);
  const int ci = lane * 8;
  f4 o0v, o1v;
#pragma unroll
  for (int j = 0; j < 4; j++) o0v[j] = (x[j] - mean) * rstd * g[ci + j] + bt[ci + j];
#pragma unroll
  for (int j = 0; j < 4; j++) o1v[j] = (x[4 + j] - mean) * rstd * g[ci + 4 + j] + bt[ci + 4 + j];
  *(f4*)&xout[base] = o0v;
  *(f4*)&xout[base + 4] = o1v;
}

// ---------------- gate: logits, top-2, softmax, counts ----------------
__global__ __launch_bounds__(256) void k_gate(const float* __restrict__ x,
                                              const float* __restrict__ gw,
                                              const float* __restrict__ gb,
                                              int* __restrict__ topi,
                                              float* __restrict__ topw,
                                              int* __restrict__ counts) {
  const int wid = threadIdx.x >> 6, lane = threadIdx.x & 63;
  const int tok = blockIdx.x * 4 + wid;
  const size_t base = (size_t)tok * DIM + lane * 8;
  f4 x0 = *(const f4*)&x[base], x1 = *(const f4*)&x[base + 4];
  float best = -1e30f, sec = -1e30f;
  int bi = 0, si = 0;
  for (int e = 0; e < NE; e++) {
    const float* w = gw + (size_t)e * DIM + lane * 8;
    f4 w0 = *(const f4*)&w[0], w1 = *(const f4*)&w[4];
    float d = x0[0] * w0[0];
    d = fmaf(x0[1], w0[1], d); d = fmaf(x0[2], w0[2], d); d = fmaf(x0[3], w0[3], d);
    d = fmaf(x1[0], w1[0], d); d = fmaf(x1[1], w1[1], d);
    d = fmaf(x1[2], w1[2], d); d = fmaf(x1[3], w1[3], d);
#pragma unroll
    for (int dd = 1; dd < 64; dd <<= 1) d += __shfl_xor(d, dd);
    d += gb[e];
    if (d > best) { sec = best; si = bi; best = d; bi = e; }
    else if (d > sec) { sec = d; si = e; }
  }
  if (lane == 0) {
    const float e1 = expf(sec - best);
    const float inv = 1.f / (1.f + e1);
    topi[2 * tok] = bi;  topi[2 * tok + 1] = si;
    topw[2 * tok] = inv; topw[2 * tok + 1] = e1 * inv;
    atomicAdd(&counts[bi], 1);
    atomicAdd(&counts[si], 1);
  }
}

__global__ void k_offsets(const int* __restrict__ counts,
                          int* __restrict__ off_pad, int* __restrict__ cursor) {
  if (threadIdx.x == 0) {
    int o = 0;
    off_pad[0] = 0;
    for (int e = 0; e < NE; e++) {
      cursor[e] = 0;
      o += ((counts[e] + BM - 1) / BM) * BM;
      off_pad[e + 1] = o;
    }
  }
}

// one wave per (token, k) assignment: claim slot + gather row as bf16
__global__ __launch_bounds__(256) void k_scatter(const float* __restrict__ x,
                                                 const int* __restrict__ topi,
                                                 const float* __restrict__ topw,
                                                 const int* __restrict__ off_pad,
                                                 int* __restrict__ cursor,
                                                 int* __restrict__ slotTok,
                                                 float* __restrict__ slotW,
                                                 unsigned short* __restrict__ Xg) {
  const int wid = threadIdx.x >> 6, lane = threadIdx.x & 63;
  const int a = blockIdx.x * 4 + wid;   // [0, 32768)
  const int t = a >> 1;
  const int e = topi[a];
  int pos = 0;
  if (lane == 0) {
    pos = off_pad[e] + atomicAdd(&cursor[e], 1);
    slotTok[pos] = t;
    slotW[pos] = topw[a];
  }
  pos = __shfl(pos, 0);
  const size_t sb = (size_t)t * DIM + lane * 8;
  f4 v0 = *(const f4*)&x[sb], v1 = *(const f4*)&x[sb + 4];
  u16x4 h0, h1;
  h0[0] = f2bf(v0[0]); h0[1] = f2bf(v0[1]); h0[2] = f2bf(v0[2]); h0[3] = f2bf(v0[3]);
  h1[0] = f2bf(v1[0]); h1[1] = f2bf(v1[1]); h1[2] = f2bf(v1[2]); h1[3] = f2bf(v1[3]);
  *(u16x4*)&Xg[(size_t)pos * DIM + lane * 8] = h0;
  *(u16x4*)&Xg[(size_t)pos * DIM + lane * 8 + 4] = h1;
}

// ---------------- grouped bf16 MFMA GEMM (MoE), T2-swizzled LDS ----------------
__global__ __launch_bounds__(256) void k_gemm_bf16(
    const unsigned short* __restrict__ A, int lda,
    const unsigned short* __restrict__ Wb, size_t westride, int ldw, int wrow0,
    const float* __restrict__ bias, int bstride, int brow0,
    int K, int epi,
    unsigned short* __restrict__ Hout, int ldh,
    float* __restrict__ dout,
    const int* __restrict__ slotTok, const float* __restrict__ slotW,
    const int* __restrict__ off_pad) {
  const int m0 = blockIdx.x * BM;
  if (m0 >= off_pad[NE]) return;
  int e = 0;
  while (off_pad[e + 1] <= m0) e++;
  const unsigned short* W = Wb + (size_t)e * westride;
  const int n0 = blockIdx.y * 128;
  __shared__ unsigned short Al[128 * 64];
  __shared__ unsigned short Bl[128 * 64];
  const int tid = threadIdx.x, lane = tid & 63, wid = tid >> 6;
  const int wm = wid >> 1, wn = wid & 1;
  f32x4 acc[4][4] = {};
  const int srow = wid * 32 + (lane >> 3);
  const int scol = (((lane & 7) ^ ((lane >> 3) & 7)) << 3);
  for (int k0 = 0; k0 < K; k0 += 64) {
    const unsigned short* ga = A + (size_t)(m0 + srow) * lda + k0 + scol;
    const unsigned short* gw = W + (size_t)(wrow0 + n0 + srow) * ldw + k0 + scol;
#pragma unroll
    for (int i = 0; i < 4; i++) {
      load_lds16(ga + (size_t)i * 8 * lda, &Al[(wid * 32 + i * 8) * 64]);
      load_lds16(gw + (size_t)i * 8 * ldw, &Bl[(wid * 32 + i * 8) * 64]);
    }
    __syncthreads();
#pragma unroll
    for (int kk = 0; kk < 2; kk++) {
      short8 av[4], bv[4];
      const int ckx = (kk * 4 + (lane >> 4)) ^ (lane & 7);
#pragma unroll
      for (int mi = 0; mi < 4; mi++)
        av[mi] = *(const short8*)&Al[(wm * 64 + mi * 16 + (lane & 15)) * 64 + ckx * 8];
#pragma unroll
      for (int ni = 0; ni < 4; ni++)
        bv[ni] = *(const short8*)&Bl[(wn * 64 + ni * 16 + (lane & 15)) * 64 + ckx * 8];
#pragma unroll
      for (int mi = 0; mi < 4; mi++) {
#pragma unroll
        for (int ni = 0; ni < 4; ni++)
          acc[mi][ni] = __builtin_amdgcn_mfma_f32_16x16x32_bf16(av[mi], bv[ni], acc[mi][ni], 0, 0, 0);
      }
    }
    __syncthreads();
  }
#pragma unroll
  for (int mi = 0; mi < 4; mi++) {
    const int rb = m0 + wm * 64 + mi * 16 + ((lane >> 4) << 2);
#pragma unroll
    for (int ni = 0; ni < 4; ni++) {
      const int n = n0 + wn * 64 + ni * 16 + (lane & 15);
      const float bn = bias ? bias[(size_t)e * bstride + brow0 + n] : 0.f;
      if (epi == 0) {
#pragma unroll
        for (int r = 0; r < 4; r++) {
          float v = acc[mi][ni][r] + bn;
          v = fmaxf(v, 0.f);
          Hout[(size_t)(rb + r) * ldh + n] = f2bf(v);
        }
      } else {
#pragma unroll
        for (int r = 0; r < 4; r++) {
          const int tok = slotTok[rb + r];
          if (tok >= 0) {
            const float v = (acc[mi][ni][r] + bn) * slotW[rb + r];
            atomicAdd(&dout[(size_t)tok * DIM + n], v);
          }
        }
      }
    }
  }
}

// ---------------- launch ----------------
extern "C" void kernel_launch(void* const* d_in, const int* in_sizes, int n_in,
                              void* d_out, int out_size, void* d_ws, size_t ws_size,
                              hipStream_t stream) {
  const float* src       = (const float*)d_in[0];
  const float* pos       = (const float*)d_in[1];
  const float* in_proj_w = (const float*)d_in[2];
  const float* in_proj_b = (const float*)d_in[3];
  const float* out_w     = (const float*)d_in[4];
  const float* out_b     = (const float*)d_in[5];
  const float* norm1_g   = (const float*)d_in[6];
  const float* norm1_b   = (const float*)d_in[7];
  const float* gate_w    = (const float*)d_in[8];
  const float* gate_b    = (const float*)d_in[9];
  const float* w1        = (const float*)d_in[10];
  const float* b1        = (const float*)d_in[11];
  const float* w2        = (const float*)d_in[12];
  const float* b2        = (const float*)d_in[13];
  float* out = (float*)d_out;
  char* wsb = (char*)d_ws;

  // ---- lifetime-packed arena (~166.5 MiB, unchanged footprint) ----
  // phase A: six bf16 hi/lo planes (16 MiB each) in [0, 96 MiB), dead after attn
  unsigned short* Qhp = (unsigned short*)(wsb + 0);
  unsigned short* Qlp = (unsigned short*)(wsb + 16777216);
  unsigned short* Khp = (unsigned short*)(wsb + 33554432);
  unsigned short* Klp = (unsigned short*)(wsb + 50331648);
  unsigned short* Vhp = (unsigned short*)(wsb + 67108864);
  unsigned short* Vlp = (unsigned short*)(wsb + 83886080);
  float* ob = (float*)(wsb + 100663296);   // attn out [S,B,D] 32 MiB, dead after out-proj
  float* proj = (float*)(wsb + 0);                          // over Q planes, dead after LN
  unsigned short* w1b = (unsigned short*)(wsb + 0);         // over proj, 32 MiB
  unsigned short* w2b = (unsigned short*)(wsb + 33554432);  // over K planes, 32 MiB
  unsigned short* Xg  = (unsigned short*)(wsb + 67108864);  // over V planes + ob-head, 34 MiB
  unsigned short* Hb  = (unsigned short*)(wsb + 102760448); // over ob-tail, 68 MiB
  unsigned short* wih = (unsigned short*)(wsb + 134217728); // 1.5 MiB, dead after QKV proj
  unsigned short* wil = (unsigned short*)(wsb + 135790592); // 1.5 MiB
  char* smallb = wsb + 174063616;
  int*   topi    = (int*)  (smallb + 0);
  float* topw    = (float*)(smallb + 131072);
  int*   slotTok = (int*)  (smallb + 262144);
  float* slotW   = (float*)(smallb + 401408);
  int*   counts  = (int*)  (smallb + 540672);
  int*   off_pad = (int*)  (smallb + 540736);
  int*   cursor  = (int*)  (smallb + 540864);

  // 1. routing init + in_proj weight split
  k_init<<<(CAP + 255) / 256, 256, 0, stream>>>(slotTok, slotW, counts);
  k_split_w<<<768, 256, 0, stream>>>(in_proj_w, wih, wil, (size_t)1536 * 512);
  // 2. Q/K projection (split MFMA, fused src+pos) -> hi/lo planes [B,H,S,HD]
  k_gemm_split<<<dim3(128, 8), 256, 0, stream>>>(src, pos, wih, wil, in_proj_b, 0,
                                                 Qhp, Qlp, Khp, Klp);
  // 3. V projection -> hi/lo planes [B,H,HD,S]
  k_gemm_split<<<dim3(128, 4), 256, 0, stream>>>(src, nullptr, wih + (size_t)1024 * 512,
                                                 wil + (size_t)1024 * 512, in_proj_b + 1024,
                                                 1, Vhp, Vlp, nullptr, nullptr);
  // 4. split-MFMA flash attention -> ob [S,B,D]
  k_attn<<<dim3(16, 128), 256, 0, stream>>>(Qhp, Qlp, Khp, Klp, Vhp, Vlp, ob);
  // 5. w2 -> bf16 (K planes dead)
  k_cvt_bf16<<<2048, 256, 0, stream>>>(w2, w2b, (size_t)NE * DIM * DFF);
  // 6. output projection (fp32 vector — gate-critical) -> proj (over Q planes)
  k_gemm_f32<<<dim3(128, 4), 256, 0, stream>>>(ob, out_w, out_b, 512, proj);
  // 7. layernorm(src + proj) -> d_out (= x)
  k_ln<<<4096, 256, 0, stream>>>(src, proj, norm1_g, norm1_b, out);
  // 8. w1 -> bf16 (proj dead)
  k_cvt_bf16<<<2048, 256, 0, stream>>>(w1, w1b, (size_t)NE * DFF * DIM);
  // 9. gate logits + top2 + counts
  k_gate<<<4096, 256, 0, stream>>>(out, gate_w, gate_b, topi, topw, counts);
  // 10. padded segment offsets
  k_offsets<<<1, 64, 0, stream>>>(counts, off_pad, cursor);
  // 11. zero gathered-token buffer
  k_zero<<<2048, 256, 0, stream>>>((u32x4*)Xg, (size_t)CAP * DIM * 2 / 16);
  // 12. scatter assignments + gather token rows as bf16
  k_scatter<<<8192, 256, 0, stream>>>(out, topi, topw, off_pad, cursor, slotTok, slotW, Xg);
  // 13. MoE, DFF halved
  for (int p = 0; p < 2; ++p) {
    k_gemm_bf16<<<dim3(CAP / BM, 8), 256, 0, stream>>>(
        Xg, DIM, w1b, (size_t)DFF * DIM, DIM, p * 1024,
        b1, DFF, p * 1024, DIM, 0, Hb, 1024,
        nullptr, nullptr, nullptr, off_pad);
    k_gemm_bf16<<<dim3(CAP / BM, 4), 256, 0, stream>>>(
        Hb, 1024, w2b + (size_t)p * 1024, (size_t)DIM * DFF, DFF, 0,
        (p == 0 ? b2 : nullptr), DIM, 0, 1024, 1, nullptr, 0,
        out, slotTok, slotW, off_pad);
  }
}

// Round 6
// 1514.525 us; speedup vs baseline: 1.6597x; 1.2115x over previous
//
#include <hip/hip_runtime.h>
#include <hip/hip_bf16.h>

// ---------------- types ----------------
typedef float f4 __attribute__((ext_vector_type(4)));
typedef float f32x4 __attribute__((ext_vector_type(4)));
typedef short short8 __attribute__((ext_vector_type(8)));
typedef unsigned short u16x4 __attribute__((ext_vector_type(4)));
typedef unsigned short u16x8 __attribute__((ext_vector_type(8)));
typedef unsigned int u32x4 __attribute__((ext_vector_type(4)));

// ---------------- problem constants ----------------
#define S_LEN 1024
#define BATCH 16
#define DIM   512
#define NH    8
#define HDIM  64
#define NE    16
#define DFF   2048
#define T_TOK 16384   // S*B
#define CAP   34816   // 32768 assignments + per-expert padding to BM
#define BM    128

__device__ __forceinline__ unsigned short f2bf(float f) {
  union { float f; unsigned u; } v; v.f = f;
  unsigned r = v.u + 0x7fffu + ((v.u >> 16) & 1u);  // RTNE
  return (unsigned short)(r >> 16);
}
__device__ __forceinline__ float bf2f(unsigned short h) {
  union { unsigned u; float f; } v; v.u = ((unsigned)h) << 16;
  return v.f;
}

__device__ __forceinline__ void load_lds16(const void* g, void* l) {
  __builtin_amdgcn_global_load_lds(
      (__attribute__((address_space(1))) void*)(void*)g,
      (__attribute__((address_space(3))) void*)l, 16, 0, 0);
}

// ---------------- small utility kernels ----------------
__global__ __launch_bounds__(256) void k_cvt_bf16(const float* __restrict__ in,
                                                  unsigned short* __restrict__ outb,
                                                  size_t n) {
  size_t i = ((size_t)blockIdx.x * 256 + threadIdx.x) * 4;
  size_t stride = (size_t)gridDim.x * 1024;
  for (; i < n; i += stride) {
    f4 v = *(const f4*)&in[i];
    u16x4 o;
    o[0] = f2bf(v[0]); o[1] = f2bf(v[1]); o[2] = f2bf(v[2]); o[3] = f2bf(v[3]);
    *(u16x4*)&outb[i] = o;
  }
}

// split fp32 -> bf16 hi + bf16 lo (lo = round(x - hi))
__global__ __launch_bounds__(256) void k_split_w(const float* __restrict__ in,
                                                 unsigned short* __restrict__ hi,
                                                 unsigned short* __restrict__ lo,
                                                 size_t n) {
  size_t i = ((size_t)blockIdx.x * 256 + threadIdx.x) * 4;
  size_t stride = (size_t)gridDim.x * 1024;
  for (; i < n; i += stride) {
    f4 v = *(const f4*)&in[i];
    u16x4 h, l;
#pragma unroll
    for (int j = 0; j < 4; j++) {
      unsigned short hh = f2bf(v[j]);
      h[j] = hh;
      l[j] = f2bf(v[j] - bf2f(hh));
    }
    *(u16x4*)&hi[i] = h;
    *(u16x4*)&lo[i] = l;
  }
}

__global__ __launch_bounds__(256) void k_init(int* __restrict__ slotTok,
                                              float* __restrict__ slotW,
                                              int* __restrict__ counts) {
  int i = blockIdx.x * 256 + threadIdx.x;
  if (i < CAP) { slotTok[i] = -1; slotW[i] = 0.f; }
  if (i < NE) counts[i] = 0;
}

__global__ __launch_bounds__(256) void k_zero(u32x4* __restrict__ p, size_t n16) {
  size_t i = (size_t)blockIdx.x * 256 + threadIdx.x;
  size_t stride = (size_t)gridDim.x * 256;
  u32x4 z = {0u, 0u, 0u, 0u};
  for (; i < n16; i += stride) p[i] = z;
}

// ---------------- split-bf16 MFMA GEMM (fp32-accurate via hi/lo) ----------------
// C = (A [+A2])[M,512] * W[N,512]^T + bias, W pre-split into Wh/Wl bf16.
// 128x128 tile, BK=32, 2x2 waves, 4x4 16x16x32 frags, 3 MFMAs per frag.
// epi 0: n<512 -> Q*0.125 split-> (o0h,o0l) [B,H,S,HD]; n>=512 -> K split-> (o1h,o1l) [B,H,S,HD]
// epi 1: V split-> (o0h,o0l) [B,H,HD,S]
__global__ __launch_bounds__(256, 2) void k_gemm_split(
    const float* __restrict__ A, const float* __restrict__ A2,
    const unsigned short* __restrict__ Wh, const unsigned short* __restrict__ Wl,
    const float* __restrict__ bias, int epi,
    unsigned short* __restrict__ o0h, unsigned short* __restrict__ o0l,
    unsigned short* __restrict__ o1h, unsigned short* __restrict__ o1l) {
  __shared__ unsigned short AhL[128 * 32];
  __shared__ unsigned short AlL[128 * 32];
  __shared__ unsigned short WhL[128 * 32];
  __shared__ unsigned short WlL[128 * 32];
  const int tid = threadIdx.x, lane = tid & 63, wid = tid >> 6;
  const int wm = wid >> 1, wn = wid & 1;
  const int m0 = blockIdx.x * 128, n0 = blockIdx.y * 128;
  const int row = tid >> 1, half = tid & 1;      // A staging: 2 threads/row
  const int xr = (row >> 1) & 3;                 // A-side write swizzle
  f32x4 acc[4][4] = {};
  f4 ar[4];
#pragma unroll
  for (int j = 0; j < 4; j++) {
    const size_t aoff = (size_t)(m0 + row) * 512 + half * 16 + j * 4;
    ar[j] = *(const f4*)&A[aoff];
    if (A2) { f4 v2 = *(const f4*)&A2[aoff]; ar[j] += v2; }
  }
  for (int k0 = 0; k0 < 512; k0 += 32) {
    __syncthreads();
    u16x8 hi8[2], lo8[2];
#pragma unroll
    for (int j = 0; j < 16; j++) {
      const float x = ar[j >> 2][j & 3];
      const unsigned short h = f2bf(x);
      hi8[j >> 3][j & 7] = h;
      lo8[j >> 3][j & 7] = f2bf(x - bf2f(h));
    }
    const int c0 = half * 2;
    *(u16x8*)&AhL[row * 32 + (((c0 + 0) ^ xr) << 3)] = hi8[0];
    *(u16x8*)&AhL[row * 32 + (((c0 + 1) ^ xr) << 3)] = hi8[1];
    *(u16x8*)&AlL[row * 32 + (((c0 + 0) ^ xr) << 3)] = lo8[0];
    *(u16x8*)&AlL[row * 32 + (((c0 + 1) ^ xr) << 3)] = lo8[1];
#pragma unroll
    for (int i = 0; i < 2; i++) {
      const int rowW = i * 64 + wid * 16 + (lane >> 2);
      const int clog = (lane & 3) ^ ((rowW >> 1) & 3);
      const size_t woff = (size_t)(n0 + rowW) * 512 + k0 + (clog << 3);
      load_lds16(Wh + woff, &WhL[i * 2048 + wid * 512]);
      load_lds16(Wl + woff, &WlL[i * 2048 + wid * 512]);
    }
    __syncthreads();
    if (k0 + 32 < 512) {
#pragma unroll
      for (int j = 0; j < 4; j++) {
        const size_t aoff = (size_t)(m0 + row) * 512 + k0 + 32 + half * 16 + j * 4;
        ar[j] = *(const f4*)&A[aoff];
        if (A2) { f4 v2 = *(const f4*)&A2[aoff]; ar[j] += v2; }
      }
    }
    const int l15 = lane & 15, lk = lane >> 4;
    const int xa = (l15 >> 1) & 3;
    short8 avh[4], avl[4], bvh[4], bvl[4];
#pragma unroll
    for (int mi = 0; mi < 4; mi++) {
      const int mr = wm * 64 + mi * 16 + l15;
      avh[mi] = *(const short8*)&AhL[mr * 32 + ((lk ^ xa) << 3)];
      avl[mi] = *(const short8*)&AlL[mr * 32 + ((lk ^ xa) << 3)];
    }
#pragma unroll
    for (int ni = 0; ni < 4; ni++) {
      const int nr = wn * 64 + ni * 16 + l15;
      bvh[ni] = *(const short8*)&WhL[nr * 32 + ((lk ^ xa) << 3)];
      bvl[ni] = *(const short8*)&WlL[nr * 32 + ((lk ^ xa) << 3)];
    }
#pragma unroll
    for (int mi = 0; mi < 4; mi++) {
#pragma unroll
      for (int ni = 0; ni < 4; ni++) {
        acc[mi][ni] = __builtin_amdgcn_mfma_f32_16x16x32_bf16(avh[mi], bvh[ni], acc[mi][ni], 0, 0, 0);
        acc[mi][ni] = __builtin_amdgcn_mfma_f32_16x16x32_bf16(avh[mi], bvl[ni], acc[mi][ni], 0, 0, 0);
        acc[mi][ni] = __builtin_amdgcn_mfma_f32_16x16x32_bf16(avl[mi], bvh[ni], acc[mi][ni], 0, 0, 0);
      }
    }
  }
  // epilogue: split-store to hi/lo planes
#pragma unroll
  for (int mi = 0; mi < 4; mi++) {
    const int rb = m0 + wm * 64 + mi * 16 + ((lane >> 4) << 2);
#pragma unroll
    for (int ni = 0; ni < 4; ni++) {
      const int n = n0 + wn * 64 + ni * 16 + (lane & 15);
      const float bn = bias[n];
#pragma unroll
      for (int r = 0; r < 4; r++) {
        const int m = rb + r;
        const int bidx = m & 15, ss = m >> 4;    // token = s*B + b
        float v = acc[mi][ni][r] + bn;
        if (epi == 0) {
          if (n < 512) {
            v *= 0.125f;
            const size_t off = ((size_t)(bidx * NH + (n >> 6)) * S_LEN + ss) * HDIM + (n & 63);
            const unsigned short hh = f2bf(v);
            o0h[off] = hh; o0l[off] = f2bf(v - bf2f(hh));
          } else {
            const int n2 = n - 512;
            const size_t off = ((size_t)(bidx * NH + (n2 >> 6)) * S_LEN + ss) * HDIM + (n2 & 63);
            const unsigned short hh = f2bf(v);
            o1h[off] = hh; o1l[off] = f2bf(v - bf2f(hh));
          }
        } else {  // V: [B,H,HD,S]
          const size_t off = ((size_t)(bidx * NH + (n >> 6)) * HDIM + (n & 63)) * S_LEN + ss;
          const unsigned short hh = f2bf(v);
          o0h[off] = hh; o0l[off] = f2bf(v - bf2f(hh));
        }
      }
    }
  }
}

// ---------------- fp32 GEMM (out-proj only): C = A[M,K]*W[N,K]^T + bias ----------------
__global__ __launch_bounds__(256, 3) void k_gemm_f32(
    const float* __restrict__ A, const float* __restrict__ W,
    const float* __restrict__ bias, int K,
    float* __restrict__ o0) {
  __shared__ float Alt[32][132];
  __shared__ float Wlt[32][132];
  const int tid = threadIdx.x, tx = tid & 15, ty = tid >> 4;
  const int m0 = blockIdx.x * 128, n0 = blockIdx.y * 128;
  float acc[8][8];
#pragma unroll
  for (int i = 0; i < 8; i++) {
#pragma unroll
    for (int j = 0; j < 8; j++) acc[i][j] = 0.f;
  }
  f4 ar[4], wr[4];
#pragma unroll
  for (int i = 0; i < 4; i++) {
    const int c = tid + i * 256;
    const int r = c >> 3, j = (c & 7) * 4;
    ar[i] = *(const f4*)&A[(size_t)(m0 + r) * K + j];
    wr[i] = *(const f4*)&W[(size_t)(n0 + r) * K + j];
  }
  for (int k0 = 0; k0 < K; k0 += 32) {
    __syncthreads();
#pragma unroll
    for (int i = 0; i < 4; i++) {
      const int c = tid + i * 256;
      const int r = c >> 3, j = (c & 7) * 4;
      Alt[j + 0][r] = ar[i][0]; Alt[j + 1][r] = ar[i][1];
      Alt[j + 2][r] = ar[i][2]; Alt[j + 3][r] = ar[i][3];
      Wlt[j + 0][r] = wr[i][0]; Wlt[j + 1][r] = wr[i][1];
      Wlt[j + 2][r] = wr[i][2]; Wlt[j + 3][r] = wr[i][3];
    }
    __syncthreads();
    if (k0 + 32 < K) {
#pragma unroll
      for (int i = 0; i < 4; i++) {
        const int c = tid + i * 256;
        const int r = c >> 3, j = (c & 7) * 4;
        ar[i] = *(const f4*)&A[(size_t)(m0 + r) * K + k0 + 32 + j];
        wr[i] = *(const f4*)&W[(size_t)(n0 + r) * K + k0 + 32 + j];
      }
    }
#pragma unroll 4
    for (int kk = 0; kk < 32; kk++) {
      float a[8], w8[8];
      *(f4*)&a[0]  = *(const f4*)&Alt[kk][ty * 8];
      *(f4*)&a[4]  = *(const f4*)&Alt[kk][ty * 8 + 4];
      *(f4*)&w8[0] = *(const f4*)&Wlt[kk][tx * 8];
      *(f4*)&w8[4] = *(const f4*)&Wlt[kk][tx * 8 + 4];
#pragma unroll
      for (int mi = 0; mi < 8; mi++) {
#pragma unroll
        for (int ni = 0; ni < 8; ni++)
          acc[mi][ni] = fmaf(a[mi], w8[ni], acc[mi][ni]);
      }
    }
  }
#pragma unroll
  for (int mi = 0; mi < 8; mi++) {
    const size_t m = (size_t)(m0 + ty * 8 + mi);
#pragma unroll
    for (int nj = 0; nj < 2; nj++) {
      const int n = n0 + tx * 8 + nj * 4;
      f4 v;
      v[0] = acc[mi][nj * 4 + 0] + bias[n + 0];
      v[1] = acc[mi][nj * 4 + 1] + bias[n + 1];
      v[2] = acc[mi][nj * 4 + 2] + bias[n + 2];
      v[3] = acc[mi][nj * 4 + 3] + bias[n + 3];
      *(f4*)&o0[m * 512 + n] = v;
    }
  }
}

// ---------------- split-bf16 MFMA flash attention ----------------
// grid (S/64, B*H), 4 waves; Q,K: [B,H,S,HD] hi/lo planes; V: [B,H,HD,S] hi/lo.
__global__ __launch_bounds__(256, 2) void k_attn(
    const unsigned short* __restrict__ Qhp, const unsigned short* __restrict__ Qlp,
    const unsigned short* __restrict__ Khp, const unsigned short* __restrict__ Klp,
    const unsigned short* __restrict__ Vhp, const unsigned short* __restrict__ Vlp,
    float* __restrict__ O) {
  const int q0 = blockIdx.x * 64;
  const int bh = blockIdx.y;
  const int b = bh >> 3, h = bh & 7;
  const size_t base = (size_t)bh * (S_LEN * HDIM);
  __shared__ unsigned short KhL[64][72], KlL[64][72];
  __shared__ unsigned short VhL[64][72], VlL[64][72];
  __shared__ float Pl[64][68];
  const int tid = threadIdx.x, lane = tid & 63, w = tid >> 6;
  const int l15 = lane & 15, lq = lane >> 4;
  short8 qh[2], ql[2];
  {
    const size_t qoff = base + (size_t)(q0 + 16 * w + l15) * HDIM + lq * 8;
    qh[0] = *(const short8*)&Qhp[qoff];
    ql[0] = *(const short8*)&Qlp[qoff];
    qh[1] = *(const short8*)&Qhp[qoff + 32];
    ql[1] = *(const short8*)&Qlp[qoff + 32];
  }
  const int sr = tid >> 2, sq = (tid & 3) * 16;
  u16x8 krh[2], krl[2], vrh[2], vrl[2];
  {
    const size_t ko = base + (size_t)sr * HDIM + sq;
    krh[0] = *(const u16x8*)&Khp[ko]; krh[1] = *(const u16x8*)&Khp[ko + 8];
    krl[0] = *(const u16x8*)&Klp[ko]; krl[1] = *(const u16x8*)&Klp[ko + 8];
    const size_t vo = base + (size_t)sr * S_LEN + sq;
    vrh[0] = *(const u16x8*)&Vhp[vo]; vrh[1] = *(const u16x8*)&Vhp[vo + 8];
    vrl[0] = *(const u16x8*)&Vlp[vo]; vrl[1] = *(const u16x8*)&Vlp[vo + 8];
  }
  float m_[4], l_[4];
  f32x4 acc[4] = {};
#pragma unroll
  for (int r = 0; r < 4; r++) { m_[r] = -1e30f; l_[r] = 0.f; }

  for (int kt = 0; kt < 16; kt++) {
    *(u16x8*)&KhL[sr][sq + 0] = krh[0]; *(u16x8*)&KhL[sr][sq + 8] = krh[1];
    *(u16x8*)&KlL[sr][sq + 0] = krl[0]; *(u16x8*)&KlL[sr][sq + 8] = krl[1];
    *(u16x8*)&VhL[sr][sq + 0] = vrh[0]; *(u16x8*)&VhL[sr][sq + 8] = vrh[1];
    *(u16x8*)&VlL[sr][sq + 0] = vrl[0]; *(u16x8*)&VlL[sr][sq + 8] = vrl[1];
    __syncthreads();
    if (kt < 15) {
      const int s0n = (kt + 1) * 64;
      const size_t ko = base + (size_t)(s0n + sr) * HDIM + sq;
      krh[0] = *(const u16x8*)&Khp[ko]; krh[1] = *(const u16x8*)&Khp[ko + 8];
      krl[0] = *(const u16x8*)&Klp[ko]; krl[1] = *(const u16x8*)&Klp[ko + 8];
      const size_t vo = base + (size_t)sr * S_LEN + s0n + sq;
      vrh[0] = *(const u16x8*)&Vhp[vo]; vrh[1] = *(const u16x8*)&Vhp[vo + 8];
      vrl[0] = *(const u16x8*)&Vlp[vo]; vrl[1] = *(const u16x8*)&Vlp[vo + 8];
    }
    f32x4 sc[4] = {};
#pragma unroll
    for (int c = 0; c < 2; c++) {
      short8 kfh[4], kfl[4];
#pragma unroll
      for (int n = 0; n < 4; n++) {
        kfh[n] = *(const short8*)&KhL[16 * n + l15][c * 32 + lq * 8];
        kfl[n] = *(const short8*)&KlL[16 * n + l15][c * 32 + lq * 8];
      }
#pragma unroll
      for (int n = 0; n < 4; n++) {
        sc[n] = __builtin_amdgcn_mfma_f32_16x16x32_bf16(qh[c], kfh[n], sc[n], 0, 0, 0);
        sc[n] = __builtin_amdgcn_mfma_f32_16x16x32_bf16(qh[c], kfl[n], sc[n], 0, 0, 0);
        sc[n] = __builtin_amdgcn_mfma_f32_16x16x32_bf16(ql[c], kfh[n], sc[n], 0, 0, 0);
      }
    }
    float esc[4], rs[4];
#pragma unroll
    for (int r = 0; r < 4; r++) {
      float t = fmaxf(fmaxf(sc[0][r], sc[1][r]), fmaxf(sc[2][r], sc[3][r]));
#pragma unroll
      for (int d = 1; d < 16; d <<= 1) t = fmaxf(t, __shfl_xor(t, d));
      const float mn = fmaxf(m_[r], t);
      esc[r] = __expf(m_[r] - mn);
      m_[r] = mn;
      rs[r] = 0.f;
    }
#pragma unroll
    for (int n = 0; n < 4; n++) {
#pragma unroll
      for (int r = 0; r < 4; r++) {
        const float p = __expf(sc[n][r] - m_[r]);
        rs[r] += p;
        sc[n][r] = p;
      }
    }
#pragma unroll
    for (int r = 0; r < 4; r++) {
#pragma unroll
      for (int d = 1; d < 16; d <<= 1) rs[r] += __shfl_xor(rs[r], d);
      l_[r] = l_[r] * esc[r] + rs[r];
      acc[0][r] *= esc[r]; acc[1][r] *= esc[r];
      acc[2][r] *= esc[r]; acc[3][r] *= esc[r];
    }
#pragma unroll
    for (int n = 0; n < 4; n++) {
#pragma unroll
      for (int r = 0; r < 4; r++)
        Pl[16 * w + 4 * lq + r][16 * n + l15] = sc[n][r];
    }
#pragma unroll
    for (int c = 0; c < 2; c++) {
      f4 p0 = *(const f4*)&Pl[16 * w + l15][c * 32 + lq * 8];
      f4 p1 = *(const f4*)&Pl[16 * w + l15][c * 32 + lq * 8 + 4];
      short8 ph, pl_;
#pragma unroll
      for (int j = 0; j < 8; j++) {
        const float x = (j < 4) ? p0[j] : p1[j - 4];
        const unsigned short hh = f2bf(x);
        ph[j] = (short)hh;
        pl_[j] = (short)f2bf(x - bf2f(hh));
      }
      short8 vfh[4], vfl[4];
#pragma unroll
      for (int n = 0; n < 4; n++) {
        vfh[n] = *(const short8*)&VhL[16 * n + l15][c * 32 + lq * 8];
        vfl[n] = *(const short8*)&VlL[16 * n + l15][c * 32 + lq * 8];
      }
#pragma unroll
      for (int n = 0; n < 4; n++) {
        acc[n] = __builtin_amdgcn_mfma_f32_16x16x32_bf16(ph, vfh[n], acc[n], 0, 0, 0);
        acc[n] = __builtin_amdgcn_mfma_f32_16x16x32_bf16(ph, vfl[n], acc[n], 0, 0, 0);
        acc[n] = __builtin_amdgcn_mfma_f32_16x16x32_bf16(pl_, vfh[n], acc[n], 0, 0, 0);
      }
    }
    __syncthreads();
  }
#pragma unroll
  for (int r = 0; r < 4; r++) {
    const float inv = 1.f / l_[r];
    const int srow = q0 + 16 * w + 4 * lq + r;
    float* orow = &O[((size_t)srow * BATCH + b) * DIM + h * HDIM];
#pragma unroll
    for (int n = 0; n < 4; n++) orow[16 * n + l15] = acc[n][r] * inv;
  }
}

// ---------------- layernorm: x = LN(src + proj)*g + b -> out ----------------
__global__ __launch_bounds__(256) void k_ln(const float* __restrict__ src,
                                            const float* __restrict__ proj,
                                            const float* __restrict__ g,
                                            const float* __restrict__ bt,
                                            float* __restrict__ xout) {
  const int wid = threadIdx.x >> 6, lane = threadIdx.x & 63;
  const int tok = blockIdx.x * 4 + wid;
  const size_t base = (size_t)tok * DIM + lane * 8;
  f4 a0 = *(const f4*)&src[base],  a1 = *(const f4*)&src[base + 4];
  f4 p0 = *(const f4*)&proj[base], p1 = *(const f4*)&proj[base + 4];
  float x[8];
  x[0] = a0[0] + p0[0]; x[1] = a0[1] + p0[1]; x[2] = a0[2] + p0[2]; x[3] = a0[3] + p0[3];
  x[4] = a1[0] + p1[0]; x[5] = a1[1] + p1[1]; x[6] = a1[2] + p1[2]; x[7] = a1[3] + p1[3];
  float s = 0.f, sq = 0.f;
#pragma unroll
  for (int j = 0; j < 8; j++) { s += x[j]; sq = fmaf(x[j], x[j], sq); }
#pragma unroll
  for (int d = 1; d < 64; d <<= 1) { s += __shfl_xor(s, d); sq += __shfl_xor(sq, d); }
  const float mean = s * (1.f / 512.f);
  const float var = sq * (1.f / 512.f) - mean * mean;
  const float rstd = 1.f / sqrtf(var + 1e-5f);
  const int ci = lane * 8;
  f4 o0v, o1v;
#pragma unroll
  for (int j = 0; j < 4; j++) o0v[j] = (x[j] - mean) * rstd * g[ci + j] + bt[ci + j];
#pragma unroll
  for (int j = 0; j < 4; j++) o1v[j] = (x[4 + j] - mean) * rstd * g[ci + 4 + j] + bt[ci + 4 + j];
  *(f4*)&xout[base] = o0v;
  *(f4*)&xout[base + 4] = o1v;
}

// ---------------- gate: block = 16 tokens x 16 experts, 4 tiles ----------------
// thread (tl, e) owns logit(t0+tl, e); x rows staged in LDS (XOR-swizzled chunks);
// top-2 via 16-lane butterfly; LDS histogram -> 16 global atomics per block.
__global__ __launch_bounds__(256) void k_gate(const float* __restrict__ x,
                                              const float* __restrict__ gw,
                                              const float* __restrict__ gb,
                                              int* __restrict__ topi,
                                              float* __restrict__ topw,
                                              int* __restrict__ counts) {
  __shared__ float xs[16 * 520];
  __shared__ int hist[16];
  const int tid = threadIdx.x;
  const int tl = tid >> 4, e = tid & 15;
  if (tid < 16) hist[tid] = 0;
  const float gbe = gb[e];
  const float* wrow = gw + (size_t)e * DIM;
  for (int tile = 0; tile < 4; tile++) {
    const int t0 = blockIdx.x * 64 + tile * 16;
    __syncthreads();   // previous tile's xs readers done (and hist init ordered)
    {
      const int r = tid >> 4, cbase = (tid & 15) * 32;
#pragma unroll
      for (int j = 0; j < 8; j++) {
        const int c = cbase + j * 4;
        const int ch = c >> 2;
        const int pc = ch ^ ((ch >> 3) & 7);   // spread 16B chunks across banks
        *(f4*)&xs[r * 520 + pc * 4] = *(const f4*)&x[(size_t)(t0 + r) * DIM + c];
      }
    }
    __syncthreads();
    float d = gbe;
#pragma unroll 8
    for (int c = 0; c < DIM; c += 4) {
      const int ch = c >> 2;
      const int pc = ch ^ ((ch >> 3) & 7);
      f4 xv = *(const f4*)&xs[tl * 520 + pc * 4];
      f4 wv = *(const f4*)&wrow[c];
      d = fmaf(xv[0], wv[0], d); d = fmaf(xv[1], wv[1], d);
      d = fmaf(xv[2], wv[2], d); d = fmaf(xv[3], wv[3], d);
    }
    // top-2 butterfly across the 16-lane expert group (index tie-break: lower wins)
    float v1 = d, v2 = -1e30f;
    int i1 = e, i2 = 1000;
#pragma unroll
    for (int s = 1; s < 16; s <<= 1) {
      const float ov1 = __shfl_xor(v1, s), ov2 = __shfl_xor(v2, s);
      const int oi1 = __shfl_xor(i1, s), oi2 = __shfl_xor(i2, s);
      if (ov1 > v1 || (ov1 == v1 && oi1 < i1)) {
        float nv2; int ni2;
        if (v1 > ov2 || (v1 == ov2 && i1 < oi2)) { nv2 = v1; ni2 = i1; }
        else { nv2 = ov2; ni2 = oi2; }
        v1 = ov1; i1 = oi1; v2 = nv2; i2 = ni2;
      } else if (ov1 > v2 || (ov1 == v2 && oi1 < i2)) {
        v2 = ov1; i2 = oi1;
      }
    }
    if (e == 0) {
      const int t = t0 + tl;
      const float e1 = __expf(v2 - v1);
      const float inv = 1.f / (1.f + e1);
      topi[2 * t] = i1;  topi[2 * t + 1] = i2;
      topw[2 * t] = inv; topw[2 * t + 1] = e1 * inv;
      atomicAdd(&hist[i1], 1);
      atomicAdd(&hist[i2], 1);
    }
  }
  __syncthreads();
  if (tid < 16 && hist[tid] > 0) atomicAdd(&counts[tid], hist[tid]);
}

__global__ void k_offsets(const int* __restrict__ counts,
                          int* __restrict__ off_pad, int* __restrict__ cursor) {
  if (threadIdx.x == 0) {
    int o = 0;
    off_pad[0] = 0;
    for (int e = 0; e < NE; e++) {
      cursor[e] = 0;
      o += ((counts[e] + BM - 1) / BM) * BM;
      off_pad[e + 1] = o;
    }
  }
}

// one wave per (token, k) assignment: claim slot + gather row as bf16
__global__ __launch_bounds__(256) void k_scatter(const float* __restrict__ x,
                                                 const int* __restrict__ topi,
                                                 const float* __restrict__ topw,
                                                 const int* __restrict__ off_pad,
                                                 int* __restrict__ cursor,
                                                 int* __restrict__ slotTok,
                                                 float* __restrict__ slotW,
                                                 unsigned short* __restrict__ Xg) {
  const int wid = threadIdx.x >> 6, lane = threadIdx.x & 63;
  const int a = blockIdx.x * 4 + wid;   // [0, 32768)
  const int t = a >> 1;
  const int e = topi[a];
  int pos = 0;
  if (lane == 0) {
    pos = off_pad[e] + atomicAdd(&cursor[e], 1);
    slotTok[pos] = t;
    slotW[pos] = topw[a];
  }
  pos = __shfl(pos, 0);
  const size_t sb = (size_t)t * DIM + lane * 8;
  f4 v0 = *(const f4*)&x[sb], v1 = *(const f4*)&x[sb + 4];
  u16x4 h0, h1;
  h0[0] = f2bf(v0[0]); h0[1] = f2bf(v0[1]); h0[2] = f2bf(v0[2]); h0[3] = f2bf(v0[3]);
  h1[0] = f2bf(v1[0]); h1[1] = f2bf(v1[1]); h1[2] = f2bf(v1[2]); h1[3] = f2bf(v1[3]);
  *(u16x4*)&Xg[(size_t)pos * DIM + lane * 8] = h0;
  *(u16x4*)&Xg[(size_t)pos * DIM + lane * 8 + 4] = h1;
}

// ---------------- grouped bf16 MFMA GEMM (MoE), T2-swizzled LDS ----------------
__global__ __launch_bounds__(256) void k_gemm_bf16(
    const unsigned short* __restrict__ A, int lda,
    const unsigned short* __restrict__ Wb, size_t westride, int ldw, int wrow0,
    const float* __restrict__ bias, int bstride, int brow0,
    int K, int epi,
    unsigned short* __restrict__ Hout, int ldh,
    float* __restrict__ dout,
    const int* __restrict__ slotTok, const float* __restrict__ slotW,
    const int* __restrict__ off_pad) {
  const int m0 = blockIdx.x * BM;
  if (m0 >= off_pad[NE]) return;
  int e = 0;
  while (off_pad[e + 1] <= m0) e++;
  const unsigned short* W = Wb + (size_t)e * westride;
  const int n0 = blockIdx.y * 128;
  __shared__ unsigned short Al[128 * 64];
  __shared__ unsigned short Bl[128 * 64];
  const int tid = threadIdx.x, lane = tid & 63, wid = tid >> 6;
  const int wm = wid >> 1, wn = wid & 1;
  f32x4 acc[4][4] = {};
  const int srow = wid * 32 + (lane >> 3);
  const int scol = (((lane & 7) ^ ((lane >> 3) & 7)) << 3);
  for (int k0 = 0; k0 < K; k0 += 64) {
    const unsigned short* ga = A + (size_t)(m0 + srow) * lda + k0 + scol;
    const unsigned short* gw = W + (size_t)(wrow0 + n0 + srow) * ldw + k0 + scol;
#pragma unroll
    for (int i = 0; i < 4; i++) {
      load_lds16(ga + (size_t)i * 8 * lda, &Al[(wid * 32 + i * 8) * 64]);
      load_lds16(gw + (size_t)i * 8 * ldw, &Bl[(wid * 32 + i * 8) * 64]);
    }
    __syncthreads();
#pragma unroll
    for (int kk = 0; kk < 2; kk++) {
      short8 av[4], bv[4];
      const int ckx = (kk * 4 + (lane >> 4)) ^ (lane & 7);
#pragma unroll
      for (int mi = 0; mi < 4; mi++)
        av[mi] = *(const short8*)&Al[(wm * 64 + mi * 16 + (lane & 15)) * 64 + ckx * 8];
#pragma unroll
      for (int ni = 0; ni < 4; ni++)
        bv[ni] = *(const short8*)&Bl[(wn * 64 + ni * 16 + (lane & 15)) * 64 + ckx * 8];
#pragma unroll
      for (int mi = 0; mi < 4; mi++) {
#pragma unroll
        for (int ni = 0; ni < 4; ni++)
          acc[mi][ni] = __builtin_amdgcn_mfma_f32_16x16x32_bf16(av[mi], bv[ni], acc[mi][ni], 0, 0, 0);
      }
    }
    __syncthreads();
  }
#pragma unroll
  for (int mi = 0; mi < 4; mi++) {
    const int rb = m0 + wm * 64 + mi * 16 + ((lane >> 4) << 2);
#pragma unroll
    for (int ni = 0; ni < 4; ni++) {
      const int n = n0 + wn * 64 + ni * 16 + (lane & 15);
      const float bn = bias ? bias[(size_t)e * bstride + brow0 + n] : 0.f;
      if (epi == 0) {
#pragma unroll
        for (int r = 0; r < 4; r++) {
          float v = acc[mi][ni][r] + bn;
          v = fmaxf(v, 0.f);
          Hout[(size_t)(rb + r) * ldh + n] = f2bf(v);
        }
      } else {
#pragma unroll
        for (int r = 0; r < 4; r++) {
          const int tok = slotTok[rb + r];
          if (tok >= 0) {
            const float v = (acc[mi][ni][r] + bn) * slotW[rb + r];
            atomicAdd(&dout[(size_t)tok * DIM + n], v);
          }
        }
      }
    }
  }
}

// ---------------- launch ----------------
extern "C" void kernel_launch(void* const* d_in, const int* in_sizes, int n_in,
                              void* d_out, int out_size, void* d_ws, size_t ws_size,
                              hipStream_t stream) {
  const float* src       = (const float*)d_in[0];
  const float* pos       = (const float*)d_in[1];
  const float* in_proj_w = (const float*)d_in[2];
  const float* in_proj_b = (const float*)d_in[3];
  const float* out_w     = (const float*)d_in[4];
  const float* out_b     = (const float*)d_in[5];
  const float* norm1_g   = (const float*)d_in[6];
  const float* norm1_b   = (const float*)d_in[7];
  const float* gate_w    = (const float*)d_in[8];
  const float* gate_b    = (const float*)d_in[9];
  const float* w1        = (const float*)d_in[10];
  const float* b1        = (const float*)d_in[11];
  const float* w2        = (const float*)d_in[12];
  const float* b2        = (const float*)d_in[13];
  float* out = (float*)d_out;
  char* wsb = (char*)d_ws;

  // ---- lifetime-packed arena (~166.5 MiB, unchanged footprint) ----
  unsigned short* Qhp = (unsigned short*)(wsb + 0);
  unsigned short* Qlp = (unsigned short*)(wsb + 16777216);
  unsigned short* Khp = (unsigned short*)(wsb + 33554432);
  unsigned short* Klp = (unsigned short*)(wsb + 50331648);
  unsigned short* Vhp = (unsigned short*)(wsb + 67108864);
  unsigned short* Vlp = (unsigned short*)(wsb + 83886080);
  float* ob = (float*)(wsb + 100663296);
  float* proj = (float*)(wsb + 0);
  unsigned short* w1b = (unsigned short*)(wsb + 0);
  unsigned short* w2b = (unsigned short*)(wsb + 33554432);
  unsigned short* Xg  = (unsigned short*)(wsb + 67108864);
  unsigned short* Hb  = (unsigned short*)(wsb + 102760448);
  unsigned short* wih = (unsigned short*)(wsb + 134217728);
  unsigned short* wil = (unsigned short*)(wsb + 135790592);
  char* smallb = wsb + 174063616;
  int*   topi    = (int*)  (smallb + 0);
  float* topw    = (float*)(smallb + 131072);
  int*   slotTok = (int*)  (smallb + 262144);
  float* slotW   = (float*)(smallb + 401408);
  int*   counts  = (int*)  (smallb + 540672);
  int*   off_pad = (int*)  (smallb + 540736);
  int*   cursor  = (int*)  (smallb + 540864);

  // 1. routing init + in_proj weight split
  k_init<<<(CAP + 255) / 256, 256, 0, stream>>>(slotTok, slotW, counts);
  k_split_w<<<768, 256, 0, stream>>>(in_proj_w, wih, wil, (size_t)1536 * 512);
  // 2. Q/K projection (split MFMA, fused src+pos) -> hi/lo planes [B,H,S,HD]
  k_gemm_split<<<dim3(128, 8), 256, 0, stream>>>(src, pos, wih, wil, in_proj_b, 0,
                                                 Qhp, Qlp, Khp, Klp);
  // 3. V projection -> hi/lo planes [B,H,HD,S]
  k_gemm_split<<<dim3(128, 4), 256, 0, stream>>>(src, nullptr, wih + (size_t)1024 * 512,
                                                 wil + (size_t)1024 * 512, in_proj_b + 1024,
                                                 1, Vhp, Vlp, nullptr, nullptr);
  // 4. split-MFMA flash attention -> ob [S,B,D]
  k_attn<<<dim3(16, 128), 256, 0, stream>>>(Qhp, Qlp, Khp, Klp, Vhp, Vlp, ob);
  // 5. w2 -> bf16 (K planes dead)
  k_cvt_bf16<<<2048, 256, 0, stream>>>(w2, w2b, (size_t)NE * DIM * DFF);
  // 6. output projection (fp32 vector — gate-critical) -> proj (over Q planes)
  k_gemm_f32<<<dim3(128, 4), 256, 0, stream>>>(ob, out_w, out_b, 512, proj);
  // 7. layernorm(src + proj) -> d_out (= x)
  k_ln<<<4096, 256, 0, stream>>>(src, proj, norm1_g, norm1_b, out);
  // 8. w1 -> bf16 (proj dead)
  k_cvt_bf16<<<2048, 256, 0, stream>>>(w1, w1b, (size_t)NE * DFF * DIM);
  // 9. gate logits + top2 + counts (restructured: 256 blocks x 64 tokens)
  k_gate<<<T_TOK / 64, 256, 0, stream>>>(out, gate_w, gate_b, topi, topw, counts);
  // 10. padded segment offsets
  k_offsets<<<1, 64, 0, stream>>>(counts, off_pad, cursor);
  // 11. zero gathered-token buffer
  k_zero<<<2048, 256, 0, stream>>>((u32x4*)Xg, (size_t)CAP * DIM * 2 / 16);
  // 12. scatter assignments + gather token rows as bf16
  k_scatter<<<8192, 256, 0, stream>>>(out, topi, topw, off_pad, cursor, slotTok, slotW, Xg);
  // 13. MoE, DFF halved
  for (int p = 0; p < 2; ++p) {
    k_gemm_bf16<<<dim3(CAP / BM, 8), 256, 0, stream>>>(
        Xg, DIM, w1b, (size_t)DFF * DIM, DIM, p * 1024,
        b1, DFF, p * 1024, DIM, 0, Hb, 1024,
        nullptr, nullptr, nullptr, off_pad);
    k_gemm_bf16<<<dim3(CAP / BM, 4), 256, 0, stream>>>(
        Hb, 1024, w2b + (size_t)p * 1024, (size_t)DIM * DFF, DFF, 0,
        (p == 0 ? b2 : nullptr), DIM, 0, 1024, 1, nullptr, 0,
        out, slotTok, slotW, off_pad);
  }
}

// Round 7
// 1152.154 us; speedup vs baseline: 2.1817x; 1.3145x over previous
//
#include <hip/hip_runtime.h>
#include <hip/hip_bf16.h>

// ---------------- types ----------------
typedef float f4 __attribute__((ext_vector_type(4)));
typedef float f32x4 __attribute__((ext_vector_type(4)));
typedef short short8 __attribute__((ext_vector_type(8)));
typedef unsigned short u16x4 __attribute__((ext_vector_type(4)));
typedef unsigned short u16x8 __attribute__((ext_vector_type(8)));
typedef unsigned int u32x4 __attribute__((ext_vector_type(4)));

// ---------------- problem constants ----------------
#define S_LEN 1024
#define BATCH 16
#define DIM   512
#define NH    8
#define HDIM  64
#define NE    16
#define DFF   2048
#define T_TOK 16384   // S*B
#define CAP   34816   // 32768 assignments + per-expert padding to BM
#define BM    128

__device__ __forceinline__ unsigned short f2bf(float f) {
  union { float f; unsigned u; } v; v.f = f;
  unsigned r = v.u + 0x7fffu + ((v.u >> 16) & 1u);  // RTNE
  return (unsigned short)(r >> 16);
}
__device__ __forceinline__ float bf2f(unsigned short h) {
  union { unsigned u; float f; } v; v.u = ((unsigned)h) << 16;
  return v.f;
}

__device__ __forceinline__ void load_lds16(const void* g, void* l) {
  __builtin_amdgcn_global_load_lds(
      (__attribute__((address_space(1))) void*)(void*)g,
      (__attribute__((address_space(3))) void*)l, 16, 0, 0);
}

// ---------------- small utility kernels ----------------
__global__ __launch_bounds__(256) void k_cvt_bf16(const float* __restrict__ in,
                                                  unsigned short* __restrict__ outb,
                                                  size_t n) {
  size_t i = ((size_t)blockIdx.x * 256 + threadIdx.x) * 4;
  size_t stride = (size_t)gridDim.x * 1024;
  for (; i < n; i += stride) {
    f4 v = *(const f4*)&in[i];
    u16x4 o;
    o[0] = f2bf(v[0]); o[1] = f2bf(v[1]); o[2] = f2bf(v[2]); o[3] = f2bf(v[3]);
    *(u16x4*)&outb[i] = o;
  }
}

// split fp32 -> bf16 hi + bf16 lo (lo = round(x - hi))
__global__ __launch_bounds__(256) void k_split_w(const float* __restrict__ in,
                                                 unsigned short* __restrict__ hi,
                                                 unsigned short* __restrict__ lo,
                                                 size_t n) {
  size_t i = ((size_t)blockIdx.x * 256 + threadIdx.x) * 4;
  size_t stride = (size_t)gridDim.x * 1024;
  for (; i < n; i += stride) {
    f4 v = *(const f4*)&in[i];
    u16x4 h, l;
#pragma unroll
    for (int j = 0; j < 4; j++) {
      unsigned short hh = f2bf(v[j]);
      h[j] = hh;
      l[j] = f2bf(v[j] - bf2f(hh));
    }
    *(u16x4*)&hi[i] = h;
    *(u16x4*)&lo[i] = l;
  }
}

__global__ __launch_bounds__(256) void k_init(int* __restrict__ slotTok,
                                              float* __restrict__ slotW,
                                              int* __restrict__ counts) {
  int i = blockIdx.x * 256 + threadIdx.x;
  if (i < CAP) { slotTok[i] = -1; slotW[i] = 0.f; }
  if (i < NE) counts[i] = 0;
}

__global__ __launch_bounds__(256) void k_zero(u32x4* __restrict__ p, size_t n16) {
  size_t i = (size_t)blockIdx.x * 256 + threadIdx.x;
  size_t stride = (size_t)gridDim.x * 256;
  u32x4 z = {0u, 0u, 0u, 0u};
  for (; i < n16; i += stride) p[i] = z;
}

// ---------------- split-bf16 MFMA GEMM (fp32-accurate via hi/lo) ----------------
// C = (A [+A2])[M,512] * W[N,512]^T + bias, W pre-split into Wh/Wl bf16.
// epi 0: n<512 -> Q*0.125 split-> (o0h,o0l) [B,H,S,HD]; n>=512 -> K split-> (o1h,o1l)
// epi 1: V split-> (o0h,o0l) [B,H,HD,S]
__global__ __launch_bounds__(256, 2) void k_gemm_split(
    const float* __restrict__ A, const float* __restrict__ A2,
    const unsigned short* __restrict__ Wh, const unsigned short* __restrict__ Wl,
    const float* __restrict__ bias, int epi,
    unsigned short* __restrict__ o0h, unsigned short* __restrict__ o0l,
    unsigned short* __restrict__ o1h, unsigned short* __restrict__ o1l) {
  __shared__ unsigned short AhL[128 * 32];
  __shared__ unsigned short AlL[128 * 32];
  __shared__ unsigned short WhL[128 * 32];
  __shared__ unsigned short WlL[128 * 32];
  const int tid = threadIdx.x, lane = tid & 63, wid = tid >> 6;
  const int wm = wid >> 1, wn = wid & 1;
  const int m0 = blockIdx.x * 128, n0 = blockIdx.y * 128;
  const int row = tid >> 1, half = tid & 1;
  const int xr = (row >> 1) & 3;
  f32x4 acc[4][4] = {};
  f4 ar[4];
#pragma unroll
  for (int j = 0; j < 4; j++) {
    const size_t aoff = (size_t)(m0 + row) * 512 + half * 16 + j * 4;
    ar[j] = *(const f4*)&A[aoff];
    if (A2) { f4 v2 = *(const f4*)&A2[aoff]; ar[j] += v2; }
  }
  for (int k0 = 0; k0 < 512; k0 += 32) {
    __syncthreads();
    u16x8 hi8[2], lo8[2];
#pragma unroll
    for (int j = 0; j < 16; j++) {
      const float x = ar[j >> 2][j & 3];
      const unsigned short h = f2bf(x);
      hi8[j >> 3][j & 7] = h;
      lo8[j >> 3][j & 7] = f2bf(x - bf2f(h));
    }
    const int c0 = half * 2;
    *(u16x8*)&AhL[row * 32 + (((c0 + 0) ^ xr) << 3)] = hi8[0];
    *(u16x8*)&AhL[row * 32 + (((c0 + 1) ^ xr) << 3)] = hi8[1];
    *(u16x8*)&AlL[row * 32 + (((c0 + 0) ^ xr) << 3)] = lo8[0];
    *(u16x8*)&AlL[row * 32 + (((c0 + 1) ^ xr) << 3)] = lo8[1];
#pragma unroll
    for (int i = 0; i < 2; i++) {
      const int rowW = i * 64 + wid * 16 + (lane >> 2);
      const int clog = (lane & 3) ^ ((rowW >> 1) & 3);
      const size_t woff = (size_t)(n0 + rowW) * 512 + k0 + (clog << 3);
      load_lds16(Wh + woff, &WhL[i * 2048 + wid * 512]);
      load_lds16(Wl + woff, &WlL[i * 2048 + wid * 512]);
    }
    __syncthreads();
    if (k0 + 32 < 512) {
#pragma unroll
      for (int j = 0; j < 4; j++) {
        const size_t aoff = (size_t)(m0 + row) * 512 + k0 + 32 + half * 16 + j * 4;
        ar[j] = *(const f4*)&A[aoff];
        if (A2) { f4 v2 = *(const f4*)&A2[aoff]; ar[j] += v2; }
      }
    }
    const int l15 = lane & 15, lk = lane >> 4;
    const int xa = (l15 >> 1) & 3;
    short8 avh[4], avl[4], bvh[4], bvl[4];
#pragma unroll
    for (int mi = 0; mi < 4; mi++) {
      const int mr = wm * 64 + mi * 16 + l15;
      avh[mi] = *(const short8*)&AhL[mr * 32 + ((lk ^ xa) << 3)];
      avl[mi] = *(const short8*)&AlL[mr * 32 + ((lk ^ xa) << 3)];
    }
#pragma unroll
    for (int ni = 0; ni < 4; ni++) {
      const int nr = wn * 64 + ni * 16 + l15;
      bvh[ni] = *(const short8*)&WhL[nr * 32 + ((lk ^ xa) << 3)];
      bvl[ni] = *(const short8*)&WlL[nr * 32 + ((lk ^ xa) << 3)];
    }
#pragma unroll
    for (int mi = 0; mi < 4; mi++) {
#pragma unroll
      for (int ni = 0; ni < 4; ni++) {
        acc[mi][ni] = __builtin_amdgcn_mfma_f32_16x16x32_bf16(avh[mi], bvh[ni], acc[mi][ni], 0, 0, 0);
        acc[mi][ni] = __builtin_amdgcn_mfma_f32_16x16x32_bf16(avh[mi], bvl[ni], acc[mi][ni], 0, 0, 0);
        acc[mi][ni] = __builtin_amdgcn_mfma_f32_16x16x32_bf16(avl[mi], bvh[ni], acc[mi][ni], 0, 0, 0);
      }
    }
  }
#pragma unroll
  for (int mi = 0; mi < 4; mi++) {
    const int rb = m0 + wm * 64 + mi * 16 + ((lane >> 4) << 2);
#pragma unroll
    for (int ni = 0; ni < 4; ni++) {
      const int n = n0 + wn * 64 + ni * 16 + (lane & 15);
      const float bn = bias[n];
#pragma unroll
      for (int r = 0; r < 4; r++) {
        const int m = rb + r;
        const int bidx = m & 15, ss = m >> 4;
        float v = acc[mi][ni][r] + bn;
        if (epi == 0) {
          if (n < 512) {
            v *= 0.125f;
            const size_t off = ((size_t)(bidx * NH + (n >> 6)) * S_LEN + ss) * HDIM + (n & 63);
            const unsigned short hh = f2bf(v);
            o0h[off] = hh; o0l[off] = f2bf(v - bf2f(hh));
          } else {
            const int n2 = n - 512;
            const size_t off = ((size_t)(bidx * NH + (n2 >> 6)) * S_LEN + ss) * HDIM + (n2 & 63);
            const unsigned short hh = f2bf(v);
            o1h[off] = hh; o1l[off] = f2bf(v - bf2f(hh));
          }
        } else {
          const size_t off = ((size_t)(bidx * NH + (n >> 6)) * HDIM + (n & 63)) * S_LEN + ss;
          const unsigned short hh = f2bf(v);
          o0h[off] = hh; o0l[off] = f2bf(v - bf2f(hh));
        }
      }
    }
  }
}

// ---------------- fp32 GEMM (out-proj only): C = A[M,K]*W[N,K]^T + bias ----------------
__global__ __launch_bounds__(256, 3) void k_gemm_f32(
    const float* __restrict__ A, const float* __restrict__ W,
    const float* __restrict__ bias, int K,
    float* __restrict__ o0) {
  __shared__ float Alt[32][132];
  __shared__ float Wlt[32][132];
  const int tid = threadIdx.x, tx = tid & 15, ty = tid >> 4;
  const int m0 = blockIdx.x * 128, n0 = blockIdx.y * 128;
  float acc[8][8];
#pragma unroll
  for (int i = 0; i < 8; i++) {
#pragma unroll
    for (int j = 0; j < 8; j++) acc[i][j] = 0.f;
  }
  f4 ar[4], wr[4];
#pragma unroll
  for (int i = 0; i < 4; i++) {
    const int c = tid + i * 256;
    const int r = c >> 3, j = (c & 7) * 4;
    ar[i] = *(const f4*)&A[(size_t)(m0 + r) * K + j];
    wr[i] = *(const f4*)&W[(size_t)(n0 + r) * K + j];
  }
  for (int k0 = 0; k0 < K; k0 += 32) {
    __syncthreads();
#pragma unroll
    for (int i = 0; i < 4; i++) {
      const int c = tid + i * 256;
      const int r = c >> 3, j = (c & 7) * 4;
      Alt[j + 0][r] = ar[i][0]; Alt[j + 1][r] = ar[i][1];
      Alt[j + 2][r] = ar[i][2]; Alt[j + 3][r] = ar[i][3];
      Wlt[j + 0][r] = wr[i][0]; Wlt[j + 1][r] = wr[i][1];
      Wlt[j + 2][r] = wr[i][2]; Wlt[j + 3][r] = wr[i][3];
    }
    __syncthreads();
    if (k0 + 32 < K) {
#pragma unroll
      for (int i = 0; i < 4; i++) {
        const int c = tid + i * 256;
        const int r = c >> 3, j = (c & 7) * 4;
        ar[i] = *(const f4*)&A[(size_t)(m0 + r) * K + k0 + 32 + j];
        wr[i] = *(const f4*)&W[(size_t)(n0 + r) * K + k0 + 32 + j];
      }
    }
#pragma unroll 4
    for (int kk = 0; kk < 32; kk++) {
      float a[8], w8[8];
      *(f4*)&a[0]  = *(const f4*)&Alt[kk][ty * 8];
      *(f4*)&a[4]  = *(const f4*)&Alt[kk][ty * 8 + 4];
      *(f4*)&w8[0] = *(const f4*)&Wlt[kk][tx * 8];
      *(f4*)&w8[4] = *(const f4*)&Wlt[kk][tx * 8 + 4];
#pragma unroll
      for (int mi = 0; mi < 8; mi++) {
#pragma unroll
        for (int ni = 0; ni < 8; ni++)
          acc[mi][ni] = fmaf(a[mi], w8[ni], acc[mi][ni]);
      }
    }
  }
#pragma unroll
  for (int mi = 0; mi < 8; mi++) {
    const size_t m = (size_t)(m0 + ty * 8 + mi);
#pragma unroll
    for (int nj = 0; nj < 2; nj++) {
      const int n = n0 + tx * 8 + nj * 4;
      f4 v;
      v[0] = acc[mi][nj * 4 + 0] + bias[n + 0];
      v[1] = acc[mi][nj * 4 + 1] + bias[n + 1];
      v[2] = acc[mi][nj * 4 + 2] + bias[n + 2];
      v[3] = acc[mi][nj * 4 + 3] + bias[n + 3];
      *(f4*)&o0[m * 512 + n] = v;
    }
  }
}

// ---------------- split-bf16 MFMA flash attention ----------------
__global__ __launch_bounds__(256, 2) void k_attn(
    const unsigned short* __restrict__ Qhp, const unsigned short* __restrict__ Qlp,
    const unsigned short* __restrict__ Khp, const unsigned short* __restrict__ Klp,
    const unsigned short* __restrict__ Vhp, const unsigned short* __restrict__ Vlp,
    float* __restrict__ O) {
  const int q0 = blockIdx.x * 64;
  const int bh = blockIdx.y;
  const int b = bh >> 3, h = bh & 7;
  const size_t base = (size_t)bh * (S_LEN * HDIM);
  __shared__ unsigned short KhL[64][72], KlL[64][72];
  __shared__ unsigned short VhL[64][72], VlL[64][72];
  __shared__ float Pl[64][68];
  const int tid = threadIdx.x, lane = tid & 63, w = tid >> 6;
  const int l15 = lane & 15, lq = lane >> 4;
  short8 qh[2], ql[2];
  {
    const size_t qoff = base + (size_t)(q0 + 16 * w + l15) * HDIM + lq * 8;
    qh[0] = *(const short8*)&Qhp[qoff];
    ql[0] = *(const short8*)&Qlp[qoff];
    qh[1] = *(const short8*)&Qhp[qoff + 32];
    ql[1] = *(const short8*)&Qlp[qoff + 32];
  }
  const int sr = tid >> 2, sq = (tid & 3) * 16;
  u16x8 krh[2], krl[2], vrh[2], vrl[2];
  {
    const size_t ko = base + (size_t)sr * HDIM + sq;
    krh[0] = *(const u16x8*)&Khp[ko]; krh[1] = *(const u16x8*)&Khp[ko + 8];
    krl[0] = *(const u16x8*)&Klp[ko]; krl[1] = *(const u16x8*)&Klp[ko + 8];
    const size_t vo = base + (size_t)sr * S_LEN + sq;
    vrh[0] = *(const u16x8*)&Vhp[vo]; vrh[1] = *(const u16x8*)&Vhp[vo + 8];
    vrl[0] = *(const u16x8*)&Vlp[vo]; vrl[1] = *(const u16x8*)&Vlp[vo + 8];
  }
  float m_[4], l_[4];
  f32x4 acc[4] = {};
#pragma unroll
  for (int r = 0; r < 4; r++) { m_[r] = -1e30f; l_[r] = 0.f; }

  for (int kt = 0; kt < 16; kt++) {
    *(u16x8*)&KhL[sr][sq + 0] = krh[0]; *(u16x8*)&KhL[sr][sq + 8] = krh[1];
    *(u16x8*)&KlL[sr][sq + 0] = krl[0]; *(u16x8*)&KlL[sr][sq + 8] = krl[1];
    *(u16x8*)&VhL[sr][sq + 0] = vrh[0]; *(u16x8*)&VhL[sr][sq + 8] = vrh[1];
    *(u16x8*)&VlL[sr][sq + 0] = vrl[0]; *(u16x8*)&VlL[sr][sq + 8] = vrl[1];
    __syncthreads();
    if (kt < 15) {
      const int s0n = (kt + 1) * 64;
      const size_t ko = base + (size_t)(s0n + sr) * HDIM + sq;
      krh[0] = *(const u16x8*)&Khp[ko]; krh[1] = *(const u16x8*)&Khp[ko + 8];
      krl[0] = *(const u16x8*)&Klp[ko]; krl[1] = *(const u16x8*)&Klp[ko + 8];
      const size_t vo = base + (size_t)sr * S_LEN + s0n + sq;
      vrh[0] = *(const u16x8*)&Vhp[vo]; vrh[1] = *(const u16x8*)&Vhp[vo + 8];
      vrl[0] = *(const u16x8*)&Vlp[vo]; vrl[1] = *(const u16x8*)&Vlp[vo + 8];
    }
    f32x4 sc[4] = {};
#pragma unroll
    for (int c = 0; c < 2; c++) {
      short8 kfh[4], kfl[4];
#pragma unroll
      for (int n = 0; n < 4; n++) {
        kfh[n] = *(const short8*)&KhL[16 * n + l15][c * 32 + lq * 8];
        kfl[n] = *(const short8*)&KlL[16 * n + l15][c * 32 + lq * 8];
      }
#pragma unroll
      for (int n = 0; n < 4; n++) {
        sc[n] = __builtin_amdgcn_mfma_f32_16x16x32_bf16(qh[c], kfh[n], sc[n], 0, 0, 0);
        sc[n] = __builtin_amdgcn_mfma_f32_16x16x32_bf16(qh[c], kfl[n], sc[n], 0, 0, 0);
        sc[n] = __builtin_amdgcn_mfma_f32_16x16x32_bf16(ql[c], kfh[n], sc[n], 0, 0, 0);
      }
    }
    float esc[4], rs[4];
#pragma unroll
    for (int r = 0; r < 4; r++) {
      float t = fmaxf(fmaxf(sc[0][r], sc[1][r]), fmaxf(sc[2][r], sc[3][r]));
#pragma unroll
      for (int d = 1; d < 16; d <<= 1) t = fmaxf(t, __shfl_xor(t, d));
      const float mn = fmaxf(m_[r], t);
      esc[r] = __expf(m_[r] - mn);
      m_[r] = mn;
      rs[r] = 0.f;
    }
#pragma unroll
    for (int n = 0; n < 4; n++) {
#pragma unroll
      for (int r = 0; r < 4; r++) {
        const float p = __expf(sc[n][r] - m_[r]);
        rs[r] += p;
        sc[n][r] = p;
      }
    }
#pragma unroll
    for (int r = 0; r < 4; r++) {
#pragma unroll
      for (int d = 1; d < 16; d <<= 1) rs[r] += __shfl_xor(rs[r], d);
      l_[r] = l_[r] * esc[r] + rs[r];
      acc[0][r] *= esc[r]; acc[1][r] *= esc[r];
      acc[2][r] *= esc[r]; acc[3][r] *= esc[r];
    }
#pragma unroll
    for (int n = 0; n < 4; n++) {
#pragma unroll
      for (int r = 0; r < 4; r++)
        Pl[16 * w + 4 * lq + r][16 * n + l15] = sc[n][r];
    }
#pragma unroll
    for (int c = 0; c < 2; c++) {
      f4 p0 = *(const f4*)&Pl[16 * w + l15][c * 32 + lq * 8];
      f4 p1 = *(const f4*)&Pl[16 * w + l15][c * 32 + lq * 8 + 4];
      short8 ph, pl_;
#pragma unroll
      for (int j = 0; j < 8; j++) {
        const float x = (j < 4) ? p0[j] : p1[j - 4];
        const unsigned short hh = f2bf(x);
        ph[j] = (short)hh;
        pl_[j] = (short)f2bf(x - bf2f(hh));
      }
      short8 vfh[4], vfl[4];
#pragma unroll
      for (int n = 0; n < 4; n++) {
        vfh[n] = *(const short8*)&VhL[16 * n + l15][c * 32 + lq * 8];
        vfl[n] = *(const short8*)&VlL[16 * n + l15][c * 32 + lq * 8];
      }
#pragma unroll
      for (int n = 0; n < 4; n++) {
        acc[n] = __builtin_amdgcn_mfma_f32_16x16x32_bf16(ph, vfh[n], acc[n], 0, 0, 0);
        acc[n] = __builtin_amdgcn_mfma_f32_16x16x32_bf16(ph, vfl[n], acc[n], 0, 0, 0);
        acc[n] = __builtin_amdgcn_mfma_f32_16x16x32_bf16(pl_, vfh[n], acc[n], 0, 0, 0);
      }
    }
    __syncthreads();
  }
#pragma unroll
  for (int r = 0; r < 4; r++) {
    const float inv = 1.f / l_[r];
    const int srow = q0 + 16 * w + 4 * lq + r;
    float* orow = &O[((size_t)srow * BATCH + b) * DIM + h * HDIM];
#pragma unroll
    for (int n = 0; n < 4; n++) orow[16 * n + l15] = acc[n][r] * inv;
  }
}

// ---------------- layernorm: x = LN(src + proj)*g + b -> out ----------------
__global__ __launch_bounds__(256) void k_ln(const float* __restrict__ src,
                                            const float* __restrict__ proj,
                                            const float* __restrict__ g,
                                            const float* __restrict__ bt,
                                            float* __restrict__ xout) {
  const int wid = threadIdx.x >> 6, lane = threadIdx.x & 63;
  const int tok = blockIdx.x * 4 + wid;
  const size_t base = (size_t)tok * DIM + lane * 8;
  f4 a0 = *(const f4*)&src[base],  a1 = *(const f4*)&src[base + 4];
  f4 p0 = *(const f4*)&proj[base], p1 = *(const f4*)&proj[base + 4];
  float x[8];
  x[0] = a0[0] + p0[0]; x[1] = a0[1] + p0[1]; x[2] = a0[2] + p0[2]; x[3] = a0[3] + p0[3];
  x[4] = a1[0] + p1[0]; x[5] = a1[1] + p1[1]; x[6] = a1[2] + p1[2]; x[7] = a1[3] + p1[3];
  float s = 0.f, sq = 0.f;
#pragma unroll
  for (int j = 0; j < 8; j++) { s += x[j]; sq = fmaf(x[j], x[j], sq); }
#pragma unroll
  for (int d = 1; d < 64; d <<= 1) { s += __shfl_xor(s, d); sq += __shfl_xor(sq, d); }
  const float mean = s * (1.f / 512.f);
  const float var = sq * (1.f / 512.f) - mean * mean;
  const float rstd = 1.f / sqrtf(var + 1e-5f);
  const int ci = lane * 8;
  f4 o0v, o1v;
#pragma unroll
  for (int j = 0; j < 4; j++) o0v[j] = (x[j] - mean) * rstd * g[ci + j] + bt[ci + j];
#pragma unroll
  for (int j = 0; j < 4; j++) o1v[j] = (x[4 + j] - mean) * rstd * g[ci + 4 + j] + bt[ci + 4 + j];
  *(f4*)&xout[base] = o0v;
  *(f4*)&xout[base + 4] = o1v;
}

// ---------------- gate: block = 16 tokens x 16 experts, 4 tiles ----------------
__global__ __launch_bounds__(256) void k_gate(const float* __restrict__ x,
                                              const float* __restrict__ gw,
                                              const float* __restrict__ gb,
                                              int* __restrict__ topi,
                                              float* __restrict__ topw,
                                              int* __restrict__ counts) {
  __shared__ float xs[16 * 520];
  __shared__ int hist[16];
  const int tid = threadIdx.x;
  const int tl = tid >> 4, e = tid & 15;
  if (tid < 16) hist[tid] = 0;
  const float gbe = gb[e];
  const float* wrow = gw + (size_t)e * DIM;
  for (int tile = 0; tile < 4; tile++) {
    const int t0 = blockIdx.x * 64 + tile * 16;
    __syncthreads();
    {
      const int r = tid >> 4, cbase = (tid & 15) * 32;
#pragma unroll
      for (int j = 0; j < 8; j++) {
        const int c = cbase + j * 4;
        const int ch = c >> 2;
        const int pc = ch ^ ((ch >> 3) & 7);
        *(f4*)&xs[r * 520 + pc * 4] = *(const f4*)&x[(size_t)(t0 + r) * DIM + c];
      }
    }
    __syncthreads();
    float d = gbe;
#pragma unroll 8
    for (int c = 0; c < DIM; c += 4) {
      const int ch = c >> 2;
      const int pc = ch ^ ((ch >> 3) & 7);
      f4 xv = *(const f4*)&xs[tl * 520 + pc * 4];
      f4 wv = *(const f4*)&wrow[c];
      d = fmaf(xv[0], wv[0], d); d = fmaf(xv[1], wv[1], d);
      d = fmaf(xv[2], wv[2], d); d = fmaf(xv[3], wv[3], d);
    }
    float v1 = d, v2 = -1e30f;
    int i1 = e, i2 = 1000;
#pragma unroll
    for (int s = 1; s < 16; s <<= 1) {
      const float ov1 = __shfl_xor(v1, s), ov2 = __shfl_xor(v2, s);
      const int oi1 = __shfl_xor(i1, s), oi2 = __shfl_xor(i2, s);
      if (ov1 > v1 || (ov1 == v1 && oi1 < i1)) {
        float nv2; int ni2;
        if (v1 > ov2 || (v1 == ov2 && i1 < oi2)) { nv2 = v1; ni2 = i1; }
        else { nv2 = ov2; ni2 = oi2; }
        v1 = ov1; i1 = oi1; v2 = nv2; i2 = ni2;
      } else if (ov1 > v2 || (ov1 == v2 && oi1 < i2)) {
        v2 = ov1; i2 = oi1;
      }
    }
    if (e == 0) {
      const int t = t0 + tl;
      const float e1 = __expf(v2 - v1);
      const float inv = 1.f / (1.f + e1);
      topi[2 * t] = i1;  topi[2 * t + 1] = i2;
      topw[2 * t] = inv; topw[2 * t + 1] = e1 * inv;
      atomicAdd(&hist[i1], 1);
      atomicAdd(&hist[i2], 1);
    }
  }
  __syncthreads();
  if (tid < 16 && hist[tid] > 0) atomicAdd(&counts[tid], hist[tid]);
}

__global__ void k_offsets(const int* __restrict__ counts,
                          int* __restrict__ off_pad, int* __restrict__ cursor) {
  if (threadIdx.x == 0) {
    int o = 0;
    off_pad[0] = 0;
    for (int e = 0; e < NE; e++) {
      cursor[e] = 0;
      o += ((counts[e] + BM - 1) / BM) * BM;
      off_pad[e + 1] = o;
    }
  }
}

// ---------------- scatter: batched slot claims, no hot-address storm ----------------
// grid 256 x 256 threads; block handles 128 assignments.
// Phase A: LDS histogram rank + one global atomic per (block, expert).
// Phase B: 4 waves x 32 rows, vectorized fp32->bf16 gather.
__global__ __launch_bounds__(256) void k_scatter(const float* __restrict__ x,
                                                 const int* __restrict__ topi,
                                                 const float* __restrict__ topw,
                                                 const int* __restrict__ off_pad,
                                                 int* __restrict__ cursor,
                                                 int* __restrict__ slotTok,
                                                 float* __restrict__ slotW,
                                                 unsigned short* __restrict__ Xg) {
  __shared__ int lcnt[16];
  __shared__ int gbase[16];
  __shared__ int posArr[128];
  const int tid = threadIdx.x;
  const int a0 = blockIdx.x * 128;
  if (tid < 16) lcnt[tid] = 0;
  __syncthreads();
  if (tid < 128) {
    const int a = a0 + tid;
    const int e = topi[a];
    const int lrank = atomicAdd(&lcnt[e], 1);
    posArr[tid] = (e << 24) | lrank;     // stash; resolved after gbase
  }
  __syncthreads();
  if (tid < 16) {
    const int c = lcnt[tid];
    gbase[tid] = (c > 0) ? atomicAdd(&cursor[tid], c) : 0;
  }
  __syncthreads();
  if (tid < 128) {
    const int a = a0 + tid;
    const int pk = posArr[tid];
    const int e = pk >> 24, lrank = pk & 0xffffff;
    const int pos = off_pad[e] + gbase[e] + lrank;
    posArr[tid] = pos;
    slotTok[pos] = a >> 1;
    slotW[pos] = topw[a];
  }
  __syncthreads();
  const int w = tid >> 6, lane = tid & 63;
#pragma unroll 4
  for (int i = 0; i < 32; i++) {
    const int idx = w * 32 + i;
    const int pos = posArr[idx];
    const int tok = (a0 + idx) >> 1;
    const size_t sb = (size_t)tok * DIM + lane * 8;
    f4 v0 = *(const f4*)&x[sb], v1 = *(const f4*)&x[sb + 4];
    u16x8 hh;
    hh[0] = f2bf(v0[0]); hh[1] = f2bf(v0[1]); hh[2] = f2bf(v0[2]); hh[3] = f2bf(v0[3]);
    hh[4] = f2bf(v1[0]); hh[5] = f2bf(v1[1]); hh[6] = f2bf(v1[2]); hh[7] = f2bf(v1[3]);
    *(u16x8*)&Xg[(size_t)pos * DIM + lane * 8] = hh;
  }
}

// ---------------- grouped bf16 MFMA GEMM (MoE), T2-swizzled LDS ----------------
__global__ __launch_bounds__(256) void k_gemm_bf16(
    const unsigned short* __restrict__ A, int lda,
    const unsigned short* __restrict__ Wb, size_t westride, int ldw, int wrow0,
    const float* __restrict__ bias, int bstride, int brow0,
    int K, int epi,
    unsigned short* __restrict__ Hout, int ldh,
    float* __restrict__ dout,
    const int* __restrict__ slotTok, const float* __restrict__ slotW,
    const int* __restrict__ off_pad) {
  const int m0 = blockIdx.x * BM;
  if (m0 >= off_pad[NE]) return;
  int e = 0;
  while (off_pad[e + 1] <= m0) e++;
  const unsigned short* W = Wb + (size_t)e * westride;
  const int n0 = blockIdx.y * 128;
  __shared__ unsigned short Al[128 * 64];
  __shared__ unsigned short Bl[128 * 64];
  const int tid = threadIdx.x, lane = tid & 63, wid = tid >> 6;
  const int wm = wid >> 1, wn = wid & 1;
  f32x4 acc[4][4] = {};
  const int srow = wid * 32 + (lane >> 3);
  const int scol = (((lane & 7) ^ ((lane >> 3) & 7)) << 3);
  for (int k0 = 0; k0 < K; k0 += 64) {
    const unsigned short* ga = A + (size_t)(m0 + srow) * lda + k0 + scol;
    const unsigned short* gw = W + (size_t)(wrow0 + n0 + srow) * ldw + k0 + scol;
#pragma unroll
    for (int i = 0; i < 4; i++) {
      load_lds16(ga + (size_t)i * 8 * lda, &Al[(wid * 32 + i * 8) * 64]);
      load_lds16(gw + (size_t)i * 8 * ldw, &Bl[(wid * 32 + i * 8) * 64]);
    }
    __syncthreads();
#pragma unroll
    for (int kk = 0; kk < 2; kk++) {
      short8 av[4], bv[4];
      const int ckx = (kk * 4 + (lane >> 4)) ^ (lane & 7);
#pragma unroll
      for (int mi = 0; mi < 4; mi++)
        av[mi] = *(const short8*)&Al[(wm * 64 + mi * 16 + (lane & 15)) * 64 + ckx * 8];
#pragma unroll
      for (int ni = 0; ni < 4; ni++)
        bv[ni] = *(const short8*)&Bl[(wn * 64 + ni * 16 + (lane & 15)) * 64 + ckx * 8];
#pragma unroll
      for (int mi = 0; mi < 4; mi++) {
#pragma unroll
        for (int ni = 0; ni < 4; ni++)
          acc[mi][ni] = __builtin_amdgcn_mfma_f32_16x16x32_bf16(av[mi], bv[ni], acc[mi][ni], 0, 0, 0);
      }
    }
    __syncthreads();
  }
#pragma unroll
  for (int mi = 0; mi < 4; mi++) {
    const int rb = m0 + wm * 64 + mi * 16 + ((lane >> 4) << 2);
#pragma unroll
    for (int ni = 0; ni < 4; ni++) {
      const int n = n0 + wn * 64 + ni * 16 + (lane & 15);
      const float bn = bias ? bias[(size_t)e * bstride + brow0 + n] : 0.f;
      if (epi == 0) {
#pragma unroll
        for (int r = 0; r < 4; r++) {
          float v = acc[mi][ni][r] + bn;
          v = fmaxf(v, 0.f);
          Hout[(size_t)(rb + r) * ldh + n] = f2bf(v);
        }
      } else {
#pragma unroll
        for (int r = 0; r < 4; r++) {
          const int tok = slotTok[rb + r];
          if (tok >= 0) {
            const float v = (acc[mi][ni][r] + bn) * slotW[rb + r];
            atomicAdd(&dout[(size_t)tok * DIM + n], v);
          }
        }
      }
    }
  }
}

// ---------------- launch ----------------
extern "C" void kernel_launch(void* const* d_in, const int* in_sizes, int n_in,
                              void* d_out, int out_size, void* d_ws, size_t ws_size,
                              hipStream_t stream) {
  const float* src       = (const float*)d_in[0];
  const float* pos       = (const float*)d_in[1];
  const float* in_proj_w = (const float*)d_in[2];
  const float* in_proj_b = (const float*)d_in[3];
  const float* out_w     = (const float*)d_in[4];
  const float* out_b     = (const float*)d_in[5];
  const float* norm1_g   = (const float*)d_in[6];
  const float* norm1_b   = (const float*)d_in[7];
  const float* gate_w    = (const float*)d_in[8];
  const float* gate_b    = (const float*)d_in[9];
  const float* w1        = (const float*)d_in[10];
  const float* b1        = (const float*)d_in[11];
  const float* w2        = (const float*)d_in[12];
  const float* b2        = (const float*)d_in[13];
  float* out = (float*)d_out;
  char* wsb = (char*)d_ws;

  // ---- lifetime-packed arena (~166.5 MiB, unchanged footprint) ----
  unsigned short* Qhp = (unsigned short*)(wsb + 0);
  unsigned short* Qlp = (unsigned short*)(wsb + 16777216);
  unsigned short* Khp = (unsigned short*)(wsb + 33554432);
  unsigned short* Klp = (unsigned short*)(wsb + 50331648);
  unsigned short* Vhp = (unsigned short*)(wsb + 67108864);
  unsigned short* Vlp = (unsigned short*)(wsb + 83886080);
  float* ob = (float*)(wsb + 100663296);
  float* proj = (float*)(wsb + 0);
  unsigned short* w1b = (unsigned short*)(wsb + 0);
  unsigned short* w2b = (unsigned short*)(wsb + 33554432);
  unsigned short* Xg  = (unsigned short*)(wsb + 67108864);
  unsigned short* Hb  = (unsigned short*)(wsb + 102760448);
  unsigned short* wih = (unsigned short*)(wsb + 134217728);
  unsigned short* wil = (unsigned short*)(wsb + 135790592);
  char* smallb = wsb + 174063616;
  int*   topi    = (int*)  (smallb + 0);
  float* topw    = (float*)(smallb + 131072);
  int*   slotTok = (int*)  (smallb + 262144);
  float* slotW   = (float*)(smallb + 401408);
  int*   counts  = (int*)  (smallb + 540672);
  int*   off_pad = (int*)  (smallb + 540736);
  int*   cursor  = (int*)  (smallb + 540864);

  // 1. routing init + in_proj weight split
  k_init<<<(CAP + 255) / 256, 256, 0, stream>>>(slotTok, slotW, counts);
  k_split_w<<<768, 256, 0, stream>>>(in_proj_w, wih, wil, (size_t)1536 * 512);
  // 2. Q/K projection (split MFMA, fused src+pos) -> hi/lo planes [B,H,S,HD]
  k_gemm_split<<<dim3(128, 8), 256, 0, stream>>>(src, pos, wih, wil, in_proj_b, 0,
                                                 Qhp, Qlp, Khp, Klp);
  // 3. V projection -> hi/lo planes [B,H,HD,S]
  k_gemm_split<<<dim3(128, 4), 256, 0, stream>>>(src, nullptr, wih + (size_t)1024 * 512,
                                                 wil + (size_t)1024 * 512, in_proj_b + 1024,
                                                 1, Vhp, Vlp, nullptr, nullptr);
  // 4. split-MFMA flash attention -> ob [S,B,D]
  k_attn<<<dim3(16, 128), 256, 0, stream>>>(Qhp, Qlp, Khp, Klp, Vhp, Vlp, ob);
  // 5. w2 -> bf16 (K planes dead)
  k_cvt_bf16<<<2048, 256, 0, stream>>>(w2, w2b, (size_t)NE * DIM * DFF);
  // 6. output projection (fp32 vector — gate-critical) -> proj (over Q planes)
  k_gemm_f32<<<dim3(128, 4), 256, 0, stream>>>(ob, out_w, out_b, 512, proj);
  // 7. layernorm(src + proj) -> d_out (= x)
  k_ln<<<4096, 256, 0, stream>>>(src, proj, norm1_g, norm1_b, out);
  // 8. w1 -> bf16 (proj dead)
  k_cvt_bf16<<<2048, 256, 0, stream>>>(w1, w1b, (size_t)NE * DFF * DIM);
  // 9. gate logits + top2 + counts
  k_gate<<<T_TOK / 64, 256, 0, stream>>>(out, gate_w, gate_b, topi, topw, counts);
  // 10. padded segment offsets
  k_offsets<<<1, 64, 0, stream>>>(counts, off_pad, cursor);
  // 11. zero gathered-token buffer
  k_zero<<<2048, 256, 0, stream>>>((u32x4*)Xg, (size_t)CAP * DIM * 2 / 16);
  // 12. scatter assignments + gather token rows as bf16 (batched claims)
  k_scatter<<<256, 256, 0, stream>>>(out, topi, topw, off_pad, cursor, slotTok, slotW, Xg);
  // 13. MoE, DFF halved
  for (int p = 0; p < 2; ++p) {
    k_gemm_bf16<<<dim3(CAP / BM, 8), 256, 0, stream>>>(
        Xg, DIM, w1b, (size_t)DFF * DIM, DIM, p * 1024,
        b1, DFF, p * 1024, DIM, 0, Hb, 1024,
        nullptr, nullptr, nullptr, off_pad);
    k_gemm_bf16<<<dim3(CAP / BM, 4), 256, 0, stream>>>(
        Hb, 1024, w2b + (size_t)p * 1024, (size_t)DIM * DFF, DFF, 0,
        (p == 0 ? b2 : nullptr), DIM, 0, 1024, 1, nullptr, 0,
        out, slotTok, slotW, off_pad);
  }
}

// Round 8
// 1121.407 us; speedup vs baseline: 2.2415x; 1.0274x over previous
//
#include <hip/hip_runtime.h>
#include <hip/hip_bf16.h>

// ---------------- types ----------------
typedef float f4 __attribute__((ext_vector_type(4)));
typedef float f32x4 __attribute__((ext_vector_type(4)));
typedef short short8 __attribute__((ext_vector_type(8)));
typedef unsigned short u16x4 __attribute__((ext_vector_type(4)));
typedef unsigned short u16x8 __attribute__((ext_vector_type(8)));
typedef unsigned int u32x4 __attribute__((ext_vector_type(4)));

// ---------------- problem constants ----------------
#define S_LEN 1024
#define BATCH 16
#define DIM   512
#define NH    8
#define HDIM  64
#define NE    16
#define DFF   2048
#define T_TOK 16384   // S*B
#define CAP   34816   // 32768 assignments + per-expert padding to BM
#define BM    128

__device__ __forceinline__ unsigned short f2bf(float f) {
  union { float f; unsigned u; } v; v.f = f;
  unsigned r = v.u + 0x7fffu + ((v.u >> 16) & 1u);  // RTNE
  return (unsigned short)(r >> 16);
}
__device__ __forceinline__ float bf2f(unsigned short h) {
  union { unsigned u; float f; } v; v.u = ((unsigned)h) << 16;
  return v.f;
}

__device__ __forceinline__ void load_lds16(const void* g, void* l) {
  __builtin_amdgcn_global_load_lds(
      (__attribute__((address_space(1))) void*)(void*)g,
      (__attribute__((address_space(3))) void*)l, 16, 0, 0);
}

// pack 8 u32 (hi16|lo16) into hi-plane / lo-plane bf16x8 operands
__device__ __forceinline__ short8 pack_hi8(const unsigned* val) {
  union { unsigned u[4]; short8 s; } t;
#pragma unroll
  for (int i = 0; i < 4; i++)
    t.u[i] = (val[2 * i] >> 16) | (val[2 * i + 1] & 0xFFFF0000u);
  return t.s;
}
__device__ __forceinline__ short8 pack_lo8(const unsigned* val) {
  union { unsigned u[4]; short8 s; } t;
#pragma unroll
  for (int i = 0; i < 4; i++)
    t.u[i] = (val[2 * i] & 0xFFFFu) | (val[2 * i + 1] << 16);
  return t.s;
}

// ---------------- small utility kernels ----------------
__global__ __launch_bounds__(256) void k_cvt_bf16(const float* __restrict__ in,
                                                  unsigned short* __restrict__ outb,
                                                  size_t n) {
  size_t i = ((size_t)blockIdx.x * 256 + threadIdx.x) * 4;
  size_t stride = (size_t)gridDim.x * 1024;
  for (; i < n; i += stride) {
    f4 v = *(const f4*)&in[i];
    u16x4 o;
    o[0] = f2bf(v[0]); o[1] = f2bf(v[1]); o[2] = f2bf(v[2]); o[3] = f2bf(v[3]);
    *(u16x4*)&outb[i] = o;
  }
}

// split fp32 -> bf16 hi + bf16 lo (lo = round(x - hi))
__global__ __launch_bounds__(256) void k_split_w(const float* __restrict__ in,
                                                 unsigned short* __restrict__ hi,
                                                 unsigned short* __restrict__ lo,
                                                 size_t n) {
  size_t i = ((size_t)blockIdx.x * 256 + threadIdx.x) * 4;
  size_t stride = (size_t)gridDim.x * 1024;
  for (; i < n; i += stride) {
    f4 v = *(const f4*)&in[i];
    u16x4 h, l;
#pragma unroll
    for (int j = 0; j < 4; j++) {
      unsigned short hh = f2bf(v[j]);
      h[j] = hh;
      l[j] = f2bf(v[j] - bf2f(hh));
    }
    *(u16x4*)&hi[i] = h;
    *(u16x4*)&lo[i] = l;
  }
}

__global__ __launch_bounds__(256) void k_init(int* __restrict__ slotTok,
                                              float* __restrict__ slotW,
                                              int* __restrict__ counts) {
  int i = blockIdx.x * 256 + threadIdx.x;
  if (i < CAP) { slotTok[i] = -1; slotW[i] = 0.f; }
  if (i < NE) counts[i] = 0;
}

// zero only the padding rows of each expert segment (<=2 MB instead of 35 MB)
__global__ __launch_bounds__(256) void k_zero_pad(const int* __restrict__ counts,
                                                  const int* __restrict__ off_pad,
                                                  unsigned short* __restrict__ Xg) {
  const int e = blockIdx.x;
  const int start = off_pad[e] + counts[e];
  const int end = off_pad[e + 1];
  for (int row = start; row < end; row++)
    *(unsigned int*)&Xg[(size_t)row * DIM + threadIdx.x * 2] = 0u;
}

// ---------------- split-bf16 MFMA GEMM (fp32-accurate via hi/lo) ----------------
// C = (A [+A2])[M,512] * W[N,512]^T + bias, W pre-split into Wh/Wl bf16.
// epi 0: n<512 -> Q*0.125 split-> (o0h,o0l) [B,H,S,HD]; n>=512 -> K split-> (o1h,o1l)
// epi 1: V split-> (o0h,o0l) [B,H,HD,S]
__global__ __launch_bounds__(256, 2) void k_gemm_split(
    const float* __restrict__ A, const float* __restrict__ A2,
    const unsigned short* __restrict__ Wh, const unsigned short* __restrict__ Wl,
    const float* __restrict__ bias, int epi,
    unsigned short* __restrict__ o0h, unsigned short* __restrict__ o0l,
    unsigned short* __restrict__ o1h, unsigned short* __restrict__ o1l) {
  __shared__ unsigned short AhL[128 * 32];
  __shared__ unsigned short AlL[128 * 32];
  __shared__ unsigned short WhL[128 * 32];
  __shared__ unsigned short WlL[128 * 32];
  const int tid = threadIdx.x, lane = tid & 63, wid = tid >> 6;
  const int wm = wid >> 1, wn = wid & 1;
  const int m0 = blockIdx.x * 128, n0 = blockIdx.y * 128;
  const int row = tid >> 1, half = tid & 1;
  const int xr = (row >> 1) & 3;
  f32x4 acc[4][4] = {};
  f4 ar[4];
#pragma unroll
  for (int j = 0; j < 4; j++) {
    const size_t aoff = (size_t)(m0 + row) * 512 + half * 16 + j * 4;
    ar[j] = *(const f4*)&A[aoff];
    if (A2) { f4 v2 = *(const f4*)&A2[aoff]; ar[j] += v2; }
  }
  for (int k0 = 0; k0 < 512; k0 += 32) {
    __syncthreads();
    u16x8 hi8[2], lo8[2];
#pragma unroll
    for (int j = 0; j < 16; j++) {
      const float x = ar[j >> 2][j & 3];
      const unsigned short h = f2bf(x);
      hi8[j >> 3][j & 7] = h;
      lo8[j >> 3][j & 7] = f2bf(x - bf2f(h));
    }
    const int c0 = half * 2;
    *(u16x8*)&AhL[row * 32 + (((c0 + 0) ^ xr) << 3)] = hi8[0];
    *(u16x8*)&AhL[row * 32 + (((c0 + 1) ^ xr) << 3)] = hi8[1];
    *(u16x8*)&AlL[row * 32 + (((c0 + 0) ^ xr) << 3)] = lo8[0];
    *(u16x8*)&AlL[row * 32 + (((c0 + 1) ^ xr) << 3)] = lo8[1];
#pragma unroll
    for (int i = 0; i < 2; i++) {
      const int rowW = i * 64 + wid * 16 + (lane >> 2);
      const int clog = (lane & 3) ^ ((rowW >> 1) & 3);
      const size_t woff = (size_t)(n0 + rowW) * 512 + k0 + (clog << 3);
      load_lds16(Wh + woff, &WhL[i * 2048 + wid * 512]);
      load_lds16(Wl + woff, &WlL[i * 2048 + wid * 512]);
    }
    __syncthreads();
    if (k0 + 32 < 512) {
#pragma unroll
      for (int j = 0; j < 4; j++) {
        const size_t aoff = (size_t)(m0 + row) * 512 + k0 + 32 + half * 16 + j * 4;
        ar[j] = *(const f4*)&A[aoff];
        if (A2) { f4 v2 = *(const f4*)&A2[aoff]; ar[j] += v2; }
      }
    }
    const int l15 = lane & 15, lk = lane >> 4;
    const int xa = (l15 >> 1) & 3;
    short8 avh[4], avl[4], bvh[4], bvl[4];
#pragma unroll
    for (int mi = 0; mi < 4; mi++) {
      const int mr = wm * 64 + mi * 16 + l15;
      avh[mi] = *(const short8*)&AhL[mr * 32 + ((lk ^ xa) << 3)];
      avl[mi] = *(const short8*)&AlL[mr * 32 + ((lk ^ xa) << 3)];
    }
#pragma unroll
    for (int ni = 0; ni < 4; ni++) {
      const int nr = wn * 64 + ni * 16 + l15;
      bvh[ni] = *(const short8*)&WhL[nr * 32 + ((lk ^ xa) << 3)];
      bvl[ni] = *(const short8*)&WlL[nr * 32 + ((lk ^ xa) << 3)];
    }
#pragma unroll
    for (int mi = 0; mi < 4; mi++) {
#pragma unroll
      for (int ni = 0; ni < 4; ni++) {
        acc[mi][ni] = __builtin_amdgcn_mfma_f32_16x16x32_bf16(avh[mi], bvh[ni], acc[mi][ni], 0, 0, 0);
        acc[mi][ni] = __builtin_amdgcn_mfma_f32_16x16x32_bf16(avh[mi], bvl[ni], acc[mi][ni], 0, 0, 0);
        acc[mi][ni] = __builtin_amdgcn_mfma_f32_16x16x32_bf16(avl[mi], bvh[ni], acc[mi][ni], 0, 0, 0);
      }
    }
  }
#pragma unroll
  for (int mi = 0; mi < 4; mi++) {
    const int rb = m0 + wm * 64 + mi * 16 + ((lane >> 4) << 2);
#pragma unroll
    for (int ni = 0; ni < 4; ni++) {
      const int n = n0 + wn * 64 + ni * 16 + (lane & 15);
      const float bn = bias[n];
#pragma unroll
      for (int r = 0; r < 4; r++) {
        const int m = rb + r;
        const int bidx = m & 15, ss = m >> 4;
        float v = acc[mi][ni][r] + bn;
        if (epi == 0) {
          if (n < 512) {
            v *= 0.125f;
            const size_t off = ((size_t)(bidx * NH + (n >> 6)) * S_LEN + ss) * HDIM + (n & 63);
            const unsigned short hh = f2bf(v);
            o0h[off] = hh; o0l[off] = f2bf(v - bf2f(hh));
          } else {
            const int n2 = n - 512;
            const size_t off = ((size_t)(bidx * NH + (n2 >> 6)) * S_LEN + ss) * HDIM + (n2 & 63);
            const unsigned short hh = f2bf(v);
            o1h[off] = hh; o1l[off] = f2bf(v - bf2f(hh));
          }
        } else {
          const size_t off = ((size_t)(bidx * NH + (n >> 6)) * HDIM + (n & 63)) * S_LEN + ss;
          const unsigned short hh = f2bf(v);
          o0h[off] = hh; o0l[off] = f2bf(v - bf2f(hh));
        }
      }
    }
  }
}

// ---------------- fp32 GEMM (out-proj only): C = A[M,K]*W[N,K]^T + bias ----------------
__global__ __launch_bounds__(256, 3) void k_gemm_f32(
    const float* __restrict__ A, const float* __restrict__ W,
    const float* __restrict__ bias, int K,
    float* __restrict__ o0) {
  __shared__ float Alt[32][132];
  __shared__ float Wlt[32][132];
  const int tid = threadIdx.x, tx = tid & 15, ty = tid >> 4;
  const int m0 = blockIdx.x * 128, n0 = blockIdx.y * 128;
  float acc[8][8];
#pragma unroll
  for (int i = 0; i < 8; i++) {
#pragma unroll
    for (int j = 0; j < 8; j++) acc[i][j] = 0.f;
  }
  f4 ar[4], wr[4];
#pragma unroll
  for (int i = 0; i < 4; i++) {
    const int c = tid + i * 256;
    const int r = c >> 3, j = (c & 7) * 4;
    ar[i] = *(const f4*)&A[(size_t)(m0 + r) * K + j];
    wr[i] = *(const f4*)&W[(size_t)(n0 + r) * K + j];
  }
  for (int k0 = 0; k0 < K; k0 += 32) {
    __syncthreads();
#pragma unroll
    for (int i = 0; i < 4; i++) {
      const int c = tid + i * 256;
      const int r = c >> 3, j = (c & 7) * 4;
      Alt[j + 0][r] = ar[i][0]; Alt[j + 1][r] = ar[i][1];
      Alt[j + 2][r] = ar[i][2]; Alt[j + 3][r] = ar[i][3];
      Wlt[j + 0][r] = wr[i][0]; Wlt[j + 1][r] = wr[i][1];
      Wlt[j + 2][r] = wr[i][2]; Wlt[j + 3][r] = wr[i][3];
    }
    __syncthreads();
    if (k0 + 32 < K) {
#pragma unroll
      for (int i = 0; i < 4; i++) {
        const int c = tid + i * 256;
        const int r = c >> 3, j = (c & 7) * 4;
        ar[i] = *(const f4*)&A[(size_t)(m0 + r) * K + k0 + 32 + j];
        wr[i] = *(const f4*)&W[(size_t)(n0 + r) * K + k0 + 32 + j];
      }
    }
#pragma unroll 4
    for (int kk = 0; kk < 32; kk++) {
      float a[8], w8[8];
      *(f4*)&a[0]  = *(const f4*)&Alt[kk][ty * 8];
      *(f4*)&a[4]  = *(const f4*)&Alt[kk][ty * 8 + 4];
      *(f4*)&w8[0] = *(const f4*)&Wlt[kk][tx * 8];
      *(f4*)&w8[4] = *(const f4*)&Wlt[kk][tx * 8 + 4];
#pragma unroll
      for (int mi = 0; mi < 8; mi++) {
#pragma unroll
        for (int ni = 0; ni < 8; ni++)
          acc[mi][ni] = fmaf(a[mi], w8[ni], acc[mi][ni]);
      }
    }
  }
#pragma unroll
  for (int mi = 0; mi < 8; mi++) {
    const size_t m = (size_t)(m0 + ty * 8 + mi);
#pragma unroll
    for (int nj = 0; nj < 2; nj++) {
      const int n = n0 + tx * 8 + nj * 4;
      f4 v;
      v[0] = acc[mi][nj * 4 + 0] + bias[n + 0];
      v[1] = acc[mi][nj * 4 + 1] + bias[n + 1];
      v[2] = acc[mi][nj * 4 + 2] + bias[n + 2];
      v[3] = acc[mi][nj * 4 + 3] + bias[n + 3];
      *(f4*)&o0[m * 512 + n] = v;
    }
  }
}

// ---------------- split-bf16 MFMA flash attention, in-register P ----------------
// Swapped QK^T: sc[n] = mfma(K_frag, Q_frag) -> lane holds P[q=l15][k=16n+4lq+r].
// P packed (bf16hi<<16|bf16lo), redistributed to PV A-fragments via 4-lane shfl.
// No P LDS tile -> 36,864 B LDS.
__global__ __launch_bounds__(256, 3) void k_attn(
    const unsigned short* __restrict__ Qhp, const unsigned short* __restrict__ Qlp,
    const unsigned short* __restrict__ Khp, const unsigned short* __restrict__ Klp,
    const unsigned short* __restrict__ Vhp, const unsigned short* __restrict__ Vlp,
    float* __restrict__ O) {
  const int q0 = blockIdx.x * 64;
  const int bh = blockIdx.y;
  const int b = bh >> 3, h = bh & 7;
  const size_t base = (size_t)bh * (S_LEN * HDIM);
  __shared__ unsigned short KhL[64][72], KlL[64][72];
  __shared__ unsigned short VhL[64][72], VlL[64][72];
  const int tid = threadIdx.x, lane = tid & 63, w = tid >> 6;
  const int l15 = lane & 15, lq = lane >> 4;
  // P redistribution source lanes (within this wave)
  const int srcA = l15 + 16 * ((2 * lq) & 3);
  const int srcB = l15 + 16 * ((2 * lq + 1) & 3);
  const bool selHi = (lane & 32) != 0;   // lq >= 2 -> needs pk[2c+1]
  // Q fragments (B-operand): col=l15 <-> q-row q0+16w+l15, d-chunk lq*8 (+c*32)
  short8 qh[2], ql[2];
  {
    const size_t qoff = base + (size_t)(q0 + 16 * w + l15) * HDIM + lq * 8;
    qh[0] = *(const short8*)&Qhp[qoff];
    ql[0] = *(const short8*)&Qlp[qoff];
    qh[1] = *(const short8*)&Qhp[qoff + 32];
    ql[1] = *(const short8*)&Qlp[qoff + 32];
  }
  const int sr = tid >> 2, sq = (tid & 3) * 16;
  u16x8 krh[2], krl[2], vrh[2], vrl[2];
  {
    const size_t ko = base + (size_t)sr * HDIM + sq;
    krh[0] = *(const u16x8*)&Khp[ko]; krh[1] = *(const u16x8*)&Khp[ko + 8];
    krl[0] = *(const u16x8*)&Klp[ko]; krl[1] = *(const u16x8*)&Klp[ko + 8];
    const size_t vo = base + (size_t)sr * S_LEN + sq;
    vrh[0] = *(const u16x8*)&Vhp[vo]; vrh[1] = *(const u16x8*)&Vhp[vo + 8];
    vrl[0] = *(const u16x8*)&Vlp[vo]; vrl[1] = *(const u16x8*)&Vlp[vo + 8];
  }
  float m_ = -1e30f, l_ = 0.f;          // per-lane, q-row = q0+16w+l15
  f32x4 acc[4] = {};                    // acc[n][r]: q-rel=4lq+r, d=16n+l15

  for (int kt = 0; kt < 16; kt++) {
    *(u16x8*)&KhL[sr][sq + 0] = krh[0]; *(u16x8*)&KhL[sr][sq + 8] = krh[1];
    *(u16x8*)&KlL[sr][sq + 0] = krl[0]; *(u16x8*)&KlL[sr][sq + 8] = krl[1];
    *(u16x8*)&VhL[sr][sq + 0] = vrh[0]; *(u16x8*)&VhL[sr][sq + 8] = vrh[1];
    *(u16x8*)&VlL[sr][sq + 0] = vrl[0]; *(u16x8*)&VlL[sr][sq + 8] = vrl[1];
    __syncthreads();
    if (kt < 15) {   // T14: next-tile prefetch in flight across compute
      const int s0n = (kt + 1) * 64;
      const size_t ko = base + (size_t)(s0n + sr) * HDIM + sq;
      krh[0] = *(const u16x8*)&Khp[ko]; krh[1] = *(const u16x8*)&Khp[ko + 8];
      krl[0] = *(const u16x8*)&Klp[ko]; krl[1] = *(const u16x8*)&Klp[ko + 8];
      const size_t vo = base + (size_t)sr * S_LEN + s0n + sq;
      vrh[0] = *(const u16x8*)&Vhp[vo]; vrh[1] = *(const u16x8*)&Vhp[vo + 8];
      vrl[0] = *(const u16x8*)&Vlp[vo]; vrl[1] = *(const u16x8*)&Vlp[vo + 8];
    }
    // ---- QK^T (swapped): sc[n][r] = S[k=16n+4lq+r][q=l15] ----
    f32x4 sc[4] = {};
#pragma unroll
    for (int c = 0; c < 2; c++) {
      short8 kfh[4], kfl[4];
#pragma unroll
      for (int n = 0; n < 4; n++) {
        kfh[n] = *(const short8*)&KhL[16 * n + l15][c * 32 + lq * 8];
        kfl[n] = *(const short8*)&KlL[16 * n + l15][c * 32 + lq * 8];
      }
#pragma unroll
      for (int n = 0; n < 4; n++) {
        sc[n] = __builtin_amdgcn_mfma_f32_16x16x32_bf16(kfh[n], qh[c], sc[n], 0, 0, 0);
        sc[n] = __builtin_amdgcn_mfma_f32_16x16x32_bf16(kfl[n], qh[c], sc[n], 0, 0, 0);
        sc[n] = __builtin_amdgcn_mfma_f32_16x16x32_bf16(kfh[n], ql[c], sc[n], 0, 0, 0);
      }
    }
    // ---- online softmax, per-lane scalar state ----
    float tm = fmaxf(fmaxf(fmaxf(sc[0][0], sc[0][1]), fmaxf(sc[0][2], sc[0][3])),
                     fmaxf(fmaxf(sc[1][0], sc[1][1]), fmaxf(sc[1][2], sc[1][3])));
    tm = fmaxf(tm, fmaxf(fmaxf(fmaxf(sc[2][0], sc[2][1]), fmaxf(sc[2][2], sc[2][3])),
                         fmaxf(fmaxf(sc[3][0], sc[3][1]), fmaxf(sc[3][2], sc[3][3]))));
    tm = fmaxf(tm, __shfl_xor(tm, 16));
    tm = fmaxf(tm, __shfl_xor(tm, 32));
    const float mn = fmaxf(m_, tm);
    const float esc = __expf(m_ - mn);
    m_ = mn;
    float rs = 0.f;
    unsigned pk[4][4];
#pragma unroll
    for (int n = 0; n < 4; n++) {
#pragma unroll
      for (int r = 0; r < 4; r++) {
        const float p = __expf(sc[n][r] - mn);
        rs += p;
        const unsigned short hh = f2bf(p);
        pk[n][r] = ((unsigned)hh << 16) | (unsigned)f2bf(p - bf2f(hh));
      }
    }
    rs += __shfl_xor(rs, 16);
    rs += __shfl_xor(rs, 32);
    l_ = l_ * esc + rs;
    // rescale acc (rows q-rel = 4lq+r need esc from lane 4lq+r)
    float escR[4];
#pragma unroll
    for (int r = 0; r < 4; r++) escR[r] = __shfl(esc, 4 * lq + r);
#pragma unroll
    for (int n = 0; n < 4; n++) {
#pragma unroll
      for (int r = 0; r < 4; r++) acc[n][r] *= escR[r];
    }
    // ---- PV: redistribute P in-register, 3-term MFMA ----
#pragma unroll
    for (int c = 0; c < 2; c++) {
      unsigned val[8];
#pragma unroll
      for (int j = 0; j < 8; j++) {
        const int src = (j >> 2) ? srcB : srcA;
        const unsigned sA = (unsigned)__shfl((int)pk[2 * c + 0][j & 3], src);
        const unsigned sB = (unsigned)__shfl((int)pk[2 * c + 1][j & 3], src);
        val[j] = selHi ? sB : sA;
      }
      const short8 ph = pack_hi8(val);
      const short8 plo = pack_lo8(val);
      short8 vfh[4], vfl[4];
#pragma unroll
      for (int n = 0; n < 4; n++) {
        vfh[n] = *(const short8*)&VhL[16 * n + l15][c * 32 + lq * 8];
        vfl[n] = *(const short8*)&VlL[16 * n + l15][c * 32 + lq * 8];
      }
#pragma unroll
      for (int n = 0; n < 4; n++) {
        acc[n] = __builtin_amdgcn_mfma_f32_16x16x32_bf16(ph, vfh[n], acc[n], 0, 0, 0);
        acc[n] = __builtin_amdgcn_mfma_f32_16x16x32_bf16(ph, vfl[n], acc[n], 0, 0, 0);
        acc[n] = __builtin_amdgcn_mfma_f32_16x16x32_bf16(plo, vfh[n], acc[n], 0, 0, 0);
      }
    }
    __syncthreads();
  }
  // epilogue: O[S,B,D]; inv(l) for row 4lq+r from lane 4lq+r
  const float inv = 1.f / l_;
  float invR[4];
#pragma unroll
  for (int r = 0; r < 4; r++) invR[r] = __shfl(inv, 4 * lq + r);
#pragma unroll
  for (int r = 0; r < 4; r++) {
    const int srow = q0 + 16 * w + 4 * lq + r;
    float* orow = &O[((size_t)srow * BATCH + b) * DIM + h * HDIM];
#pragma unroll
    for (int n = 0; n < 4; n++) orow[16 * n + l15] = acc[n][r] * invR[r];
  }
}

// ---------------- layernorm: x = LN(src + proj)*g + b -> out ----------------
__global__ __launch_bounds__(256) void k_ln(const float* __restrict__ src,
                                            const float* __restrict__ proj,
                                            const float* __restrict__ g,
                                            const float* __restrict__ bt,
                                            float* __restrict__ xout) {
  const int wid = threadIdx.x >> 6, lane = threadIdx.x & 63;
  const int tok = blockIdx.x * 4 + wid;
  const size_t base = (size_t)tok * DIM + lane * 8;
  f4 a0 = *(const f4*)&src[base],  a1 = *(const f4*)&src[base + 4];
  f4 p0 = *(const f4*)&proj[base], p1 = *(const f4*)&proj[base + 4];
  float x[8];
  x[0] = a0[0] + p0[0]; x[1] = a0[1] + p0[1]; x[2] = a0[2] + p0[2]; x[3] = a0[3] + p0[3];
  x[4] = a1[0] + p1[0]; x[5] = a1[1] + p1[1]; x[6] = a1[2] + p1[2]; x[7] = a1[3] + p1[3];
  float s = 0.f, sq = 0.f;
#pragma unroll
  for (int j = 0; j < 8; j++) { s += x[j]; sq = fmaf(x[j], x[j], sq); }
#pragma unroll
  for (int d = 1; d < 64; d <<= 1) { s += __shfl_xor(s, d); sq += __shfl_xor(sq, d); }
  const float mean = s * (1.f / 512.f);
  const float var = sq * (1.f / 512.f) - mean * mean;
  const float rstd = 1.f / sqrtf(var + 1e-5f);
  const int ci = lane * 8;
  f4 o0v, o1v;
#pragma unroll
  for (int j = 0; j < 4; j++) o0v[j] = (x[j] - mean) * rstd * g[ci + j] + bt[ci + j];
#pragma unroll
  for (int j = 0; j < 4; j++) o1v[j] = (x[4 + j] - mean) * rstd * g[ci + 4 + j] + bt[ci + 4 + j];
  *(f4*)&xout[base] = o0v;
  *(f4*)&xout[base + 4] = o1v;
}

// ---------------- gate: block = 16 tokens x 16 experts, 4 tiles ----------------
__global__ __launch_bounds__(256) void k_gate(const float* __restrict__ x,
                                              const float* __restrict__ gw,
                                              const float* __restrict__ gb,
                                              int* __restrict__ topi,
                                              float* __restrict__ topw,
                                              int* __restrict__ counts) {
  __shared__ float xs[16 * 520];
  __shared__ int hist[16];
  const int tid = threadIdx.x;
  const int tl = tid >> 4, e = tid & 15;
  if (tid < 16) hist[tid] = 0;
  const float gbe = gb[e];
  const float* wrow = gw + (size_t)e * DIM;
  for (int tile = 0; tile < 4; tile++) {
    const int t0 = blockIdx.x * 64 + tile * 16;
    __syncthreads();
    {
      const int r = tid >> 4, cbase = (tid & 15) * 32;
#pragma unroll
      for (int j = 0; j < 8; j++) {
        const int c = cbase + j * 4;
        const int ch = c >> 2;
        const int pc = ch ^ ((ch >> 3) & 7);
        *(f4*)&xs[r * 520 + pc * 4] = *(const f4*)&x[(size_t)(t0 + r) * DIM + c];
      }
    }
    __syncthreads();
    float d = gbe;
#pragma unroll 8
    for (int c = 0; c < DIM; c += 4) {
      const int ch = c >> 2;
      const int pc = ch ^ ((ch >> 3) & 7);
      f4 xv = *(const f4*)&xs[tl * 520 + pc * 4];
      f4 wv = *(const f4*)&wrow[c];
      d = fmaf(xv[0], wv[0], d); d = fmaf(xv[1], wv[1], d);
      d = fmaf(xv[2], wv[2], d); d = fmaf(xv[3], wv[3], d);
    }
    float v1 = d, v2 = -1e30f;
    int i1 = e, i2 = 1000;
#pragma unroll
    for (int s = 1; s < 16; s <<= 1) {
      const float ov1 = __shfl_xor(v1, s), ov2 = __shfl_xor(v2, s);
      const int oi1 = __shfl_xor(i1, s), oi2 = __shfl_xor(i2, s);
      if (ov1 > v1 || (ov1 == v1 && oi1 < i1)) {
        float nv2; int ni2;
        if (v1 > ov2 || (v1 == ov2 && i1 < oi2)) { nv2 = v1; ni2 = i1; }
        else { nv2 = ov2; ni2 = oi2; }
        v1 = ov1; i1 = oi1; v2 = nv2; i2 = ni2;
      } else if (ov1 > v2 || (ov1 == v2 && oi1 < i2)) {
        v2 = ov1; i2 = oi1;
      }
    }
    if (e == 0) {
      const int t = t0 + tl;
      const float e1 = __expf(v2 - v1);
      const float inv = 1.f / (1.f + e1);
      topi[2 * t] = i1;  topi[2 * t + 1] = i2;
      topw[2 * t] = inv; topw[2 * t + 1] = e1 * inv;
      atomicAdd(&hist[i1], 1);
      atomicAdd(&hist[i2], 1);
    }
  }
  __syncthreads();
  if (tid < 16 && hist[tid] > 0) atomicAdd(&counts[tid], hist[tid]);
}

__global__ void k_offsets(const int* __restrict__ counts,
                          int* __restrict__ off_pad, int* __restrict__ cursor) {
  if (threadIdx.x == 0) {
    int o = 0;
    off_pad[0] = 0;
    for (int e = 0; e < NE; e++) {
      cursor[e] = 0;
      o += ((counts[e] + BM - 1) / BM) * BM;
      off_pad[e + 1] = o;
    }
  }
}

// ---------------- scatter: batched slot claims ----------------
__global__ __launch_bounds__(256) void k_scatter(const float* __restrict__ x,
                                                 const int* __restrict__ topi,
                                                 const float* __restrict__ topw,
                                                 const int* __restrict__ off_pad,
                                                 int* __restrict__ cursor,
                                                 int* __restrict__ slotTok,
                                                 float* __restrict__ slotW,
                                                 unsigned short* __restrict__ Xg) {
  __shared__ int lcnt[16];
  __shared__ int gbase[16];
  __shared__ int posArr[128];
  const int tid = threadIdx.x;
  const int a0 = blockIdx.x * 128;
  if (tid < 16) lcnt[tid] = 0;
  __syncthreads();
  if (tid < 128) {
    const int a = a0 + tid;
    const int e = topi[a];
    const int lrank = atomicAdd(&lcnt[e], 1);
    posArr[tid] = (e << 24) | lrank;
  }
  __syncthreads();
  if (tid < 16) {
    const int c = lcnt[tid];
    gbase[tid] = (c > 0) ? atomicAdd(&cursor[tid], c) : 0;
  }
  __syncthreads();
  if (tid < 128) {
    const int a = a0 + tid;
    const int pk = posArr[tid];
    const int e = pk >> 24, lrank = pk & 0xffffff;
    const int pos = off_pad[e] + gbase[e] + lrank;
    posArr[tid] = pos;
    slotTok[pos] = a >> 1;
    slotW[pos] = topw[a];
  }
  __syncthreads();
  const int w = tid >> 6, lane = tid & 63;
#pragma unroll 4
  for (int i = 0; i < 32; i++) {
    const int idx = w * 32 + i;
    const int pos = posArr[idx];
    const int tok = (a0 + idx) >> 1;
    const size_t sb = (size_t)tok * DIM + lane * 8;
    f4 v0 = *(const f4*)&x[sb], v1 = *(const f4*)&x[sb + 4];
    u16x8 hh;
    hh[0] = f2bf(v0[0]); hh[1] = f2bf(v0[1]); hh[2] = f2bf(v0[2]); hh[3] = f2bf(v0[3]);
    hh[4] = f2bf(v1[0]); hh[5] = f2bf(v1[1]); hh[6] = f2bf(v1[2]); hh[7] = f2bf(v1[3]);
    *(u16x8*)&Xg[(size_t)pos * DIM + lane * 8] = hh;
  }
}

// ---------------- grouped bf16 MFMA GEMM (MoE), T2 swizzle + T1 XCD swizzle ----------------
__global__ __launch_bounds__(256) void k_gemm_bf16(
    const unsigned short* __restrict__ A, int lda,
    const unsigned short* __restrict__ Wb, size_t westride, int ldw, int wrow0,
    const float* __restrict__ bias, int bstride, int brow0,
    int K, int epi,
    unsigned short* __restrict__ Hout, int ldh,
    float* __restrict__ dout,
    const int* __restrict__ slotTok, const float* __restrict__ slotW,
    const int* __restrict__ off_pad) {
  // T1: XCD-aware swizzle (consecutive swizzled blocks share expert weights)
  int bx = blockIdx.x;
  const int nwg = gridDim.x;
  if ((nwg & 7) == 0) bx = (bx & 7) * (nwg >> 3) + (bx >> 3);
  const int m0 = bx * BM;
  if (m0 >= off_pad[NE]) return;
  int e = 0;
  while (off_pad[e + 1] <= m0) e++;
  const unsigned short* W = Wb + (size_t)e * westride;
  const int n0 = blockIdx.y * 128;
  __shared__ unsigned short Al[128 * 64];
  __shared__ unsigned short Bl[128 * 64];
  const int tid = threadIdx.x, lane = tid & 63, wid = tid >> 6;
  const int wm = wid >> 1, wn = wid & 1;
  f32x4 acc[4][4] = {};
  const int srow = wid * 32 + (lane >> 3);
  const int scol = (((lane & 7) ^ ((lane >> 3) & 7)) << 3);
  for (int k0 = 0; k0 < K; k0 += 64) {
    const unsigned short* ga = A + (size_t)(m0 + srow) * lda + k0 + scol;
    const unsigned short* gw = W + (size_t)(wrow0 + n0 + srow) * ldw + k0 + scol;
#pragma unroll
    for (int i = 0; i < 4; i++) {
      load_lds16(ga + (size_t)i * 8 * lda, &Al[(wid * 32 + i * 8) * 64]);
      load_lds16(gw + (size_t)i * 8 * ldw, &Bl[(wid * 32 + i * 8) * 64]);
    }
    __syncthreads();
#pragma unroll
    for (int kk = 0; kk < 2; kk++) {
      short8 av[4], bv[4];
      const int ckx = (kk * 4 + (lane >> 4)) ^ (lane & 7);
#pragma unroll
      for (int mi = 0; mi < 4; mi++)
        av[mi] = *(const short8*)&Al[(wm * 64 + mi * 16 + (lane & 15)) * 64 + ckx * 8];
#pragma unroll
      for (int ni = 0; ni < 4; ni++)
        bv[ni] = *(const short8*)&Bl[(wn * 64 + ni * 16 + (lane & 15)) * 64 + ckx * 8];
#pragma unroll
      for (int mi = 0; mi < 4; mi++) {
#pragma unroll
        for (int ni = 0; ni < 4; ni++)
          acc[mi][ni] = __builtin_amdgcn_mfma_f32_16x16x32_bf16(av[mi], bv[ni], acc[mi][ni], 0, 0, 0);
      }
    }
    __syncthreads();
  }
#pragma unroll
  for (int mi = 0; mi < 4; mi++) {
    const int rb = m0 + wm * 64 + mi * 16 + ((lane >> 4) << 2);
#pragma unroll
    for (int ni = 0; ni < 4; ni++) {
      const int n = n0 + wn * 64 + ni * 16 + (lane & 15);
      const float bn = bias ? bias[(size_t)e * bstride + brow0 + n] : 0.f;
      if (epi == 0) {
#pragma unroll
        for (int r = 0; r < 4; r++) {
          float v = acc[mi][ni][r] + bn;
          v = fmaxf(v, 0.f);
          Hout[(size_t)(rb + r) * ldh + n] = f2bf(v);
        }
      } else {
#pragma unroll
        for (int r = 0; r < 4; r++) {
          const int tok = slotTok[rb + r];
          if (tok >= 0) {
            const float v = (acc[mi][ni][r] + bn) * slotW[rb + r];
            atomicAdd(&dout[(size_t)tok * DIM + n], v);
          }
        }
      }
    }
  }
}

// ---------------- launch ----------------
extern "C" void kernel_launch(void* const* d_in, const int* in_sizes, int n_in,
                              void* d_out, int out_size, void* d_ws, size_t ws_size,
                              hipStream_t stream) {
  const float* src       = (const float*)d_in[0];
  const float* pos       = (const float*)d_in[1];
  const float* in_proj_w = (const float*)d_in[2];
  const float* in_proj_b = (const float*)d_in[3];
  const float* out_w     = (const float*)d_in[4];
  const float* out_b     = (const float*)d_in[5];
  const float* norm1_g   = (const float*)d_in[6];
  const float* norm1_b   = (const float*)d_in[7];
  const float* gate_w    = (const float*)d_in[8];
  const float* gate_b    = (const float*)d_in[9];
  const float* w1        = (const float*)d_in[10];
  const float* b1        = (const float*)d_in[11];
  const float* w2        = (const float*)d_in[12];
  const float* b2        = (const float*)d_in[13];
  float* out = (float*)d_out;
  char* wsb = (char*)d_ws;

  // ---- lifetime-packed arena (~166.5 MiB, unchanged footprint) ----
  unsigned short* Qhp = (unsigned short*)(wsb + 0);
  unsigned short* Qlp = (unsigned short*)(wsb + 16777216);
  unsigned short* Khp = (unsigned short*)(wsb + 33554432);
  unsigned short* Klp = (unsigned short*)(wsb + 50331648);
  unsigned short* Vhp = (unsigned short*)(wsb + 67108864);
  unsigned short* Vlp = (unsigned short*)(wsb + 83886080);
  float* ob = (float*)(wsb + 100663296);
  float* proj = (float*)(wsb + 0);
  unsigned short* w1b = (unsigned short*)(wsb + 0);
  unsigned short* w2b = (unsigned short*)(wsb + 33554432);
  unsigned short* Xg  = (unsigned short*)(wsb + 67108864);
  unsigned short* Hb  = (unsigned short*)(wsb + 102760448);
  unsigned short* wih = (unsigned short*)(wsb + 134217728);
  unsigned short* wil = (unsigned short*)(wsb + 135790592);
  char* smallb = wsb + 174063616;
  int*   topi    = (int*)  (smallb + 0);
  float* topw    = (float*)(smallb + 131072);
  int*   slotTok = (int*)  (smallb + 262144);
  float* slotW   = (float*)(smallb + 401408);
  int*   counts  = (int*)  (smallb + 540672);
  int*   off_pad = (int*)  (smallb + 540736);
  int*   cursor  = (int*)  (smallb + 540864);

  // 1. routing init + in_proj weight split
  k_init<<<(CAP + 255) / 256, 256, 0, stream>>>(slotTok, slotW, counts);
  k_split_w<<<768, 256, 0, stream>>>(in_proj_w, wih, wil, (size_t)1536 * 512);
  // 2. Q/K projection (split MFMA, fused src+pos) -> hi/lo planes [B,H,S,HD]
  k_gemm_split<<<dim3(128, 8), 256, 0, stream>>>(src, pos, wih, wil, in_proj_b, 0,
                                                 Qhp, Qlp, Khp, Klp);
  // 3. V projection -> hi/lo planes [B,H,HD,S]
  k_gemm_split<<<dim3(128, 4), 256, 0, stream>>>(src, nullptr, wih + (size_t)1024 * 512,
                                                 wil + (size_t)1024 * 512, in_proj_b + 1024,
                                                 1, Vhp, Vlp, nullptr, nullptr);
  // 4. split-MFMA flash attention (in-register P) -> ob [S,B,D]
  k_attn<<<dim3(16, 128), 256, 0, stream>>>(Qhp, Qlp, Khp, Klp, Vhp, Vlp, ob);
  // 5. w2 -> bf16 (K planes dead)
  k_cvt_bf16<<<2048, 256, 0, stream>>>(w2, w2b, (size_t)NE * DIM * DFF);
  // 6. output projection (fp32 vector — gate-critical) -> proj (over Q planes)
  k_gemm_f32<<<dim3(128, 4), 256, 0, stream>>>(ob, out_w, out_b, 512, proj);
  // 7. layernorm(src + proj) -> d_out (= x)
  k_ln<<<4096, 256, 0, stream>>>(src, proj, norm1_g, norm1_b, out);
  // 8. w1 -> bf16 (proj dead)
  k_cvt_bf16<<<2048, 256, 0, stream>>>(w1, w1b, (size_t)NE * DFF * DIM);
  // 9. gate logits + top2 + counts
  k_gate<<<T_TOK / 64, 256, 0, stream>>>(out, gate_w, gate_b, topi, topw, counts);
  // 10. padded segment offsets
  k_offsets<<<1, 64, 0, stream>>>(counts, off_pad, cursor);
  // 11. zero only padding rows of Xg
  k_zero_pad<<<NE, 256, 0, stream>>>(counts, off_pad, Xg);
  // 12. scatter assignments + gather token rows as bf16 (batched claims)
  k_scatter<<<256, 256, 0, stream>>>(out, topi, topw, off_pad, cursor, slotTok, slotW, Xg);
  // 13. MoE, DFF halved
  for (int p = 0; p < 2; ++p) {
    k_gemm_bf16<<<dim3(CAP / BM, 8), 256, 0, stream>>>(
        Xg, DIM, w1b, (size_t)DFF * DIM, DIM, p * 1024,
        b1, DFF, p * 1024, DIM, 0, Hb, 1024,
        nullptr, nullptr, nullptr, off_pad);
    k_gemm_bf16<<<dim3(CAP / BM, 4), 256, 0, stream>>>(
        Hb, 1024, w2b + (size_t)p * 1024, (size_t)DIM * DFF, DFF, 0,
        (p == 0 ? b2 : nullptr), DIM, 0, 1024, 1, nullptr, 0,
        out, slotTok, slotW, off_pad);
  }
}

// Round 9
// 985.201 us; speedup vs baseline: 2.5514x; 1.1383x over previous
//
#include <hip/hip_runtime.h>
#include <hip/hip_bf16.h>

// ---------------- types ----------------
typedef float f4 __attribute__((ext_vector_type(4)));
typedef float f32x4 __attribute__((ext_vector_type(4)));
typedef short short8 __attribute__((ext_vector_type(8)));
typedef unsigned short u16x4 __attribute__((ext_vector_type(4)));
typedef unsigned short u16x8 __attribute__((ext_vector_type(8)));
typedef unsigned int u32x4 __attribute__((ext_vector_type(4)));
typedef unsigned int u32x8 __attribute__((ext_vector_type(8)));

// ---------------- problem constants ----------------
#define S_LEN 1024
#define BATCH 16
#define DIM   512
#define NH    8
#define HDIM  64
#define NE    16
#define DFF   2048
#define T_TOK 16384   // S*B
#define CAP   34816   // 32768 assignments + per-expert padding to BM
#define BM    128

__device__ __forceinline__ unsigned short f2bf(float f) {
  union { float f; unsigned u; } v; v.f = f;
  unsigned r = v.u + 0x7fffu + ((v.u >> 16) & 1u);  // RTNE
  return (unsigned short)(r >> 16);
}
__device__ __forceinline__ float bf2f(unsigned short h) {
  union { unsigned u; float f; } v; v.u = ((unsigned)h) << 16;
  return v.f;
}

__device__ __forceinline__ void load_lds16(const void* g, void* l) {
  __builtin_amdgcn_global_load_lds(
      (__attribute__((address_space(1))) void*)(void*)g,
      (__attribute__((address_space(3))) void*)l, 16, 0, 0);
}

// unpack 8 packed u32 (hi16|lo16) into hi-plane / lo-plane bf16x8 operands
__device__ __forceinline__ short8 pack_hi8(const unsigned* val) {
  union { unsigned u[4]; short8 s; } t;
#pragma unroll
  for (int i = 0; i < 4; i++)
    t.u[i] = (val[2 * i] >> 16) | (val[2 * i + 1] & 0xFFFF0000u);
  return t.s;
}
__device__ __forceinline__ short8 pack_lo8(const unsigned* val) {
  union { unsigned u[4]; short8 s; } t;
#pragma unroll
  for (int i = 0; i < 4; i++)
    t.u[i] = (val[2 * i] & 0xFFFFu) | (val[2 * i + 1] << 16);
  return t.s;
}

// ---------------- small utility kernels ----------------
__global__ __launch_bounds__(256) void k_cvt_bf16(const float* __restrict__ in,
                                                  unsigned short* __restrict__ outb,
                                                  size_t n) {
  size_t i = ((size_t)blockIdx.x * 256 + threadIdx.x) * 4;
  size_t stride = (size_t)gridDim.x * 1024;
  for (; i < n; i += stride) {
    f4 v = *(const f4*)&in[i];
    u16x4 o;
    o[0] = f2bf(v[0]); o[1] = f2bf(v[1]); o[2] = f2bf(v[2]); o[3] = f2bf(v[3]);
    *(u16x4*)&outb[i] = o;
  }
}

// split fp32 -> bf16 hi + bf16 lo (lo = round(x - hi))
__global__ __launch_bounds__(256) void k_split_w(const float* __restrict__ in,
                                                 unsigned short* __restrict__ hi,
                                                 unsigned short* __restrict__ lo,
                                                 size_t n) {
  size_t i = ((size_t)blockIdx.x * 256 + threadIdx.x) * 4;
  size_t stride = (size_t)gridDim.x * 1024;
  for (; i < n; i += stride) {
    f4 v = *(const f4*)&in[i];
    u16x4 h, l;
#pragma unroll
    for (int j = 0; j < 4; j++) {
      unsigned short hh = f2bf(v[j]);
      h[j] = hh;
      l[j] = f2bf(v[j] - bf2f(hh));
    }
    *(u16x4*)&hi[i] = h;
    *(u16x4*)&lo[i] = l;
  }
}

__global__ __launch_bounds__(256) void k_init(int* __restrict__ slotTok,
                                              float* __restrict__ slotW,
                                              int* __restrict__ counts) {
  int i = blockIdx.x * 256 + threadIdx.x;
  if (i < CAP) { slotTok[i] = -1; slotW[i] = 0.f; }
  if (i < NE) counts[i] = 0;
}

// zero only the padding rows of each expert segment
__global__ __launch_bounds__(256) void k_zero_pad(const int* __restrict__ counts,
                                                  const int* __restrict__ off_pad,
                                                  unsigned short* __restrict__ Xg) {
  const int e = blockIdx.x;
  const int start = off_pad[e] + counts[e];
  const int end = off_pad[e + 1];
  for (int row = start; row < end; row++)
    *(unsigned int*)&Xg[(size_t)row * DIM + threadIdx.x * 2] = 0u;
}

// ---------------- split-bf16 MFMA GEMM (fp32-accurate via hi/lo) ----------------
// C = (A [+A2])[M,512] * W[N,512]^T + bias; outputs packed-u32 (hi<<16|lo) planes,
// all in [B,H,S,HD] layout -> fully coalesced 64B epilogue stores.
// epi 0: n<512 -> Q*0.125 -> p0; n>=512 -> K -> p1.   epi 1: V -> p0.
__global__ __launch_bounds__(256, 2) void k_gemm_split(
    const float* __restrict__ A, const float* __restrict__ A2,
    const unsigned short* __restrict__ Wh, const unsigned short* __restrict__ Wl,
    const float* __restrict__ bias, int epi,
    unsigned* __restrict__ p0, unsigned* __restrict__ p1) {
  __shared__ unsigned short AhL[128 * 32];
  __shared__ unsigned short AlL[128 * 32];
  __shared__ unsigned short WhL[128 * 32];
  __shared__ unsigned short WlL[128 * 32];
  const int tid = threadIdx.x, lane = tid & 63, wid = tid >> 6;
  const int wm = wid >> 1, wn = wid & 1;
  const int m0 = blockIdx.x * 128, n0 = blockIdx.y * 128;
  const int row = tid >> 1, half = tid & 1;
  const int xr = (row >> 1) & 3;
  f32x4 acc[4][4] = {};
  f4 ar[4];
#pragma unroll
  for (int j = 0; j < 4; j++) {
    const size_t aoff = (size_t)(m0 + row) * 512 + half * 16 + j * 4;
    ar[j] = *(const f4*)&A[aoff];
    if (A2) { f4 v2 = *(const f4*)&A2[aoff]; ar[j] += v2; }
  }
  for (int k0 = 0; k0 < 512; k0 += 32) {
    __syncthreads();
    u16x8 hi8[2], lo8[2];
#pragma unroll
    for (int j = 0; j < 16; j++) {
      const float x = ar[j >> 2][j & 3];
      const unsigned short h = f2bf(x);
      hi8[j >> 3][j & 7] = h;
      lo8[j >> 3][j & 7] = f2bf(x - bf2f(h));
    }
    const int c0 = half * 2;
    *(u16x8*)&AhL[row * 32 + (((c0 + 0) ^ xr) << 3)] = hi8[0];
    *(u16x8*)&AhL[row * 32 + (((c0 + 1) ^ xr) << 3)] = hi8[1];
    *(u16x8*)&AlL[row * 32 + (((c0 + 0) ^ xr) << 3)] = lo8[0];
    *(u16x8*)&AlL[row * 32 + (((c0 + 1) ^ xr) << 3)] = lo8[1];
#pragma unroll
    for (int i = 0; i < 2; i++) {
      const int rowW = i * 64 + wid * 16 + (lane >> 2);
      const int clog = (lane & 3) ^ ((rowW >> 1) & 3);
      const size_t woff = (size_t)(n0 + rowW) * 512 + k0 + (clog << 3);
      load_lds16(Wh + woff, &WhL[i * 2048 + wid * 512]);
      load_lds16(Wl + woff, &WlL[i * 2048 + wid * 512]);
    }
    __syncthreads();
    if (k0 + 32 < 512) {
#pragma unroll
      for (int j = 0; j < 4; j++) {
        const size_t aoff = (size_t)(m0 + row) * 512 + k0 + 32 + half * 16 + j * 4;
        ar[j] = *(const f4*)&A[aoff];
        if (A2) { f4 v2 = *(const f4*)&A2[aoff]; ar[j] += v2; }
      }
    }
    const int l15 = lane & 15, lk = lane >> 4;
    const int xa = (l15 >> 1) & 3;
    short8 avh[4], avl[4], bvh[4], bvl[4];
#pragma unroll
    for (int mi = 0; mi < 4; mi++) {
      const int mr = wm * 64 + mi * 16 + l15;
      avh[mi] = *(const short8*)&AhL[mr * 32 + ((lk ^ xa) << 3)];
      avl[mi] = *(const short8*)&AlL[mr * 32 + ((lk ^ xa) << 3)];
    }
#pragma unroll
    for (int ni = 0; ni < 4; ni++) {
      const int nr = wn * 64 + ni * 16 + l15;
      bvh[ni] = *(const short8*)&WhL[nr * 32 + ((lk ^ xa) << 3)];
      bvl[ni] = *(const short8*)&WlL[nr * 32 + ((lk ^ xa) << 3)];
    }
#pragma unroll
    for (int mi = 0; mi < 4; mi++) {
#pragma unroll
      for (int ni = 0; ni < 4; ni++) {
        acc[mi][ni] = __builtin_amdgcn_mfma_f32_16x16x32_bf16(avh[mi], bvh[ni], acc[mi][ni], 0, 0, 0);
        acc[mi][ni] = __builtin_amdgcn_mfma_f32_16x16x32_bf16(avh[mi], bvl[ni], acc[mi][ni], 0, 0, 0);
        acc[mi][ni] = __builtin_amdgcn_mfma_f32_16x16x32_bf16(avl[mi], bvh[ni], acc[mi][ni], 0, 0, 0);
      }
    }
  }
  // epilogue: packed u32 store, coalesced along head-dim
#pragma unroll
  for (int mi = 0; mi < 4; mi++) {
    const int rb = m0 + wm * 64 + mi * 16 + ((lane >> 4) << 2);
#pragma unroll
    for (int ni = 0; ni < 4; ni++) {
      const int n = n0 + wn * 64 + ni * 16 + (lane & 15);
      const float bn = bias[n];
#pragma unroll
      for (int r = 0; r < 4; r++) {
        const int m = rb + r;
        const int bidx = m & 15, ss = m >> 4;   // token = s*B + b
        float v = acc[mi][ni][r] + bn;
        unsigned* pl;
        int nn;
        if (epi == 0) {
          if (n < 512) { v *= 0.125f; pl = p0; nn = n; }
          else { pl = p1; nn = n - 512; }
        } else { pl = p0; nn = n; }
        const size_t off = ((size_t)(bidx * NH + (nn >> 6)) * S_LEN + ss) * HDIM + (nn & 63);
        const unsigned short hh = f2bf(v);
        pl[off] = ((unsigned)hh << 16) | (unsigned)f2bf(v - bf2f(hh));
      }
    }
  }
}

// ---------------- fp32 GEMM (out-proj only): C = A[M,K]*W[N,K]^T + bias ----------------
__global__ __launch_bounds__(256, 3) void k_gemm_f32(
    const float* __restrict__ A, const float* __restrict__ W,
    const float* __restrict__ bias, int K,
    float* __restrict__ o0) {
  __shared__ float Alt[32][132];
  __shared__ float Wlt[32][132];
  const int tid = threadIdx.x, tx = tid & 15, ty = tid >> 4;
  const int m0 = blockIdx.x * 128, n0 = blockIdx.y * 128;
  float acc[8][8];
#pragma unroll
  for (int i = 0; i < 8; i++) {
#pragma unroll
    for (int j = 0; j < 8; j++) acc[i][j] = 0.f;
  }
  f4 ar[4], wr[4];
#pragma unroll
  for (int i = 0; i < 4; i++) {
    const int c = tid + i * 256;
    const int r = c >> 3, j = (c & 7) * 4;
    ar[i] = *(const f4*)&A[(size_t)(m0 + r) * K + j];
    wr[i] = *(const f4*)&W[(size_t)(n0 + r) * K + j];
  }
  for (int k0 = 0; k0 < K; k0 += 32) {
    __syncthreads();
#pragma unroll
    for (int i = 0; i < 4; i++) {
      const int c = tid + i * 256;
      const int r = c >> 3, j = (c & 7) * 4;
      Alt[j + 0][r] = ar[i][0]; Alt[j + 1][r] = ar[i][1];
      Alt[j + 2][r] = ar[i][2]; Alt[j + 3][r] = ar[i][3];
      Wlt[j + 0][r] = wr[i][0]; Wlt[j + 1][r] = wr[i][1];
      Wlt[j + 2][r] = wr[i][2]; Wlt[j + 3][r] = wr[i][3];
    }
    __syncthreads();
    if (k0 + 32 < K) {
#pragma unroll
      for (int i = 0; i < 4; i++) {
        const int c = tid + i * 256;
        const int r = c >> 3, j = (c & 7) * 4;
        ar[i] = *(const f4*)&A[(size_t)(m0 + r) * K + k0 + 32 + j];
        wr[i] = *(const f4*)&W[(size_t)(n0 + r) * K + k0 + 32 + j];
      }
    }
#pragma unroll 4
    for (int kk = 0; kk < 32; kk++) {
      float a[8], w8[8];
      *(f4*)&a[0]  = *(const f4*)&Alt[kk][ty * 8];
      *(f4*)&a[4]  = *(const f4*)&Alt[kk][ty * 8 + 4];
      *(f4*)&w8[0] = *(const f4*)&Wlt[kk][tx * 8];
      *(f4*)&w8[4] = *(const f4*)&Wlt[kk][tx * 8 + 4];
#pragma unroll
      for (int mi = 0; mi < 8; mi++) {
#pragma unroll
        for (int ni = 0; ni < 8; ni++)
          acc[mi][ni] = fmaf(a[mi], w8[ni], acc[mi][ni]);
      }
    }
  }
#pragma unroll
  for (int mi = 0; mi < 8; mi++) {
    const size_t m = (size_t)(m0 + ty * 8 + mi);
#pragma unroll
    for (int nj = 0; nj < 2; nj++) {
      const int n = n0 + tx * 8 + nj * 4;
      f4 v;
      v[0] = acc[mi][nj * 4 + 0] + bias[n + 0];
      v[1] = acc[mi][nj * 4 + 1] + bias[n + 1];
      v[2] = acc[mi][nj * 4 + 2] + bias[n + 2];
      v[3] = acc[mi][nj * 4 + 3] + bias[n + 3];
      *(f4*)&o0[m * 512 + n] = v;
    }
  }
}

// ---------------- split-bf16 MFMA flash attention, packed planes ----------------
// Q,K,V all [B,H,S,HD] packed u32 (hi<<16|lo). V transposed into LDS at staging.
// Swapped QK^T -> in-register P; no P LDS tile. LDS = 34,816 B.
__global__ __launch_bounds__(256, 3) void k_attn(
    const unsigned* __restrict__ Qp, const unsigned* __restrict__ Kp,
    const unsigned* __restrict__ Vp, float* __restrict__ O) {
  const int q0 = blockIdx.x * 64;
  const int bh = blockIdx.y;
  const int b = bh >> 3, h = bh & 7;
  const size_t base = (size_t)bh * (S_LEN * HDIM);
  __shared__ unsigned KL[64][68];   // [key][d]
  __shared__ unsigned VL[64][68];   // [d][key]  (transposed at staging)
  const int tid = threadIdx.x, lane = tid & 63, w = tid >> 6;
  const int l15 = lane & 15, lq = lane >> 4;
  const int srcA = l15 + 16 * ((2 * lq) & 3);
  const int srcB = l15 + 16 * ((2 * lq + 1) & 3);
  const bool selHi = (lane & 32) != 0;
  // Q fragments
  short8 qh[2], ql[2];
  {
    const size_t qoff = base + (size_t)(q0 + 16 * w + l15) * HDIM + lq * 8;
    u32x8 qv0 = *(const u32x8*)&Qp[qoff];
    u32x8 qv1 = *(const u32x8*)&Qp[qoff + 32];
    qh[0] = pack_hi8((const unsigned*)&qv0); ql[0] = pack_lo8((const unsigned*)&qv0);
    qh[1] = pack_hi8((const unsigned*)&qv1); ql[1] = pack_lo8((const unsigned*)&qv1);
  }
  // staging: thread -> (key row sr, d-quarter sq); identical addressing for K and V
  const int sr = tid >> 2, sq = (tid & 3) * 16;
  const int jq = tid & 3;   // lane stagger for conflict-free V transpose writes
  u32x4 kr[4], vr[4];
  {
    const size_t ko = base + (size_t)sr * HDIM + sq;
#pragma unroll
    for (int i = 0; i < 4; i++) {
      kr[i] = *(const u32x4*)&Kp[ko + 4 * i];
      vr[i] = *(const u32x4*)&Vp[ko + 4 * i];
    }
  }
  float m_ = -1e30f, l_ = 0.f;          // per-lane, q-row = q0+16w+l15
  f32x4 acc[4] = {};                    // acc[n][r]: q-rel=4lq+r, d=16n+l15

  for (int kt = 0; kt < 16; kt++) {
    // K: linear rows; V: transpose d->row (staggered, conflict-free)
#pragma unroll
    for (int i = 0; i < 4; i++) *(u32x4*)&KL[sr][sq + 4 * i] = kr[i];
#pragma unroll
    for (int j = 0; j < 16; j++) {
      const int jj = j ^ jq;
      VL[sq + jj][sr] = vr[jj >> 2][jj & 3];
    }
    __syncthreads();
    if (kt < 15) {   // T14 prefetch
      const size_t ko = base + (size_t)((kt + 1) * 64 + sr) * HDIM + sq;
#pragma unroll
      for (int i = 0; i < 4; i++) {
        kr[i] = *(const u32x4*)&Kp[ko + 4 * i];
        vr[i] = *(const u32x4*)&Vp[ko + 4 * i];
      }
    }
    // ---- QK^T (swapped): sc[n][r] = S[k=16n+4lq+r][q=l15] ----
    f32x4 sc[4] = {};
#pragma unroll
    for (int c = 0; c < 2; c++) {
      short8 kfh[4], kfl[4];
#pragma unroll
      for (int n = 0; n < 4; n++) {
        u32x8 k32 = *(const u32x8*)&KL[16 * n + l15][c * 32 + lq * 8];
        kfh[n] = pack_hi8((const unsigned*)&k32);
        kfl[n] = pack_lo8((const unsigned*)&k32);
      }
#pragma unroll
      for (int n = 0; n < 4; n++) {
        sc[n] = __builtin_amdgcn_mfma_f32_16x16x32_bf16(kfh[n], qh[c], sc[n], 0, 0, 0);
        sc[n] = __builtin_amdgcn_mfma_f32_16x16x32_bf16(kfl[n], qh[c], sc[n], 0, 0, 0);
        sc[n] = __builtin_amdgcn_mfma_f32_16x16x32_bf16(kfh[n], ql[c], sc[n], 0, 0, 0);
      }
    }
    // ---- online softmax, per-lane scalar state ----
    float tm = fmaxf(fmaxf(fmaxf(sc[0][0], sc[0][1]), fmaxf(sc[0][2], sc[0][3])),
                     fmaxf(fmaxf(sc[1][0], sc[1][1]), fmaxf(sc[1][2], sc[1][3])));
    tm = fmaxf(tm, fmaxf(fmaxf(fmaxf(sc[2][0], sc[2][1]), fmaxf(sc[2][2], sc[2][3])),
                         fmaxf(fmaxf(sc[3][0], sc[3][1]), fmaxf(sc[3][2], sc[3][3]))));
    tm = fmaxf(tm, __shfl_xor(tm, 16));
    tm = fmaxf(tm, __shfl_xor(tm, 32));
    const float mn = fmaxf(m_, tm);
    const float esc = __expf(m_ - mn);
    m_ = mn;
    float rs = 0.f;
    unsigned pk[4][4];
#pragma unroll
    for (int n = 0; n < 4; n++) {
#pragma unroll
      for (int r = 0; r < 4; r++) {
        const float p = __expf(sc[n][r] - mn);
        rs += p;
        const unsigned short hh = f2bf(p);
        pk[n][r] = ((unsigned)hh << 16) | (unsigned)f2bf(p - bf2f(hh));
      }
    }
    rs += __shfl_xor(rs, 16);
    rs += __shfl_xor(rs, 32);
    l_ = l_ * esc + rs;
    float escR[4];
#pragma unroll
    for (int r = 0; r < 4; r++) escR[r] = __shfl(esc, 4 * lq + r);
#pragma unroll
    for (int n = 0; n < 4; n++) {
#pragma unroll
      for (int r = 0; r < 4; r++) acc[n][r] *= escR[r];
    }
    // ---- PV: in-register P redistribution, 3-term MFMA ----
#pragma unroll
    for (int c = 0; c < 2; c++) {
      unsigned val[8];
#pragma unroll
      for (int j = 0; j < 8; j++) {
        const int src = (j >> 2) ? srcB : srcA;
        const unsigned sA = (unsigned)__shfl((int)pk[2 * c + 0][j & 3], src);
        const unsigned sB = (unsigned)__shfl((int)pk[2 * c + 1][j & 3], src);
        val[j] = selHi ? sB : sA;
      }
      const short8 ph = pack_hi8(val);
      const short8 plo = pack_lo8(val);
      short8 vfh[4], vfl[4];
#pragma unroll
      for (int n = 0; n < 4; n++) {
        u32x8 v32 = *(const u32x8*)&VL[16 * n + l15][c * 32 + lq * 8];
        vfh[n] = pack_hi8((const unsigned*)&v32);
        vfl[n] = pack_lo8((const unsigned*)&v32);
      }
#pragma unroll
      for (int n = 0; n < 4; n++) {
        acc[n] = __builtin_amdgcn_mfma_f32_16x16x32_bf16(ph, vfh[n], acc[n], 0, 0, 0);
        acc[n] = __builtin_amdgcn_mfma_f32_16x16x32_bf16(ph, vfl[n], acc[n], 0, 0, 0);
        acc[n] = __builtin_amdgcn_mfma_f32_16x16x32_bf16(plo, vfh[n], acc[n], 0, 0, 0);
      }
    }
    __syncthreads();
  }
  const float inv = 1.f / l_;
  float invR[4];
#pragma unroll
  for (int r = 0; r < 4; r++) invR[r] = __shfl(inv, 4 * lq + r);
#pragma unroll
  for (int r = 0; r < 4; r++) {
    const int srow = q0 + 16 * w + 4 * lq + r;
    float* orow = &O[((size_t)srow * BATCH + b) * DIM + h * HDIM];
#pragma unroll
    for (int n = 0; n < 4; n++) orow[16 * n + l15] = acc[n][r] * invR[r];
  }
}

// ---------------- layernorm: x = LN(src + proj)*g + b -> out ----------------
__global__ __launch_bounds__(256) void k_ln(const float* __restrict__ src,
                                            const float* __restrict__ proj,
                                            const float* __restrict__ g,
                                            const float* __restrict__ bt,
                                            float* __restrict__ xout) {
  const int wid = threadIdx.x >> 6, lane = threadIdx.x & 63;
  const int tok = blockIdx.x * 4 + wid;
  const size_t base = (size_t)tok * DIM + lane * 8;
  f4 a0 = *(const f4*)&src[base],  a1 = *(const f4*)&src[base + 4];
  f4 p0 = *(const f4*)&proj[base], p1 = *(const f4*)&proj[base + 4];
  float x[8];
  x[0] = a0[0] + p0[0]; x[1] = a0[1] + p0[1]; x[2] = a0[2] + p0[2]; x[3] = a0[3] + p0[3];
  x[4] = a1[0] + p1[0]; x[5] = a1[1] + p1[1]; x[6] = a1[2] + p1[2]; x[7] = a1[3] + p1[3];
  float s = 0.f, sq = 0.f;
#pragma unroll
  for (int j = 0; j < 8; j++) { s += x[j]; sq = fmaf(x[j], x[j], sq); }
#pragma unroll
  for (int d = 1; d < 64; d <<= 1) { s += __shfl_xor(s, d); sq += __shfl_xor(sq, d); }
  const float mean = s * (1.f / 512.f);
  const float var = sq * (1.f / 512.f) - mean * mean;
  const float rstd = 1.f / sqrtf(var + 1e-5f);
  const int ci = lane * 8;
  f4 o0v, o1v;
#pragma unroll
  for (int j = 0; j < 4; j++) o0v[j] = (x[j] - mean) * rstd * g[ci + j] + bt[ci + j];
#pragma unroll
  for (int j = 0; j < 4; j++) o1v[j] = (x[4 + j] - mean) * rstd * g[ci + 4 + j] + bt[ci + 4 + j];
  *(f4*)&xout[base] = o0v;
  *(f4*)&xout[base + 4] = o1v;
}

// ---------------- gate: block = 16 tokens x 16 experts, 4 tiles ----------------
__global__ __launch_bounds__(256) void k_gate(const float* __restrict__ x,
                                              const float* __restrict__ gw,
                                              const float* __restrict__ gb,
                                              int* __restrict__ topi,
                                              float* __restrict__ topw,
                                              int* __restrict__ counts) {
  __shared__ float xs[16 * 520];
  __shared__ int hist[16];
  const int tid = threadIdx.x;
  const int tl = tid >> 4, e = tid & 15;
  if (tid < 16) hist[tid] = 0;
  const float gbe = gb[e];
  const float* wrow = gw + (size_t)e * DIM;
  for (int tile = 0; tile < 4; tile++) {
    const int t0 = blockIdx.x * 64 + tile * 16;
    __syncthreads();
    {
      const int r = tid >> 4, cbase = (tid & 15) * 32;
#pragma unroll
      for (int j = 0; j < 8; j++) {
        const int c = cbase + j * 4;
        const int ch = c >> 2;
        const int pc = ch ^ ((ch >> 3) & 7);
        *(f4*)&xs[r * 520 + pc * 4] = *(const f4*)&x[(size_t)(t0 + r) * DIM + c];
      }
    }
    __syncthreads();
    float d = gbe;
#pragma unroll 8
    for (int c = 0; c < DIM; c += 4) {
      const int ch = c >> 2;
      const int pc = ch ^ ((ch >> 3) & 7);
      f4 xv = *(const f4*)&xs[tl * 520 + pc * 4];
      f4 wv = *(const f4*)&wrow[c];
      d = fmaf(xv[0], wv[0], d); d = fmaf(xv[1], wv[1], d);
      d = fmaf(xv[2], wv[2], d); d = fmaf(xv[3], wv[3], d);
    }
    float v1 = d, v2 = -1e30f;
    int i1 = e, i2 = 1000;
#pragma unroll
    for (int s = 1; s < 16; s <<= 1) {
      const float ov1 = __shfl_xor(v1, s), ov2 = __shfl_xor(v2, s);
      const int oi1 = __shfl_xor(i1, s), oi2 = __shfl_xor(i2, s);
      if (ov1 > v1 || (ov1 == v1 && oi1 < i1)) {
        float nv2; int ni2;
        if (v1 > ov2 || (v1 == ov2 && i1 < oi2)) { nv2 = v1; ni2 = i1; }
        else { nv2 = ov2; ni2 = oi2; }
        v1 = ov1; i1 = oi1; v2 = nv2; i2 = ni2;
      } else if (ov1 > v2 || (ov1 == v2 && oi1 < i2)) {
        v2 = ov1; i2 = oi1;
      }
    }
    if (e == 0) {
      const int t = t0 + tl;
      const float e1 = __expf(v2 - v1);
      const float inv = 1.f / (1.f + e1);
      topi[2 * t] = i1;  topi[2 * t + 1] = i2;
      topw[2 * t] = inv; topw[2 * t + 1] = e1 * inv;
      atomicAdd(&hist[i1], 1);
      atomicAdd(&hist[i2], 1);
    }
  }
  __syncthreads();
  if (tid < 16 && hist[tid] > 0) atomicAdd(&counts[tid], hist[tid]);
}

__global__ void k_offsets(const int* __restrict__ counts,
                          int* __restrict__ off_pad, int* __restrict__ cursor) {
  if (threadIdx.x == 0) {
    int o = 0;
    off_pad[0] = 0;
    for (int e = 0; e < NE; e++) {
      cursor[e] = 0;
      o += ((counts[e] + BM - 1) / BM) * BM;
      off_pad[e + 1] = o;
    }
  }
}

// ---------------- scatter: batched slot claims ----------------
__global__ __launch_bounds__(256) void k_scatter(const float* __restrict__ x,
                                                 const int* __restrict__ topi,
                                                 const float* __restrict__ topw,
                                                 const int* __restrict__ off_pad,
                                                 int* __restrict__ cursor,
                                                 int* __restrict__ slotTok,
                                                 float* __restrict__ slotW,
                                                 unsigned short* __restrict__ Xg) {
  __shared__ int lcnt[16];
  __shared__ int gbase[16];
  __shared__ int posArr[128];
  const int tid = threadIdx.x;
  const int a0 = blockIdx.x * 128;
  if (tid < 16) lcnt[tid] = 0;
  __syncthreads();
  if (tid < 128) {
    const int a = a0 + tid;
    const int e = topi[a];
    const int lrank = atomicAdd(&lcnt[e], 1);
    posArr[tid] = (e << 24) | lrank;
  }
  __syncthreads();
  if (tid < 16) {
    const int c = lcnt[tid];
    gbase[tid] = (c > 0) ? atomicAdd(&cursor[tid], c) : 0;
  }
  __syncthreads();
  if (tid < 128) {
    const int a = a0 + tid;
    const int pk = posArr[tid];
    const int e = pk >> 24, lrank = pk & 0xffffff;
    const int pos = off_pad[e] + gbase[e] + lrank;
    posArr[tid] = pos;
    slotTok[pos] = a >> 1;
    slotW[pos] = topw[a];
  }
  __syncthreads();
  const int w = tid >> 6, lane = tid & 63;
#pragma unroll 4
  for (int i = 0; i < 32; i++) {
    const int idx = w * 32 + i;
    const int pos = posArr[idx];
    const int tok = (a0 + idx) >> 1;
    const size_t sb = (size_t)tok * DIM + lane * 8;
    f4 v0 = *(const f4*)&x[sb], v1 = *(const f4*)&x[sb + 4];
    u16x8 hh;
    hh[0] = f2bf(v0[0]); hh[1] = f2bf(v0[1]); hh[2] = f2bf(v0[2]); hh[3] = f2bf(v0[3]);
    hh[4] = f2bf(v1[0]); hh[5] = f2bf(v1[1]); hh[6] = f2bf(v1[2]); hh[7] = f2bf(v1[3]);
    *(u16x8*)&Xg[(size_t)pos * DIM + lane * 8] = hh;
  }
}

// ---------------- grouped bf16 MFMA GEMM (MoE), T2 swizzle + T1 XCD swizzle ----------------
__global__ __launch_bounds__(256) void k_gemm_bf16(
    const unsigned short* __restrict__ A, int lda,
    const unsigned short* __restrict__ Wb, size_t westride, int ldw, int wrow0,
    const float* __restrict__ bias, int bstride, int brow0,
    int K, int epi,
    unsigned short* __restrict__ Hout, int ldh,
    float* __restrict__ dout,
    const int* __restrict__ slotTok, const float* __restrict__ slotW,
    const int* __restrict__ off_pad) {
  int bx = blockIdx.x;
  const int nwg = gridDim.x;
  if ((nwg & 7) == 0) bx = (bx & 7) * (nwg >> 3) + (bx >> 3);
  const int m0 = bx * BM;
  if (m0 >= off_pad[NE]) return;
  int e = 0;
  while (off_pad[e + 1] <= m0) e++;
  const unsigned short* W = Wb + (size_t)e * westride;
  const int n0 = blockIdx.y * 128;
  __shared__ unsigned short Al[128 * 64];
  __shared__ unsigned short Bl[128 * 64];
  const int tid = threadIdx.x, lane = tid & 63, wid = tid >> 6;
  const int wm = wid >> 1, wn = wid & 1;
  f32x4 acc[4][4] = {};
  const int srow = wid * 32 + (lane >> 3);
  const int scol = (((lane & 7) ^ ((lane >> 3) & 7)) << 3);
  for (int k0 = 0; k0 < K; k0 += 64) {
    const unsigned short* ga = A + (size_t)(m0 + srow) * lda + k0 + scol;
    const unsigned short* gw = W + (size_t)(wrow0 + n0 + srow) * ldw + k0 + scol;
#pragma unroll
    for (int i = 0; i < 4; i++) {
      load_lds16(ga + (size_t)i * 8 * lda, &Al[(wid * 32 + i * 8) * 64]);
      load_lds16(gw + (size_t)i * 8 * ldw, &Bl[(wid * 32 + i * 8) * 64]);
    }
    __syncthreads();
#pragma unroll
    for (int kk = 0; kk < 2; kk++) {
      short8 av[4], bv[4];
      const int ckx = (kk * 4 + (lane >> 4)) ^ (lane & 7);
#pragma unroll
      for (int mi = 0; mi < 4; mi++)
        av[mi] = *(const short8*)&Al[(wm * 64 + mi * 16 + (lane & 15)) * 64 + ckx * 8];
#pragma unroll
      for (int ni = 0; ni < 4; ni++)
        bv[ni] = *(const short8*)&Bl[(wn * 64 + ni * 16 + (lane & 15)) * 64 + ckx * 8];
#pragma unroll
      for (int mi = 0; mi < 4; mi++) {
#pragma unroll
        for (int ni = 0; ni < 4; ni++)
          acc[mi][ni] = __builtin_amdgcn_mfma_f32_16x16x32_bf16(av[mi], bv[ni], acc[mi][ni], 0, 0, 0);
      }
    }
    __syncthreads();
  }
#pragma unroll
  for (int mi = 0; mi < 4; mi++) {
    const int rb = m0 + wm * 64 + mi * 16 + ((lane >> 4) << 2);
#pragma unroll
    for (int ni = 0; ni < 4; ni++) {
      const int n = n0 + wn * 64 + ni * 16 + (lane & 15);
      const float bn = bias ? bias[(size_t)e * bstride + brow0 + n] : 0.f;
      if (epi == 0) {
#pragma unroll
        for (int r = 0; r < 4; r++) {
          float v = acc[mi][ni][r] + bn;
          v = fmaxf(v, 0.f);
          Hout[(size_t)(rb + r) * ldh + n] = f2bf(v);
        }
      } else {
#pragma unroll
        for (int r = 0; r < 4; r++) {
          const int tok = slotTok[rb + r];
          if (tok >= 0) {
            const float v = (acc[mi][ni][r] + bn) * slotW[rb + r];
            atomicAdd(&dout[(size_t)tok * DIM + n], v);
          }
        }
      }
    }
  }
}

// ---------------- launch ----------------
extern "C" void kernel_launch(void* const* d_in, const int* in_sizes, int n_in,
                              void* d_out, int out_size, void* d_ws, size_t ws_size,
                              hipStream_t stream) {
  const float* src       = (const float*)d_in[0];
  const float* pos       = (const float*)d_in[1];
  const float* in_proj_w = (const float*)d_in[2];
  const float* in_proj_b = (const float*)d_in[3];
  const float* out_w     = (const float*)d_in[4];
  const float* out_b     = (const float*)d_in[5];
  const float* norm1_g   = (const float*)d_in[6];
  const float* norm1_b   = (const float*)d_in[7];
  const float* gate_w    = (const float*)d_in[8];
  const float* gate_b    = (const float*)d_in[9];
  const float* w1        = (const float*)d_in[10];
  const float* b1        = (const float*)d_in[11];
  const float* w2        = (const float*)d_in[12];
  const float* b2        = (const float*)d_in[13];
  float* out = (float*)d_out;
  char* wsb = (char*)d_ws;

  // ---- lifetime-packed arena (~166.5 MiB, unchanged footprint) ----
  // packed u32 planes [B,H,S,HD], 32 MiB each, occupy [0, 96 MiB)
  unsigned* Qp = (unsigned*)(wsb + 0);
  unsigned* Kp = (unsigned*)(wsb + 33554432);
  unsigned* Vp = (unsigned*)(wsb + 67108864);
  float* ob = (float*)(wsb + 100663296);
  float* proj = (float*)(wsb + 0);
  unsigned short* w1b = (unsigned short*)(wsb + 0);
  unsigned short* w2b = (unsigned short*)(wsb + 33554432);
  unsigned short* Xg  = (unsigned short*)(wsb + 67108864);
  unsigned short* Hb  = (unsigned short*)(wsb + 102760448);
  unsigned short* wih = (unsigned short*)(wsb + 134217728);
  unsigned short* wil = (unsigned short*)(wsb + 135790592);
  char* smallb = wsb + 174063616;
  int*   topi    = (int*)  (smallb + 0);
  float* topw    = (float*)(smallb + 131072);
  int*   slotTok = (int*)  (smallb + 262144);
  float* slotW   = (float*)(smallb + 401408);
  int*   counts  = (int*)  (smallb + 540672);
  int*   off_pad = (int*)  (smallb + 540736);
  int*   cursor  = (int*)  (smallb + 540864);

  // 1. routing init + in_proj weight split
  k_init<<<(CAP + 255) / 256, 256, 0, stream>>>(slotTok, slotW, counts);
  k_split_w<<<768, 256, 0, stream>>>(in_proj_w, wih, wil, (size_t)1536 * 512);
  // 2. Q/K projection (split MFMA, fused src+pos) -> packed planes
  k_gemm_split<<<dim3(128, 8), 256, 0, stream>>>(src, pos, wih, wil, in_proj_b, 0, Qp, Kp);
  // 3. V projection -> packed plane
  k_gemm_split<<<dim3(128, 4), 256, 0, stream>>>(src, nullptr, wih + (size_t)1024 * 512,
                                                 wil + (size_t)1024 * 512, in_proj_b + 1024,
                                                 1, Vp, nullptr);
  // 4. split-MFMA flash attention -> ob [S,B,D]
  k_attn<<<dim3(16, 128), 256, 0, stream>>>(Qp, Kp, Vp, ob);
  // 5. w2 -> bf16 (K plane dead)
  k_cvt_bf16<<<2048, 256, 0, stream>>>(w2, w2b, (size_t)NE * DIM * DFF);
  // 6. output projection (fp32 vector — gate-critical) -> proj (over Qp)
  k_gemm_f32<<<dim3(128, 4), 256, 0, stream>>>(ob, out_w, out_b, 512, proj);
  // 7. layernorm(src + proj) -> d_out (= x)
  k_ln<<<4096, 256, 0, stream>>>(src, proj, norm1_g, norm1_b, out);
  // 8. w1 -> bf16 (proj dead)
  k_cvt_bf16<<<2048, 256, 0, stream>>>(w1, w1b, (size_t)NE * DFF * DIM);
  // 9. gate logits + top2 + counts
  k_gate<<<T_TOK / 64, 256, 0, stream>>>(out, gate_w, gate_b, topi, topw, counts);
  // 10. padded segment offsets
  k_offsets<<<1, 64, 0, stream>>>(counts, off_pad, cursor);
  // 11. zero only padding rows of Xg
  k_zero_pad<<<NE, 256, 0, stream>>>(counts, off_pad, Xg);
  // 12. scatter assignments + gather token rows as bf16
  k_scatter<<<256, 256, 0, stream>>>(out, topi, topw, off_pad, cursor, slotTok, slotW, Xg);
  // 13. MoE, DFF halved
  for (int p = 0; p < 2; ++p) {
    k_gemm_bf16<<<dim3(CAP / BM, 8), 256, 0, stream>>>(
        Xg, DIM, w1b, (size_t)DFF * DIM, DIM, p * 1024,
        b1, DFF, p * 1024, DIM, 0, Hb, 1024,
        nullptr, nullptr, nullptr, off_pad);
    k_gemm_bf16<<<dim3(CAP / BM, 4), 256, 0, stream>>>(
        Hb, 1024, w2b + (size_t)p * 1024, (size_t)DIM * DFF, DFF, 0,
        (p == 0 ? b2 : nullptr), DIM, 0, 1024, 1, nullptr, 0,
        out, slotTok, slotW, off_pad);
  }
}

// Round 10
// 962.938 us; speedup vs baseline: 2.6104x; 1.0231x over previous
//
#include <hip/hip_runtime.h>
#include <hip/hip_bf16.h>

// ---------------- types ----------------
typedef float f4 __attribute__((ext_vector_type(4)));
typedef float f32x4 __attribute__((ext_vector_type(4)));
typedef short short8 __attribute__((ext_vector_type(8)));
typedef unsigned short u16x4 __attribute__((ext_vector_type(4)));
typedef unsigned short u16x8 __attribute__((ext_vector_type(8)));
typedef unsigned int u32x4 __attribute__((ext_vector_type(4)));
typedef unsigned int u32x8 __attribute__((ext_vector_type(8)));

// ---------------- problem constants ----------------
#define S_LEN 1024
#define BATCH 16
#define DIM   512
#define NH    8
#define HDIM  64
#define NE    16
#define DFF   2048
#define T_TOK 16384   // S*B
#define CAP   34816   // 32768 assignments + per-expert padding to BM
#define BM    128

__device__ __forceinline__ unsigned short f2bf(float f) {
  union { float f; unsigned u; } v; v.f = f;
  unsigned r = v.u + 0x7fffu + ((v.u >> 16) & 1u);  // RTNE
  return (unsigned short)(r >> 16);
}
__device__ __forceinline__ float bf2f(unsigned short h) {
  union { unsigned u; float f; } v; v.u = ((unsigned)h) << 16;
  return v.f;
}

__device__ __forceinline__ void load_lds16(const void* g, void* l) {
  __builtin_amdgcn_global_load_lds(
      (__attribute__((address_space(1))) void*)(void*)g,
      (__attribute__((address_space(3))) void*)l, 16, 0, 0);
}

// extract hi/lo bf16 planes from 8 packed u32 (hi16|lo16)
__device__ __forceinline__ short8 pack_hi8(const unsigned* val) {
  union { unsigned u[4]; short8 s; } t;
#pragma unroll
  for (int i = 0; i < 4; i++)
    t.u[i] = (val[2 * i] >> 16) | (val[2 * i + 1] & 0xFFFF0000u);
  return t.s;
}
__device__ __forceinline__ short8 pack_lo8(const unsigned* val) {
  union { unsigned u[4]; short8 s; } t;
#pragma unroll
  for (int i = 0; i < 4; i++)
    t.u[i] = (val[2 * i] & 0xFFFFu) | (val[2 * i + 1] << 16);
  return t.s;
}

// ---------------- small utility kernels ----------------
__global__ __launch_bounds__(256) void k_cvt_bf16(const float* __restrict__ in,
                                                  unsigned short* __restrict__ outb,
                                                  size_t n) {
  size_t i = ((size_t)blockIdx.x * 256 + threadIdx.x) * 4;
  size_t stride = (size_t)gridDim.x * 1024;
  for (; i < n; i += stride) {
    f4 v = *(const f4*)&in[i];
    u16x4 o;
    o[0] = f2bf(v[0]); o[1] = f2bf(v[1]); o[2] = f2bf(v[2]); o[3] = f2bf(v[3]);
    *(u16x4*)&outb[i] = o;
  }
}

// split fp32 -> bf16 hi + bf16 lo (lo = round(x - hi))
__global__ __launch_bounds__(256) void k_split_w(const float* __restrict__ in,
                                                 unsigned short* __restrict__ hi,
                                                 unsigned short* __restrict__ lo,
                                                 size_t n) {
  size_t i = ((size_t)blockIdx.x * 256 + threadIdx.x) * 4;
  size_t stride = (size_t)gridDim.x * 1024;
  for (; i < n; i += stride) {
    f4 v = *(const f4*)&in[i];
    u16x4 h, l;
#pragma unroll
    for (int j = 0; j < 4; j++) {
      unsigned short hh = f2bf(v[j]);
      h[j] = hh;
      l[j] = f2bf(v[j] - bf2f(hh));
    }
    *(u16x4*)&hi[i] = h;
    *(u16x4*)&lo[i] = l;
  }
}

__global__ __launch_bounds__(256) void k_init(int* __restrict__ slotTok,
                                              float* __restrict__ slotW,
                                              int* __restrict__ counts) {
  int i = blockIdx.x * 256 + threadIdx.x;
  if (i < CAP) { slotTok[i] = -1; slotW[i] = 0.f; }
  if (i < NE) counts[i] = 0;
}

// zero only the padding rows of each expert segment
__global__ __launch_bounds__(256) void k_zero_pad(const int* __restrict__ counts,
                                                  const int* __restrict__ off_pad,
                                                  unsigned short* __restrict__ Xg) {
  const int e = blockIdx.x;
  const int start = off_pad[e] + counts[e];
  const int end = off_pad[e + 1];
  for (int row = start; row < end; row++)
    *(unsigned int*)&Xg[(size_t)row * DIM + threadIdx.x * 2] = 0u;
}

// ---------------- split-bf16 MFMA GEMM (fp32-accurate via hi/lo) ----------------
// C = (A [+A2])[M,512] * W[N,512]^T + bias; outputs packed-u32 (hi<<16|lo) planes.
// epi 0: n<512 -> Q*0.125 -> p0 [B,H,S,HD]; n>=512 -> K -> p1 [B,H,S,HD]  (direct store)
// epi 1: V -> p0 [B,H,HD,S]  (LDS-bounce transposed, 32B-run coalesced stores)
__global__ __launch_bounds__(256, 2) void k_gemm_split(
    const float* __restrict__ A, const float* __restrict__ A2,
    const unsigned short* __restrict__ Wh, const unsigned short* __restrict__ Wl,
    const float* __restrict__ bias, int epi,
    unsigned* __restrict__ p0, unsigned* __restrict__ p1) {
  __shared__ __align__(16) char smem[33792];   // staging 32 KB | bounce 128x66 u32
  unsigned short* AhL = (unsigned short*)smem;
  unsigned short* AlL = (unsigned short*)(smem + 8192);
  unsigned short* WhL = (unsigned short*)(smem + 16384);
  unsigned short* WlL = (unsigned short*)(smem + 24576);
  unsigned* bounce = (unsigned*)smem;
  const int tid = threadIdx.x, lane = tid & 63, wid = tid >> 6;
  const int wm = wid >> 1, wn = wid & 1;
  const int m0 = blockIdx.x * 128, n0 = blockIdx.y * 128;
  const int row = tid >> 1, half = tid & 1;
  const int xr = (row >> 1) & 3;
  f32x4 acc[4][4] = {};
  f4 ar[4];
#pragma unroll
  for (int j = 0; j < 4; j++) {
    const size_t aoff = (size_t)(m0 + row) * 512 + half * 16 + j * 4;
    ar[j] = *(const f4*)&A[aoff];
    if (A2) { f4 v2 = *(const f4*)&A2[aoff]; ar[j] += v2; }
  }
  for (int k0 = 0; k0 < 512; k0 += 32) {
    __syncthreads();
    u16x8 hi8[2], lo8[2];
#pragma unroll
    for (int j = 0; j < 16; j++) {
      const float x = ar[j >> 2][j & 3];
      const unsigned short h = f2bf(x);
      hi8[j >> 3][j & 7] = h;
      lo8[j >> 3][j & 7] = f2bf(x - bf2f(h));
    }
    const int c0 = half * 2;
    *(u16x8*)&AhL[row * 32 + (((c0 + 0) ^ xr) << 3)] = hi8[0];
    *(u16x8*)&AhL[row * 32 + (((c0 + 1) ^ xr) << 3)] = hi8[1];
    *(u16x8*)&AlL[row * 32 + (((c0 + 0) ^ xr) << 3)] = lo8[0];
    *(u16x8*)&AlL[row * 32 + (((c0 + 1) ^ xr) << 3)] = lo8[1];
#pragma unroll
    for (int i = 0; i < 2; i++) {
      const int rowW = i * 64 + wid * 16 + (lane >> 2);
      const int clog = (lane & 3) ^ ((rowW >> 1) & 3);
      const size_t woff = (size_t)(n0 + rowW) * 512 + k0 + (clog << 3);
      load_lds16(Wh + woff, &WhL[i * 2048 + wid * 512]);
      load_lds16(Wl + woff, &WlL[i * 2048 + wid * 512]);
    }
    __syncthreads();
    if (k0 + 32 < 512) {
#pragma unroll
      for (int j = 0; j < 4; j++) {
        const size_t aoff = (size_t)(m0 + row) * 512 + k0 + 32 + half * 16 + j * 4;
        ar[j] = *(const f4*)&A[aoff];
        if (A2) { f4 v2 = *(const f4*)&A2[aoff]; ar[j] += v2; }
      }
    }
    const int l15 = lane & 15, lk = lane >> 4;
    const int xa = (l15 >> 1) & 3;
    short8 avh[4], avl[4], bvh[4], bvl[4];
#pragma unroll
    for (int mi = 0; mi < 4; mi++) {
      const int mr = wm * 64 + mi * 16 + l15;
      avh[mi] = *(const short8*)&AhL[mr * 32 + ((lk ^ xa) << 3)];
      avl[mi] = *(const short8*)&AlL[mr * 32 + ((lk ^ xa) << 3)];
    }
#pragma unroll
    for (int ni = 0; ni < 4; ni++) {
      const int nr = wn * 64 + ni * 16 + l15;
      bvh[ni] = *(const short8*)&WhL[nr * 32 + ((lk ^ xa) << 3)];
      bvl[ni] = *(const short8*)&WlL[nr * 32 + ((lk ^ xa) << 3)];
    }
#pragma unroll
    for (int mi = 0; mi < 4; mi++) {
#pragma unroll
      for (int ni = 0; ni < 4; ni++) {
        acc[mi][ni] = __builtin_amdgcn_mfma_f32_16x16x32_bf16(avh[mi], bvh[ni], acc[mi][ni], 0, 0, 0);
        acc[mi][ni] = __builtin_amdgcn_mfma_f32_16x16x32_bf16(avh[mi], bvl[ni], acc[mi][ni], 0, 0, 0);
        acc[mi][ni] = __builtin_amdgcn_mfma_f32_16x16x32_bf16(avl[mi], bvh[ni], acc[mi][ni], 0, 0, 0);
      }
    }
  }
  const int l15 = lane & 15, lq = lane >> 4;
  if (epi == 0) {
    // direct packed store, coalesced along head-dim
#pragma unroll
    for (int mi = 0; mi < 4; mi++) {
      const int rb = m0 + wm * 64 + mi * 16 + (lq << 2);
#pragma unroll
      for (int ni = 0; ni < 4; ni++) {
        const int n = n0 + wn * 64 + ni * 16 + l15;
        const float bn = bias[n];
#pragma unroll
        for (int r = 0; r < 4; r++) {
          const int m = rb + r;
          const int bidx = m & 15, ss = m >> 4;   // token = s*B + b
          float v = acc[mi][ni][r] + bn;
          unsigned* pl;
          int nn;
          if (n < 512) { v *= 0.125f; pl = p0; nn = n; }
          else { pl = p1; nn = n - 512; }
          const size_t off = ((size_t)(bidx * NH + (nn >> 6)) * S_LEN + ss) * HDIM + (nn & 63);
          const unsigned short hh = f2bf(v);
          pl[off] = ((unsigned)hh << 16) | (unsigned)f2bf(v - bf2f(hh));
        }
      }
    }
  } else {
    // V: bounce through LDS, store [B,H,HD,S] with 8-consecutive-s 32B runs
    const int s_base = m0 >> 4;   // = blockIdx.x * 8
    for (int halfn = 0; halfn < 2; halfn++) {
      __syncthreads();
      if (wn == halfn) {
#pragma unroll
        for (int mi = 0; mi < 4; mi++) {
          const int mlb = wm * 64 + mi * 16 + (lq << 2);
#pragma unroll
          for (int ni = 0; ni < 4; ni++) {
            const int n = n0 + wn * 64 + ni * 16 + l15;
            const float bn = bias[n];
            const int nc = ni * 16 + l15;
#pragma unroll
            for (int r = 0; r < 4; r++) {
              const float v = acc[mi][ni][r] + bn;
              const unsigned short hh = f2bf(v);
              bounce[(mlb + r) * 66 + nc] =
                  ((unsigned)hh << 16) | (unsigned)f2bf(v - bf2f(hh));
            }
          }
        }
      }
      __syncthreads();
#pragma unroll
      for (int i = 0; i < 4; i++) {
        const int idx = tid + 256 * i;        // 0..1023
        const int nc = idx & 63, bb = idx >> 6;
        const int ng = n0 + halfn * 64 + nc;
        const int hh_ = ng >> 6, dd = ng & 63;
        u32x8 vals;
#pragma unroll
        for (int s = 0; s < 8; s++) vals[s] = bounce[(s * 16 + bb) * 66 + nc];
        *(u32x8*)&p0[((size_t)(bb * NH + hh_) * HDIM + dd) * S_LEN + s_base] = vals;
      }
    }
  }
}

// ---------------- fp32 GEMM (out-proj only): C = A[M,K]*W[N,K]^T + bias ----------------
__global__ __launch_bounds__(256, 3) void k_gemm_f32(
    const float* __restrict__ A, const float* __restrict__ W,
    const float* __restrict__ bias, int K,
    float* __restrict__ o0) {
  __shared__ float Alt[32][132];
  __shared__ float Wlt[32][132];
  const int tid = threadIdx.x, tx = tid & 15, ty = tid >> 4;
  const int m0 = blockIdx.x * 128, n0 = blockIdx.y * 128;
  float acc[8][8];
#pragma unroll
  for (int i = 0; i < 8; i++) {
#pragma unroll
    for (int j = 0; j < 8; j++) acc[i][j] = 0.f;
  }
  f4 ar[4], wr[4];
#pragma unroll
  for (int i = 0; i < 4; i++) {
    const int c = tid + i * 256;
    const int r = c >> 3, j = (c & 7) * 4;
    ar[i] = *(const f4*)&A[(size_t)(m0 + r) * K + j];
    wr[i] = *(const f4*)&W[(size_t)(n0 + r) * K + j];
  }
  for (int k0 = 0; k0 < K; k0 += 32) {
    __syncthreads();
#pragma unroll
    for (int i = 0; i < 4; i++) {
      const int c = tid + i * 256;
      const int r = c >> 3, j = (c & 7) * 4;
      Alt[j + 0][r] = ar[i][0]; Alt[j + 1][r] = ar[i][1];
      Alt[j + 2][r] = ar[i][2]; Alt[j + 3][r] = ar[i][3];
      Wlt[j + 0][r] = wr[i][0]; Wlt[j + 1][r] = wr[i][1];
      Wlt[j + 2][r] = wr[i][2]; Wlt[j + 3][r] = wr[i][3];
    }
    __syncthreads();
    if (k0 + 32 < K) {
#pragma unroll
      for (int i = 0; i < 4; i++) {
        const int c = tid + i * 256;
        const int r = c >> 3, j = (c & 7) * 4;
        ar[i] = *(const f4*)&A[(size_t)(m0 + r) * K + k0 + 32 + j];
        wr[i] = *(const f4*)&W[(size_t)(n0 + r) * K + k0 + 32 + j];
      }
    }
#pragma unroll 4
    for (int kk = 0; kk < 32; kk++) {
      float a[8], w8[8];
      *(f4*)&a[0]  = *(const f4*)&Alt[kk][ty * 8];
      *(f4*)&a[4]  = *(const f4*)&Alt[kk][ty * 8 + 4];
      *(f4*)&w8[0] = *(const f4*)&Wlt[kk][tx * 8];
      *(f4*)&w8[4] = *(const f4*)&Wlt[kk][tx * 8 + 4];
#pragma unroll
      for (int mi = 0; mi < 8; mi++) {
#pragma unroll
        for (int ni = 0; ni < 8; ni++)
          acc[mi][ni] = fmaf(a[mi], w8[ni], acc[mi][ni]);
      }
    }
  }
#pragma unroll
  for (int mi = 0; mi < 8; mi++) {
    const size_t m = (size_t)(m0 + ty * 8 + mi);
#pragma unroll
    for (int nj = 0; nj < 2; nj++) {
      const int n = n0 + tx * 8 + nj * 4;
      f4 v;
      v[0] = acc[mi][nj * 4 + 0] + bias[n + 0];
      v[1] = acc[mi][nj * 4 + 1] + bias[n + 1];
      v[2] = acc[mi][nj * 4 + 2] + bias[n + 2];
      v[3] = acc[mi][nj * 4 + 3] + bias[n + 3];
      *(f4*)&o0[m * 512 + n] = v;
    }
  }
}

// ---------------- split-bf16 MFMA flash attention ----------------
// Q,K packed u32 [B,H,S,HD]; V packed u32 [B,H,HD,S] (pre-transposed).
// Unpack ONCE at staging into hi/lo u16 LDS arrays; fragment reads = plain short8.
// Swapped QK^T -> in-register P. LDS = 36,864 B.
__global__ __launch_bounds__(256, 4) void k_attn(
    const unsigned* __restrict__ Qp, const unsigned* __restrict__ Kp,
    const unsigned* __restrict__ Vp, float* __restrict__ O) {
  const int q0 = blockIdx.x * 64;
  const int bh = blockIdx.y;
  const int b = bh >> 3, h = bh & 7;
  const size_t base = (size_t)bh * (S_LEN * HDIM);
  __shared__ unsigned short KhL[64][72], KlL[64][72];   // [key][d]
  __shared__ unsigned short VhL[64][72], VlL[64][72];   // [d][key]
  const int tid = threadIdx.x, lane = tid & 63, w = tid >> 6;
  const int l15 = lane & 15, lq = lane >> 4;
  const int srcA = l15 + 16 * ((2 * lq) & 3);
  const int srcB = l15 + 16 * ((2 * lq + 1) & 3);
  const bool selHi = (lane & 32) != 0;
  // Q fragments (unpack once)
  short8 qh[2], ql[2];
  {
    const size_t qoff = base + (size_t)(q0 + 16 * w + l15) * HDIM + lq * 8;
    u32x8 qv0 = *(const u32x8*)&Qp[qoff];
    u32x8 qv1 = *(const u32x8*)&Qp[qoff + 32];
    qh[0] = pack_hi8((const unsigned*)&qv0); ql[0] = pack_lo8((const unsigned*)&qv0);
    qh[1] = pack_hi8((const unsigned*)&qv1); ql[1] = pack_lo8((const unsigned*)&qv1);
  }
  // staging: thread -> row sr (K: key, V: d), col-quarter sq
  const int sr = tid >> 2, sq = (tid & 3) * 16;
  u32x4 kr[4], vr[4];
  {
    const size_t ko = base + (size_t)sr * HDIM + sq;       // K [key][d]
    const size_t vo = base + (size_t)sr * S_LEN + sq;      // V [d][key]
#pragma unroll
    for (int i = 0; i < 4; i++) {
      kr[i] = *(const u32x4*)&Kp[ko + 4 * i];
      vr[i] = *(const u32x4*)&Vp[vo + 4 * i];
    }
  }
  float m_ = -1e30f, l_ = 0.f;          // per-lane, q-row = q0+16w+l15
  f32x4 acc[4] = {};                    // acc[n][r]: q-rel=4lq+r, d=16n+l15

  for (int kt = 0; kt < 16; kt++) {
    // unpack staged regs -> hi/lo LDS (shared by all 4 waves)
    {
      const unsigned* ku = (const unsigned*)kr;
      const unsigned* vu = (const unsigned*)vr;
      *(short8*)&KhL[sr][sq + 0] = pack_hi8(ku);
      *(short8*)&KhL[sr][sq + 8] = pack_hi8(ku + 8);
      *(short8*)&KlL[sr][sq + 0] = pack_lo8(ku);
      *(short8*)&KlL[sr][sq + 8] = pack_lo8(ku + 8);
      *(short8*)&VhL[sr][sq + 0] = pack_hi8(vu);
      *(short8*)&VhL[sr][sq + 8] = pack_hi8(vu + 8);
      *(short8*)&VlL[sr][sq + 0] = pack_lo8(vu);
      *(short8*)&VlL[sr][sq + 8] = pack_lo8(vu + 8);
    }
    __syncthreads();
    if (kt < 15) {   // T14 prefetch (in flight across QK+softmax+PV)
      const int s0n = (kt + 1) * 64;
      const size_t ko = base + (size_t)(s0n + sr) * HDIM + sq;
      const size_t vo = base + (size_t)sr * S_LEN + s0n + sq;
#pragma unroll
      for (int i = 0; i < 4; i++) {
        kr[i] = *(const u32x4*)&Kp[ko + 4 * i];
        vr[i] = *(const u32x4*)&Vp[vo + 4 * i];
      }
    }
    // ---- QK^T (swapped): sc[n][r] = S[k=16n+4lq+r][q=l15] ----
    f32x4 sc[4] = {};
#pragma unroll
    for (int c = 0; c < 2; c++) {
      short8 kfh[4], kfl[4];
#pragma unroll
      for (int n = 0; n < 4; n++) {
        kfh[n] = *(const short8*)&KhL[16 * n + l15][c * 32 + lq * 8];
        kfl[n] = *(const short8*)&KlL[16 * n + l15][c * 32 + lq * 8];
      }
#pragma unroll
      for (int n = 0; n < 4; n++) {
        sc[n] = __builtin_amdgcn_mfma_f32_16x16x32_bf16(kfh[n], qh[c], sc[n], 0, 0, 0);
        sc[n] = __builtin_amdgcn_mfma_f32_16x16x32_bf16(kfl[n], qh[c], sc[n], 0, 0, 0);
        sc[n] = __builtin_amdgcn_mfma_f32_16x16x32_bf16(kfh[n], ql[c], sc[n], 0, 0, 0);
      }
    }
    // ---- online softmax, per-lane scalar state ----
    float tm = fmaxf(fmaxf(fmaxf(sc[0][0], sc[0][1]), fmaxf(sc[0][2], sc[0][3])),
                     fmaxf(fmaxf(sc[1][0], sc[1][1]), fmaxf(sc[1][2], sc[1][3])));
    tm = fmaxf(tm, fmaxf(fmaxf(fmaxf(sc[2][0], sc[2][1]), fmaxf(sc[2][2], sc[2][3])),
                         fmaxf(fmaxf(sc[3][0], sc[3][1]), fmaxf(sc[3][2], sc[3][3]))));
    tm = fmaxf(tm, __shfl_xor(tm, 16));
    tm = fmaxf(tm, __shfl_xor(tm, 32));
    const float mn = fmaxf(m_, tm);
    const float esc = __expf(m_ - mn);
    m_ = mn;
    float rs = 0.f;
    unsigned pk[4][4];
#pragma unroll
    for (int n = 0; n < 4; n++) {
#pragma unroll
      for (int r = 0; r < 4; r++) {
        const float p = __expf(sc[n][r] - mn);
        rs += p;
        const unsigned short hh = f2bf(p);
        pk[n][r] = ((unsigned)hh << 16) | (unsigned)f2bf(p - bf2f(hh));
      }
    }
    rs += __shfl_xor(rs, 16);
    rs += __shfl_xor(rs, 32);
    l_ = l_ * esc + rs;
    float escR[4];
#pragma unroll
    for (int r = 0; r < 4; r++) escR[r] = __shfl(esc, 4 * lq + r);
#pragma unroll
    for (int n = 0; n < 4; n++) {
#pragma unroll
      for (int r = 0; r < 4; r++) acc[n][r] *= escR[r];
    }
    // ---- PV: in-register P redistribution, 3-term MFMA ----
#pragma unroll
    for (int c = 0; c < 2; c++) {
      unsigned val[8];
#pragma unroll
      for (int j = 0; j < 8; j++) {
        const int src = (j >> 2) ? srcB : srcA;
        const unsigned sA = (unsigned)__shfl((int)pk[2 * c + 0][j & 3], src);
        const unsigned sB = (unsigned)__shfl((int)pk[2 * c + 1][j & 3], src);
        val[j] = selHi ? sB : sA;
      }
      const short8 ph = pack_hi8(val);
      const short8 plo = pack_lo8(val);
      short8 vfh[4], vfl[4];
#pragma unroll
      for (int n = 0; n < 4; n++) {
        vfh[n] = *(const short8*)&VhL[16 * n + l15][c * 32 + lq * 8];
        vfl[n] = *(const short8*)&VlL[16 * n + l15][c * 32 + lq * 8];
      }
#pragma unroll
      for (int n = 0; n < 4; n++) {
        acc[n] = __builtin_amdgcn_mfma_f32_16x16x32_bf16(ph, vfh[n], acc[n], 0, 0, 0);
        acc[n] = __builtin_amdgcn_mfma_f32_16x16x32_bf16(ph, vfl[n], acc[n], 0, 0, 0);
        acc[n] = __builtin_amdgcn_mfma_f32_16x16x32_bf16(plo, vfh[n], acc[n], 0, 0, 0);
      }
    }
    __syncthreads();
  }
  const float inv = 1.f / l_;
  float invR[4];
#pragma unroll
  for (int r = 0; r < 4; r++) invR[r] = __shfl(inv, 4 * lq + r);
#pragma unroll
  for (int r = 0; r < 4; r++) {
    const int srow = q0 + 16 * w + 4 * lq + r;
    float* orow = &O[((size_t)srow * BATCH + b) * DIM + h * HDIM];
#pragma unroll
    for (int n = 0; n < 4; n++) orow[16 * n + l15] = acc[n][r] * invR[r];
  }
}

// ---------------- layernorm: x = LN(src + proj)*g + b -> out ----------------
__global__ __launch_bounds__(256) void k_ln(const float* __restrict__ src,
                                            const float* __restrict__ proj,
                                            const float* __restrict__ g,
                                            const float* __restrict__ bt,
                                            float* __restrict__ xout) {
  const int wid = threadIdx.x >> 6, lane = threadIdx.x & 63;
  const int tok = blockIdx.x * 4 + wid;
  const size_t base = (size_t)tok * DIM + lane * 8;
  f4 a0 = *(const f4*)&src[base],  a1 = *(const f4*)&src[base + 4];
  f4 p0 = *(const f4*)&proj[base], p1 = *(const f4*)&proj[base + 4];
  float x[8];
  x[0] = a0[0] + p0[0]; x[1] = a0[1] + p0[1]; x[2] = a0[2] + p0[2]; x[3] = a0[3] + p0[3];
  x[4] = a1[0] + p1[0]; x[5] = a1[1] + p1[1]; x[6] = a1[2] + p1[2]; x[7] = a1[3] + p1[3];
  float s = 0.f, sq = 0.f;
#pragma unroll
  for (int j = 0; j < 8; j++) { s += x[j]; sq = fmaf(x[j], x[j], sq); }
#pragma unroll
  for (int d = 1; d < 64; d <<= 1) { s += __shfl_xor(s, d); sq += __shfl_xor(sq, d); }
  const float mean = s * (1.f / 512.f);
  const float var = sq * (1.f / 512.f) - mean * mean;
  const float rstd = 1.f / sqrtf(var + 1e-5f);
  const int ci = lane * 8;
  f4 o0v, o1v;
#pragma unroll
  for (int j = 0; j < 4; j++) o0v[j] = (x[j] - mean) * rstd * g[ci + j] + bt[ci + j];
#pragma unroll
  for (int j = 0; j < 4; j++) o1v[j] = (x[4 + j] - mean) * rstd * g[ci + 4 + j] + bt[ci + 4 + j];
  *(f4*)&xout[base] = o0v;
  *(f4*)&xout[base + 4] = o1v;
}

// ---------------- gate: block = 16 tokens x 16 experts, 4 tiles ----------------
__global__ __launch_bounds__(256) void k_gate(const float* __restrict__ x,
                                              const float* __restrict__ gw,
                                              const float* __restrict__ gb,
                                              int* __restrict__ topi,
                                              float* __restrict__ topw,
                                              int* __restrict__ counts) {
  __shared__ float xs[16 * 520];
  __shared__ int hist[16];
  const int tid = threadIdx.x;
  const int tl = tid >> 4, e = tid & 15;
  if (tid < 16) hist[tid] = 0;
  const float gbe = gb[e];
  const float* wrow = gw + (size_t)e * DIM;
  for (int tile = 0; tile < 4; tile++) {
    const int t0 = blockIdx.x * 64 + tile * 16;
    __syncthreads();
    {
      const int r = tid >> 4, cbase = (tid & 15) * 32;
#pragma unroll
      for (int j = 0; j < 8; j++) {
        const int c = cbase + j * 4;
        const int ch = c >> 2;
        const int pc = ch ^ ((ch >> 3) & 7);
        *(f4*)&xs[r * 520 + pc * 4] = *(const f4*)&x[(size_t)(t0 + r) * DIM + c];
      }
    }
    __syncthreads();
    float d = gbe;
#pragma unroll 8
    for (int c = 0; c < DIM; c += 4) {
      const int ch = c >> 2;
      const int pc = ch ^ ((ch >> 3) & 7);
      f4 xv = *(const f4*)&xs[tl * 520 + pc * 4];
      f4 wv = *(const f4*)&wrow[c];
      d = fmaf(xv[0], wv[0], d); d = fmaf(xv[1], wv[1], d);
      d = fmaf(xv[2], wv[2], d); d = fmaf(xv[3], wv[3], d);
    }
    float v1 = d, v2 = -1e30f;
    int i1 = e, i2 = 1000;
#pragma unroll
    for (int s = 1; s < 16; s <<= 1) {
      const float ov1 = __shfl_xor(v1, s), ov2 = __shfl_xor(v2, s);
      const int oi1 = __shfl_xor(i1, s), oi2 = __shfl_xor(i2, s);
      if (ov1 > v1 || (ov1 == v1 && oi1 < i1)) {
        float nv2; int ni2;
        if (v1 > ov2 || (v1 == ov2 && i1 < oi2)) { nv2 = v1; ni2 = i1; }
        else { nv2 = ov2; ni2 = oi2; }
        v1 = ov1; i1 = oi1; v2 = nv2; i2 = ni2;
      } else if (ov1 > v2 || (ov1 == v2 && oi1 < i2)) {
        v2 = ov1; i2 = oi1;
      }
    }
    if (e == 0) {
      const int t = t0 + tl;
      const float e1 = __expf(v2 - v1);
      const float inv = 1.f / (1.f + e1);
      topi[2 * t] = i1;  topi[2 * t + 1] = i2;
      topw[2 * t] = inv; topw[2 * t + 1] = e1 * inv;
      atomicAdd(&hist[i1], 1);
      atomicAdd(&hist[i2], 1);
    }
  }
  __syncthreads();
  if (tid < 16 && hist[tid] > 0) atomicAdd(&counts[tid], hist[tid]);
}

__global__ void k_offsets(const int* __restrict__ counts,
                          int* __restrict__ off_pad, int* __restrict__ cursor) {
  if (threadIdx.x == 0) {
    int o = 0;
    off_pad[0] = 0;
    for (int e = 0; e < NE; e++) {
      cursor[e] = 0;
      o += ((counts[e] + BM - 1) / BM) * BM;
      off_pad[e + 1] = o;
    }
  }
}

// ---------------- scatter: batched slot claims ----------------
__global__ __launch_bounds__(256) void k_scatter(const float* __restrict__ x,
                                                 const int* __restrict__ topi,
                                                 const float* __restrict__ topw,
                                                 const int* __restrict__ off_pad,
                                                 int* __restrict__ cursor,
                                                 int* __restrict__ slotTok,
                                                 float* __restrict__ slotW,
                                                 unsigned short* __restrict__ Xg) {
  __shared__ int lcnt[16];
  __shared__ int gbase[16];
  __shared__ int posArr[128];
  const int tid = threadIdx.x;
  const int a0 = blockIdx.x * 128;
  if (tid < 16) lcnt[tid] = 0;
  __syncthreads();
  if (tid < 128) {
    const int a = a0 + tid;
    const int e = topi[a];
    const int lrank = atomicAdd(&lcnt[e], 1);
    posArr[tid] = (e << 24) | lrank;
  }
  __syncthreads();
  if (tid < 16) {
    const int c = lcnt[tid];
    gbase[tid] = (c > 0) ? atomicAdd(&cursor[tid], c) : 0;
  }
  __syncthreads();
  if (tid < 128) {
    const int a = a0 + tid;
    const int pk = posArr[tid];
    const int e = pk >> 24, lrank = pk & 0xffffff;
    const int pos = off_pad[e] + gbase[e] + lrank;
    posArr[tid] = pos;
    slotTok[pos] = a >> 1;
    slotW[pos] = topw[a];
  }
  __syncthreads();
  const int w = tid >> 6, lane = tid & 63;
#pragma unroll 4
  for (int i = 0; i < 32; i++) {
    const int idx = w * 32 + i;
    const int pos = posArr[idx];
    const int tok = (a0 + idx) >> 1;
    const size_t sb = (size_t)tok * DIM + lane * 8;
    f4 v0 = *(const f4*)&x[sb], v1 = *(const f4*)&x[sb + 4];
    u16x8 hh;
    hh[0] = f2bf(v0[0]); hh[1] = f2bf(v0[1]); hh[2] = f2bf(v0[2]); hh[3] = f2bf(v0[3]);
    hh[4] = f2bf(v1[0]); hh[5] = f2bf(v1[1]); hh[6] = f2bf(v1[2]); hh[7] = f2bf(v1[3]);
    *(u16x8*)&Xg[(size_t)pos * DIM + lane * 8] = hh;
  }
}

// ---------------- grouped bf16 MFMA GEMM (MoE), T2 swizzle + T1 XCD swizzle ----------------
__global__ __launch_bounds__(256) void k_gemm_bf16(
    const unsigned short* __restrict__ A, int lda,
    const unsigned short* __restrict__ Wb, size_t westride, int ldw, int wrow0,
    const float* __restrict__ bias, int bstride, int brow0,
    int K, int epi,
    unsigned short* __restrict__ Hout, int ldh,
    float* __restrict__ dout,
    const int* __restrict__ slotTok, const float* __restrict__ slotW,
    const int* __restrict__ off_pad) {
  int bx = blockIdx.x;
  const int nwg = gridDim.x;
  if ((nwg & 7) == 0) bx = (bx & 7) * (nwg >> 3) + (bx >> 3);
  const int m0 = bx * BM;
  if (m0 >= off_pad[NE]) return;
  int e = 0;
  while (off_pad[e + 1] <= m0) e++;
  const unsigned short* W = Wb + (size_t)e * westride;
  const int n0 = blockIdx.y * 128;
  __shared__ unsigned short Al[128 * 64];
  __shared__ unsigned short Bl[128 * 64];
  const int tid = threadIdx.x, lane = tid & 63, wid = tid >> 6;
  const int wm = wid >> 1, wn = wid & 1;
  f32x4 acc[4][4] = {};
  const int srow = wid * 32 + (lane >> 3);
  const int scol = (((lane & 7) ^ ((lane >> 3) & 7)) << 3);
  for (int k0 = 0; k0 < K; k0 += 64) {
    const unsigned short* ga = A + (size_t)(m0 + srow) * lda + k0 + scol;
    const unsigned short* gw = W + (size_t)(wrow0 + n0 + srow) * ldw + k0 + scol;
#pragma unroll
    for (int i = 0; i < 4; i++) {
      load_lds16(ga + (size_t)i * 8 * lda, &Al[(wid * 32 + i * 8) * 64]);
      load_lds16(gw + (size_t)i * 8 * ldw, &Bl[(wid * 32 + i * 8) * 64]);
    }
    __syncthreads();
#pragma unroll
    for (int kk = 0; kk < 2; kk++) {
      short8 av[4], bv[4];
      const int ckx = (kk * 4 + (lane >> 4)) ^ (lane & 7);
#pragma unroll
      for (int mi = 0; mi < 4; mi++)
        av[mi] = *(const short8*)&Al[(wm * 64 + mi * 16 + (lane & 15)) * 64 + ckx * 8];
#pragma unroll
      for (int ni = 0; ni < 4; ni++)
        bv[ni] = *(const short8*)&Bl[(wn * 64 + ni * 16 + (lane & 15)) * 64 + ckx * 8];
#pragma unroll
      for (int mi = 0; mi < 4; mi++) {
#pragma unroll
        for (int ni = 0; ni < 4; ni++)
          acc[mi][ni] = __builtin_amdgcn_mfma_f32_16x16x32_bf16(av[mi], bv[ni], acc[mi][ni], 0, 0, 0);
      }
    }
    __syncthreads();
  }
#pragma unroll
  for (int mi = 0; mi < 4; mi++) {
    const int rb = m0 + wm * 64 + mi * 16 + ((lane >> 4) << 2);
#pragma unroll
    for (int ni = 0; ni < 4; ni++) {
      const int n = n0 + wn * 64 + ni * 16 + (lane & 15);
      const float bn = bias ? bias[(size_t)e * bstride + brow0 + n] : 0.f;
      if (epi == 0) {
#pragma unroll
        for (int r = 0; r < 4; r++) {
          float v = acc[mi][ni][r] + bn;
          v = fmaxf(v, 0.f);
          Hout[(size_t)(rb + r) * ldh + n] = f2bf(v);
        }
      } else {
#pragma unroll
        for (int r = 0; r < 4; r++) {
          const int tok = slotTok[rb + r];
          if (tok >= 0) {
            const float v = (acc[mi][ni][r] + bn) * slotW[rb + r];
            atomicAdd(&dout[(size_t)tok * DIM + n], v);
          }
        }
      }
    }
  }
}

// ---------------- launch ----------------
extern "C" void kernel_launch(void* const* d_in, const int* in_sizes, int n_in,
                              void* d_out, int out_size, void* d_ws, size_t ws_size,
                              hipStream_t stream) {
  const float* src       = (const float*)d_in[0];
  const float* pos       = (const float*)d_in[1];
  const float* in_proj_w = (const float*)d_in[2];
  const float* in_proj_b = (const float*)d_in[3];
  const float* out_w     = (const float*)d_in[4];
  const float* out_b     = (const float*)d_in[5];
  const float* norm1_g   = (const float*)d_in[6];
  const float* norm1_b   = (const float*)d_in[7];
  const float* gate_w    = (const float*)d_in[8];
  const float* gate_b    = (const float*)d_in[9];
  const float* w1        = (const float*)d_in[10];
  const float* b1        = (const float*)d_in[11];
  const float* w2        = (const float*)d_in[12];
  const float* b2        = (const float*)d_in[13];
  float* out = (float*)d_out;
  char* wsb = (char*)d_ws;

  // ---- lifetime-packed arena (~166.5 MiB, unchanged footprint) ----
  unsigned* Qp = (unsigned*)(wsb + 0);          // [B,H,S,HD] packed
  unsigned* Kp = (unsigned*)(wsb + 33554432);   // [B,H,S,HD] packed
  unsigned* Vp = (unsigned*)(wsb + 67108864);   // [B,H,HD,S] packed
  float* ob = (float*)(wsb + 100663296);
  float* proj = (float*)(wsb + 0);
  unsigned short* w1b = (unsigned short*)(wsb + 0);
  unsigned short* w2b = (unsigned short*)(wsb + 33554432);
  unsigned short* Xg  = (unsigned short*)(wsb + 67108864);
  unsigned short* Hb  = (unsigned short*)(wsb + 102760448);
  unsigned short* wih = (unsigned short*)(wsb + 134217728);
  unsigned short* wil = (unsigned short*)(wsb + 135790592);
  char* smallb = wsb + 174063616;
  int*   topi    = (int*)  (smallb + 0);
  float* topw    = (float*)(smallb + 131072);
  int*   slotTok = (int*)  (smallb + 262144);
  float* slotW   = (float*)(smallb + 401408);
  int*   counts  = (int*)  (smallb + 540672);
  int*   off_pad = (int*)  (smallb + 540736);
  int*   cursor  = (int*)  (smallb + 540864);

  // 1. routing init + in_proj weight split
  k_init<<<(CAP + 255) / 256, 256, 0, stream>>>(slotTok, slotW, counts);
  k_split_w<<<768, 256, 0, stream>>>(in_proj_w, wih, wil, (size_t)1536 * 512);
  // 2. Q/K projection (split MFMA, fused src+pos) -> packed planes [B,H,S,HD]
  k_gemm_split<<<dim3(128, 8), 256, 0, stream>>>(src, pos, wih, wil, in_proj_b, 0, Qp, Kp);
  // 3. V projection -> packed plane [B,H,HD,S] (LDS-bounce transposed epilogue)
  k_gemm_split<<<dim3(128, 4), 256, 0, stream>>>(src, nullptr, wih + (size_t)1024 * 512,
                                                 wil + (size_t)1024 * 512, in_proj_b + 1024,
                                                 1, Vp, nullptr);
  // 4. split-MFMA flash attention -> ob [S,B,D]
  k_attn<<<dim3(16, 128), 256, 0, stream>>>(Qp, Kp, Vp, ob);
  // 5. w2 -> bf16 (K plane dead)
  k_cvt_bf16<<<2048, 256, 0, stream>>>(w2, w2b, (size_t)NE * DIM * DFF);
  // 6. output projection (fp32 vector — gate-critical) -> proj (over Qp)
  k_gemm_f32<<<dim3(128, 4), 256, 0, stream>>>(ob, out_w, out_b, 512, proj);
  // 7. layernorm(src + proj) -> d_out (= x)
  k_ln<<<4096, 256, 0, stream>>>(src, proj, norm1_g, norm1_b, out);
  // 8. w1 -> bf16 (proj dead)
  k_cvt_bf16<<<2048, 256, 0, stream>>>(w1, w1b, (size_t)NE * DFF * DIM);
  // 9. gate logits + top2 + counts
  k_gate<<<T_TOK / 64, 256, 0, stream>>>(out, gate_w, gate_b, topi, topw, counts);
  // 10. padded segment offsets
  k_offsets<<<1, 64, 0, stream>>>(counts, off_pad, cursor);
  // 11. zero only padding rows of Xg
  k_zero_pad<<<NE, 256, 0, stream>>>(counts, off_pad, Xg);
  // 12. scatter assignments + gather token rows as bf16
  k_scatter<<<256, 256, 0, stream>>>(out, topi, topw, off_pad, cursor, slotTok, slotW, Xg);
  // 13. MoE, DFF halved
  for (int p = 0; p < 2; ++p) {
    k_gemm_bf16<<<dim3(CAP / BM, 8), 256, 0, stream>>>(
        Xg, DIM, w1b, (size_t)DFF * DIM, DIM, p * 1024,
        b1, DFF, p * 1024, DIM, 0, Hb, 1024,
        nullptr, nullptr, nullptr, off_pad);
    k_gemm_bf16<<<dim3(CAP / BM, 4), 256, 0, stream>>>(
        Hb, 1024, w2b + (size_t)p * 1024, (size_t)DIM * DFF, DFF, 0,
        (p == 0 ? b2 : nullptr), DIM, 0, 1024, 1, nullptr, 0,
        out, slotTok, slotW, off_pad);
  }
}

// Round 11
// 886.831 us; speedup vs baseline: 2.8344x; 1.0858x over previous
//
#include <hip/hip_runtime.h>
#include <hip/hip_bf16.h>

// ---------------- types ----------------
typedef float f4 __attribute__((ext_vector_type(4)));
typedef float f32x4 __attribute__((ext_vector_type(4)));
typedef short short8 __attribute__((ext_vector_type(8)));
typedef unsigned short u16x4 __attribute__((ext_vector_type(4)));
typedef unsigned short u16x8 __attribute__((ext_vector_type(8)));
typedef unsigned int u32x4 __attribute__((ext_vector_type(4)));
typedef unsigned int u32x8 __attribute__((ext_vector_type(8)));

// ---------------- problem constants ----------------
#define S_LEN 1024
#define BATCH 16
#define DIM   512
#define NH    8
#define HDIM  64
#define NE    16
#define DFF   2048
#define T_TOK 16384   // S*B
#define CAP   34816   // 32768 assignments + per-expert padding to BM
#define BM    128

__device__ __forceinline__ unsigned short f2bf(float f) {
  union { float f; unsigned u; } v; v.f = f;
  unsigned r = v.u + 0x7fffu + ((v.u >> 16) & 1u);  // RTNE
  return (unsigned short)(r >> 16);
}
__device__ __forceinline__ float bf2f(unsigned short h) {
  union { unsigned u; float f; } v; v.u = ((unsigned)h) << 16;
  return v.f;
}

__device__ __forceinline__ void load_lds16(const void* g, void* l) {
  __builtin_amdgcn_global_load_lds(
      (__attribute__((address_space(1))) void*)(void*)g,
      (__attribute__((address_space(3))) void*)l, 16, 0, 0);
}

// extract hi/lo bf16 planes from 8 packed u32 (hi16|lo16)
__device__ __forceinline__ short8 pack_hi8(const unsigned* val) {
  union { unsigned u[4]; short8 s; } t;
#pragma unroll
  for (int i = 0; i < 4; i++)
    t.u[i] = (val[2 * i] >> 16) | (val[2 * i + 1] & 0xFFFF0000u);
  return t.s;
}
__device__ __forceinline__ short8 pack_lo8(const unsigned* val) {
  union { unsigned u[4]; short8 s; } t;
#pragma unroll
  for (int i = 0; i < 4; i++)
    t.u[i] = (val[2 * i] & 0xFFFFu) | (val[2 * i + 1] << 16);
  return t.s;
}

// ---------------- small utility kernels ----------------
__global__ __launch_bounds__(256) void k_cvt_bf16(const float* __restrict__ in,
                                                  unsigned short* __restrict__ outb,
                                                  size_t n) {
  size_t i = ((size_t)blockIdx.x * 256 + threadIdx.x) * 4;
  size_t stride = (size_t)gridDim.x * 1024;
  for (; i < n; i += stride) {
    f4 v = *(const f4*)&in[i];
    u16x4 o;
    o[0] = f2bf(v[0]); o[1] = f2bf(v[1]); o[2] = f2bf(v[2]); o[3] = f2bf(v[3]);
    *(u16x4*)&outb[i] = o;
  }
}

// split fp32 -> bf16 hi + bf16 lo (lo = round(x - hi))
__global__ __launch_bounds__(256) void k_split_w(const float* __restrict__ in,
                                                 unsigned short* __restrict__ hi,
                                                 unsigned short* __restrict__ lo,
                                                 size_t n) {
  size_t i = ((size_t)blockIdx.x * 256 + threadIdx.x) * 4;
  size_t stride = (size_t)gridDim.x * 1024;
  for (; i < n; i += stride) {
    f4 v = *(const f4*)&in[i];
    u16x4 h, l;
#pragma unroll
    for (int j = 0; j < 4; j++) {
      unsigned short hh = f2bf(v[j]);
      h[j] = hh;
      l[j] = f2bf(v[j] - bf2f(hh));
    }
    *(u16x4*)&hi[i] = h;
    *(u16x4*)&lo[i] = l;
  }
}

__global__ __launch_bounds__(256) void k_init(int* __restrict__ slotTok,
                                              float* __restrict__ slotW,
                                              int* __restrict__ counts) {
  int i = blockIdx.x * 256 + threadIdx.x;
  if (i < CAP) { slotTok[i] = -1; slotW[i] = 0.f; }
  if (i < NE) counts[i] = 0;
}

// zero only the padding rows of each expert segment
__global__ __launch_bounds__(256) void k_zero_pad(const int* __restrict__ counts,
                                                  const int* __restrict__ off_pad,
                                                  unsigned short* __restrict__ Xg) {
  const int e = blockIdx.x;
  const int start = off_pad[e] + counts[e];
  const int end = off_pad[e + 1];
  for (int row = start; row < end; row++)
    *(unsigned int*)&Xg[(size_t)row * DIM + threadIdx.x * 2] = 0u;
}

// ---------------- split-bf16 MFMA GEMM (fp32-accurate via hi/lo) ----------------
// C = (A [+A2])[M,512] * W[N,512]^T + bias.
// epi 0: n<512 -> Q*0.125 -> p0 [B,H,S,HD] packed; n>=512 -> K -> p1 packed
// epi 1: V -> p0 [B,H,HD,S] packed (LDS-bounce transposed)
// epi 2: plain fp32 row-major -> (float*)p0  (out-proj)
__global__ __launch_bounds__(256, 2) void k_gemm_split(
    const float* __restrict__ A, const float* __restrict__ A2,
    const unsigned short* __restrict__ Wh, const unsigned short* __restrict__ Wl,
    const float* __restrict__ bias, int epi,
    unsigned* __restrict__ p0, unsigned* __restrict__ p1) {
  __shared__ __align__(16) char smem[33792];   // staging 32 KB | bounce 128x66 u32
  unsigned short* AhL = (unsigned short*)smem;
  unsigned short* AlL = (unsigned short*)(smem + 8192);
  unsigned short* WhL = (unsigned short*)(smem + 16384);
  unsigned short* WlL = (unsigned short*)(smem + 24576);
  unsigned* bounce = (unsigned*)smem;
  const int tid = threadIdx.x, lane = tid & 63, wid = tid >> 6;
  const int wm = wid >> 1, wn = wid & 1;
  const int m0 = blockIdx.x * 128, n0 = blockIdx.y * 128;
  const int row = tid >> 1, half = tid & 1;
  const int xr = (row >> 1) & 3;
  f32x4 acc[4][4] = {};
  f4 ar[4];
#pragma unroll
  for (int j = 0; j < 4; j++) {
    const size_t aoff = (size_t)(m0 + row) * 512 + half * 16 + j * 4;
    ar[j] = *(const f4*)&A[aoff];
    if (A2) { f4 v2 = *(const f4*)&A2[aoff]; ar[j] += v2; }
  }
  for (int k0 = 0; k0 < 512; k0 += 32) {
    __syncthreads();
    u16x8 hi8[2], lo8[2];
#pragma unroll
    for (int j = 0; j < 16; j++) {
      const float x = ar[j >> 2][j & 3];
      const unsigned short h = f2bf(x);
      hi8[j >> 3][j & 7] = h;
      lo8[j >> 3][j & 7] = f2bf(x - bf2f(h));
    }
    const int c0 = half * 2;
    *(u16x8*)&AhL[row * 32 + (((c0 + 0) ^ xr) << 3)] = hi8[0];
    *(u16x8*)&AhL[row * 32 + (((c0 + 1) ^ xr) << 3)] = hi8[1];
    *(u16x8*)&AlL[row * 32 + (((c0 + 0) ^ xr) << 3)] = lo8[0];
    *(u16x8*)&AlL[row * 32 + (((c0 + 1) ^ xr) << 3)] = lo8[1];
#pragma unroll
    for (int i = 0; i < 2; i++) {
      const int rowW = i * 64 + wid * 16 + (lane >> 2);
      const int clog = (lane & 3) ^ ((rowW >> 1) & 3);
      const size_t woff = (size_t)(n0 + rowW) * 512 + k0 + (clog << 3);
      load_lds16(Wh + woff, &WhL[i * 2048 + wid * 512]);
      load_lds16(Wl + woff, &WlL[i * 2048 + wid * 512]);
    }
    __syncthreads();
    if (k0 + 32 < 512) {
#pragma unroll
      for (int j = 0; j < 4; j++) {
        const size_t aoff = (size_t)(m0 + row) * 512 + k0 + 32 + half * 16 + j * 4;
        ar[j] = *(const f4*)&A[aoff];
        if (A2) { f4 v2 = *(const f4*)&A2[aoff]; ar[j] += v2; }
      }
    }
    const int l15 = lane & 15, lk = lane >> 4;
    const int xa = (l15 >> 1) & 3;
    short8 avh[4], avl[4], bvh[4], bvl[4];
#pragma unroll
    for (int mi = 0; mi < 4; mi++) {
      const int mr = wm * 64 + mi * 16 + l15;
      avh[mi] = *(const short8*)&AhL[mr * 32 + ((lk ^ xa) << 3)];
      avl[mi] = *(const short8*)&AlL[mr * 32 + ((lk ^ xa) << 3)];
    }
#pragma unroll
    for (int ni = 0; ni < 4; ni++) {
      const int nr = wn * 64 + ni * 16 + l15;
      bvh[ni] = *(const short8*)&WhL[nr * 32 + ((lk ^ xa) << 3)];
      bvl[ni] = *(const short8*)&WlL[nr * 32 + ((lk ^ xa) << 3)];
    }
#pragma unroll
    for (int mi = 0; mi < 4; mi++) {
#pragma unroll
      for (int ni = 0; ni < 4; ni++) {
        acc[mi][ni] = __builtin_amdgcn_mfma_f32_16x16x32_bf16(avh[mi], bvh[ni], acc[mi][ni], 0, 0, 0);
        acc[mi][ni] = __builtin_amdgcn_mfma_f32_16x16x32_bf16(avh[mi], bvl[ni], acc[mi][ni], 0, 0, 0);
        acc[mi][ni] = __builtin_amdgcn_mfma_f32_16x16x32_bf16(avl[mi], bvh[ni], acc[mi][ni], 0, 0, 0);
      }
    }
  }
  const int l15 = lane & 15, lq = lane >> 4;
  if (epi == 2) {
    // plain fp32 row-major store (out-proj)
    float* of = (float*)p0;
#pragma unroll
    for (int mi = 0; mi < 4; mi++) {
      const int rb = m0 + wm * 64 + mi * 16 + (lq << 2);
#pragma unroll
      for (int ni = 0; ni < 4; ni++) {
        const int n = n0 + wn * 64 + ni * 16 + l15;
        const float bn = bias[n];
#pragma unroll
        for (int r = 0; r < 4; r++)
          of[(size_t)(rb + r) * 512 + n] = acc[mi][ni][r] + bn;
      }
    }
  } else if (epi == 0) {
    // direct packed store, coalesced along head-dim
#pragma unroll
    for (int mi = 0; mi < 4; mi++) {
      const int rb = m0 + wm * 64 + mi * 16 + (lq << 2);
#pragma unroll
      for (int ni = 0; ni < 4; ni++) {
        const int n = n0 + wn * 64 + ni * 16 + l15;
        const float bn = bias[n];
#pragma unroll
        for (int r = 0; r < 4; r++) {
          const int m = rb + r;
          const int bidx = m & 15, ss = m >> 4;   // token = s*B + b
          float v = acc[mi][ni][r] + bn;
          unsigned* pl;
          int nn;
          if (n < 512) { v *= 0.125f; pl = p0; nn = n; }
          else { pl = p1; nn = n - 512; }
          const size_t off = ((size_t)(bidx * NH + (nn >> 6)) * S_LEN + ss) * HDIM + (nn & 63);
          const unsigned short hh = f2bf(v);
          pl[off] = ((unsigned)hh << 16) | (unsigned)f2bf(v - bf2f(hh));
        }
      }
    }
  } else {
    // V: bounce through LDS, store [B,H,HD,S] with 8-consecutive-s 32B runs
    const int s_base = m0 >> 4;   // = blockIdx.x * 8
    for (int halfn = 0; halfn < 2; halfn++) {
      __syncthreads();
      if (wn == halfn) {
#pragma unroll
        for (int mi = 0; mi < 4; mi++) {
          const int mlb = wm * 64 + mi * 16 + (lq << 2);
#pragma unroll
          for (int ni = 0; ni < 4; ni++) {
            const int n = n0 + wn * 64 + ni * 16 + l15;
            const float bn = bias[n];
            const int nc = ni * 16 + l15;
#pragma unroll
            for (int r = 0; r < 4; r++) {
              const float v = acc[mi][ni][r] + bn;
              const unsigned short hh = f2bf(v);
              bounce[(mlb + r) * 66 + nc] =
                  ((unsigned)hh << 16) | (unsigned)f2bf(v - bf2f(hh));
            }
          }
        }
      }
      __syncthreads();
#pragma unroll
      for (int i = 0; i < 4; i++) {
        const int idx = tid + 256 * i;        // 0..1023
        const int nc = idx & 63, bb = idx >> 6;
        const int ng = n0 + halfn * 64 + nc;
        const int hh_ = ng >> 6, dd = ng & 63;
        u32x8 vals;
#pragma unroll
        for (int s = 0; s < 8; s++) vals[s] = bounce[(s * 16 + bb) * 66 + nc];
        *(u32x8*)&p0[((size_t)(bb * NH + hh_) * HDIM + dd) * S_LEN + s_base] = vals;
      }
    }
  }
}

// ---------------- split-bf16 MFMA flash attention ----------------
// Q,K packed u32 [B,H,S,HD]; V packed u32 [B,H,HD,S] (pre-transposed).
// Unpack ONCE at staging into hi/lo u16 LDS arrays; fragment reads = plain short8.
// Swapped QK^T -> in-register P. LDS = 36,864 B.
__global__ __launch_bounds__(256, 4) void k_attn(
    const unsigned* __restrict__ Qp, const unsigned* __restrict__ Kp,
    const unsigned* __restrict__ Vp, float* __restrict__ O) {
  const int q0 = blockIdx.x * 64;
  const int bh = blockIdx.y;
  const int b = bh >> 3, h = bh & 7;
  const size_t base = (size_t)bh * (S_LEN * HDIM);
  __shared__ unsigned short KhL[64][72], KlL[64][72];   // [key][d]
  __shared__ unsigned short VhL[64][72], VlL[64][72];   // [d][key]
  const int tid = threadIdx.x, lane = tid & 63, w = tid >> 6;
  const int l15 = lane & 15, lq = lane >> 4;
  const int srcA = l15 + 16 * ((2 * lq) & 3);
  const int srcB = l15 + 16 * ((2 * lq + 1) & 3);
  const bool selHi = (lane & 32) != 0;
  // Q fragments (unpack once)
  short8 qh[2], ql[2];
  {
    const size_t qoff = base + (size_t)(q0 + 16 * w + l15) * HDIM + lq * 8;
    u32x8 qv0 = *(const u32x8*)&Qp[qoff];
    u32x8 qv1 = *(const u32x8*)&Qp[qoff + 32];
    qh[0] = pack_hi8((const unsigned*)&qv0); ql[0] = pack_lo8((const unsigned*)&qv0);
    qh[1] = pack_hi8((const unsigned*)&qv1); ql[1] = pack_lo8((const unsigned*)&qv1);
  }
  // staging: thread -> row sr (K: key, V: d), col-quarter sq
  const int sr = tid >> 2, sq = (tid & 3) * 16;
  u32x4 kr[4], vr[4];
  {
    const size_t ko = base + (size_t)sr * HDIM + sq;       // K [key][d]
    const size_t vo = base + (size_t)sr * S_LEN + sq;      // V [d][key]
#pragma unroll
    for (int i = 0; i < 4; i++) {
      kr[i] = *(const u32x4*)&Kp[ko + 4 * i];
      vr[i] = *(const u32x4*)&Vp[vo + 4 * i];
    }
  }
  float m_ = -1e30f, l_ = 0.f;          // per-lane, q-row = q0+16w+l15
  f32x4 acc[4] = {};                    // acc[n][r]: q-rel=4lq+r, d=16n+l15

  for (int kt = 0; kt < 16; kt++) {
    // unpack staged regs -> hi/lo LDS (shared by all 4 waves)
    {
      const unsigned* ku = (const unsigned*)kr;
      const unsigned* vu = (const unsigned*)vr;
      *(short8*)&KhL[sr][sq + 0] = pack_hi8(ku);
      *(short8*)&KhL[sr][sq + 8] = pack_hi8(ku + 8);
      *(short8*)&KlL[sr][sq + 0] = pack_lo8(ku);
      *(short8*)&KlL[sr][sq + 8] = pack_lo8(ku + 8);
      *(short8*)&VhL[sr][sq + 0] = pack_hi8(vu);
      *(short8*)&VhL[sr][sq + 8] = pack_hi8(vu + 8);
      *(short8*)&VlL[sr][sq + 0] = pack_lo8(vu);
      *(short8*)&VlL[sr][sq + 8] = pack_lo8(vu + 8);
    }
    __syncthreads();
    if (kt < 15) {   // T14 prefetch (in flight across QK+softmax+PV)
      const int s0n = (kt + 1) * 64;
      const size_t ko = base + (size_t)(s0n + sr) * HDIM + sq;
      const size_t vo = base + (size_t)sr * S_LEN + s0n + sq;
#pragma unroll
      for (int i = 0; i < 4; i++) {
        kr[i] = *(const u32x4*)&Kp[ko + 4 * i];
        vr[i] = *(const u32x4*)&Vp[vo + 4 * i];
      }
    }
    // ---- QK^T (swapped): sc[n][r] = S[k=16n+4lq+r][q=l15] ----
    f32x4 sc[4] = {};
#pragma unroll
    for (int c = 0; c < 2; c++) {
      short8 kfh[4], kfl[4];
#pragma unroll
      for (int n = 0; n < 4; n++) {
        kfh[n] = *(const short8*)&KhL[16 * n + l15][c * 32 + lq * 8];
        kfl[n] = *(const short8*)&KlL[16 * n + l15][c * 32 + lq * 8];
      }
#pragma unroll
      for (int n = 0; n < 4; n++) {
        sc[n] = __builtin_amdgcn_mfma_f32_16x16x32_bf16(kfh[n], qh[c], sc[n], 0, 0, 0);
        sc[n] = __builtin_amdgcn_mfma_f32_16x16x32_bf16(kfl[n], qh[c], sc[n], 0, 0, 0);
        sc[n] = __builtin_amdgcn_mfma_f32_16x16x32_bf16(kfh[n], ql[c], sc[n], 0, 0, 0);
      }
    }
    // ---- online softmax, per-lane scalar state ----
    float tm = fmaxf(fmaxf(fmaxf(sc[0][0], sc[0][1]), fmaxf(sc[0][2], sc[0][3])),
                     fmaxf(fmaxf(sc[1][0], sc[1][1]), fmaxf(sc[1][2], sc[1][3])));
    tm = fmaxf(tm, fmaxf(fmaxf(fmaxf(sc[2][0], sc[2][1]), fmaxf(sc[2][2], sc[2][3])),
                         fmaxf(fmaxf(sc[3][0], sc[3][1]), fmaxf(sc[3][2], sc[3][3]))));
    tm = fmaxf(tm, __shfl_xor(tm, 16));
    tm = fmaxf(tm, __shfl_xor(tm, 32));
    const float mn = fmaxf(m_, tm);
    const float esc = __expf(m_ - mn);
    m_ = mn;
    float rs = 0.f;
    unsigned pk[4][4];
#pragma unroll
    for (int n = 0; n < 4; n++) {
#pragma unroll
      for (int r = 0; r < 4; r++) {
        const float p = __expf(sc[n][r] - mn);
        rs += p;
        const unsigned short hh = f2bf(p);
        pk[n][r] = ((unsigned)hh << 16) | (unsigned)f2bf(p - bf2f(hh));
      }
    }
    rs += __shfl_xor(rs, 16);
    rs += __shfl_xor(rs, 32);
    l_ = l_ * esc + rs;
    float escR[4];
#pragma unroll
    for (int r = 0; r < 4; r++) escR[r] = __shfl(esc, 4 * lq + r);
#pragma unroll
    for (int n = 0; n < 4; n++) {
#pragma unroll
      for (int r = 0; r < 4; r++) acc[n][r] *= escR[r];
    }
    // ---- PV: in-register P redistribution, 3-term MFMA ----
#pragma unroll
    for (int c = 0; c < 2; c++) {
      unsigned val[8];
#pragma unroll
      for (int j = 0; j < 8; j++) {
        const int src = (j >> 2) ? srcB : srcA;
        const unsigned sA = (unsigned)__shfl((int)pk[2 * c + 0][j & 3], src);
        const unsigned sB = (unsigned)__shfl((int)pk[2 * c + 1][j & 3], src);
        val[j] = selHi ? sB : sA;
      }
      const short8 ph = pack_hi8(val);
      const short8 plo = pack_lo8(val);
      short8 vfh[4], vfl[4];
#pragma unroll
      for (int n = 0; n < 4; n++) {
        vfh[n] = *(const short8*)&VhL[16 * n + l15][c * 32 + lq * 8];
        vfl[n] = *(const short8*)&VlL[16 * n + l15][c * 32 + lq * 8];
      }
#pragma unroll
      for (int n = 0; n < 4; n++) {
        acc[n] = __builtin_amdgcn_mfma_f32_16x16x32_bf16(ph, vfh[n], acc[n], 0, 0, 0);
        acc[n] = __builtin_amdgcn_mfma_f32_16x16x32_bf16(ph, vfl[n], acc[n], 0, 0, 0);
        acc[n] = __builtin_amdgcn_mfma_f32_16x16x32_bf16(plo, vfh[n], acc[n], 0, 0, 0);
      }
    }
    __syncthreads();
  }
  const float inv = 1.f / l_;
  float invR[4];
#pragma unroll
  for (int r = 0; r < 4; r++) invR[r] = __shfl(inv, 4 * lq + r);
#pragma unroll
  for (int r = 0; r < 4; r++) {
    const int srow = q0 + 16 * w + 4 * lq + r;
    float* orow = &O[((size_t)srow * BATCH + b) * DIM + h * HDIM];
#pragma unroll
    for (int n = 0; n < 4; n++) orow[16 * n + l15] = acc[n][r] * invR[r];
  }
}

// ---------------- layernorm: x = LN(src + proj)*g + b -> out ----------------
__global__ __launch_bounds__(256) void k_ln(const float* __restrict__ src,
                                            const float* __restrict__ proj,
                                            const float* __restrict__ g,
                                            const float* __restrict__ bt,
                                            float* __restrict__ xout) {
  const int wid = threadIdx.x >> 6, lane = threadIdx.x & 63;
  const int tok = blockIdx.x * 4 + wid;
  const size_t base = (size_t)tok * DIM + lane * 8;
  f4 a0 = *(const f4*)&src[base],  a1 = *(const f4*)&src[base + 4];
  f4 p0 = *(const f4*)&proj[base], p1 = *(const f4*)&proj[base + 4];
  float x[8];
  x[0] = a0[0] + p0[0]; x[1] = a0[1] + p0[1]; x[2] = a0[2] + p0[2]; x[3] = a0[3] + p0[3];
  x[4] = a1[0] + p1[0]; x[5] = a1[1] + p1[1]; x[6] = a1[2] + p1[2]; x[7] = a1[3] + p1[3];
  float s = 0.f, sq = 0.f;
#pragma unroll
  for (int j = 0; j < 8; j++) { s += x[j]; sq = fmaf(x[j], x[j], sq); }
#pragma unroll
  for (int d = 1; d < 64; d <<= 1) { s += __shfl_xor(s, d); sq += __shfl_xor(sq, d); }
  const float mean = s * (1.f / 512.f);
  const float var = sq * (1.f / 512.f) - mean * mean;
  const float rstd = 1.f / sqrtf(var + 1e-5f);
  const int ci = lane * 8;
  f4 o0v, o1v;
#pragma unroll
  for (int j = 0; j < 4; j++) o0v[j] = (x[j] - mean) * rstd * g[ci + j] + bt[ci + j];
#pragma unroll
  for (int j = 0; j < 4; j++) o1v[j] = (x[4 + j] - mean) * rstd * g[ci + 4 + j] + bt[ci + 4 + j];
  *(f4*)&xout[base] = o0v;
  *(f4*)&xout[base + 4] = o1v;
}

// ---------------- gate: block = 16 tokens x 16 experts, 4 tiles ----------------
__global__ __launch_bounds__(256) void k_gate(const float* __restrict__ x,
                                              const float* __restrict__ gw,
                                              const float* __restrict__ gb,
                                              int* __restrict__ topi,
                                              float* __restrict__ topw,
                                              int* __restrict__ counts) {
  __shared__ float xs[16 * 520];
  __shared__ int hist[16];
  const int tid = threadIdx.x;
  const int tl = tid >> 4, e = tid & 15;
  if (tid < 16) hist[tid] = 0;
  const float gbe = gb[e];
  const float* wrow = gw + (size_t)e * DIM;
  for (int tile = 0; tile < 4; tile++) {
    const int t0 = blockIdx.x * 64 + tile * 16;
    __syncthreads();
    {
      const int r = tid >> 4, cbase = (tid & 15) * 32;
#pragma unroll
      for (int j = 0; j < 8; j++) {
        const int c = cbase + j * 4;
        const int ch = c >> 2;
        const int pc = ch ^ ((ch >> 3) & 7);
        *(f4*)&xs[r * 520 + pc * 4] = *(const f4*)&x[(size_t)(t0 + r) * DIM + c];
      }
    }
    __syncthreads();
    float d = gbe;
#pragma unroll 8
    for (int c = 0; c < DIM; c += 4) {
      const int ch = c >> 2;
      const int pc = ch ^ ((ch >> 3) & 7);
      f4 xv = *(const f4*)&xs[tl * 520 + pc * 4];
      f4 wv = *(const f4*)&wrow[c];
      d = fmaf(xv[0], wv[0], d); d = fmaf(xv[1], wv[1], d);
      d = fmaf(xv[2], wv[2], d); d = fmaf(xv[3], wv[3], d);
    }
    float v1 = d, v2 = -1e30f;
    int i1 = e, i2 = 1000;
#pragma unroll
    for (int s = 1; s < 16; s <<= 1) {
      const float ov1 = __shfl_xor(v1, s), ov2 = __shfl_xor(v2, s);
      const int oi1 = __shfl_xor(i1, s), oi2 = __shfl_xor(i2, s);
      if (ov1 > v1 || (ov1 == v1 && oi1 < i1)) {
        float nv2; int ni2;
        if (v1 > ov2 || (v1 == ov2 && i1 < oi2)) { nv2 = v1; ni2 = i1; }
        else { nv2 = ov2; ni2 = oi2; }
        v1 = ov1; i1 = oi1; v2 = nv2; i2 = ni2;
      } else if (ov1 > v2 || (ov1 == v2 && oi1 < i2)) {
        v2 = ov1; i2 = oi1;
      }
    }
    if (e == 0) {
      const int t = t0 + tl;
      const float e1 = __expf(v2 - v1);
      const float inv = 1.f / (1.f + e1);
      topi[2 * t] = i1;  topi[2 * t + 1] = i2;
      topw[2 * t] = inv; topw[2 * t + 1] = e1 * inv;
      atomicAdd(&hist[i1], 1);
      atomicAdd(&hist[i2], 1);
    }
  }
  __syncthreads();
  if (tid < 16 && hist[tid] > 0) atomicAdd(&counts[tid], hist[tid]);
}

__global__ void k_offsets(const int* __restrict__ counts,
                          int* __restrict__ off_pad, int* __restrict__ cursor) {
  if (threadIdx.x == 0) {
    int o = 0;
    off_pad[0] = 0;
    for (int e = 0; e < NE; e++) {
      cursor[e] = 0;
      o += ((counts[e] + BM - 1) / BM) * BM;
      off_pad[e + 1] = o;
    }
  }
}

// ---------------- scatter: batched slot claims ----------------
__global__ __launch_bounds__(256) void k_scatter(const float* __restrict__ x,
                                                 const int* __restrict__ topi,
                                                 const float* __restrict__ topw,
                                                 const int* __restrict__ off_pad,
                                                 int* __restrict__ cursor,
                                                 int* __restrict__ slotTok,
                                                 float* __restrict__ slotW,
                                                 unsigned short* __restrict__ Xg) {
  __shared__ int lcnt[16];
  __shared__ int gbase[16];
  __shared__ int posArr[128];
  const int tid = threadIdx.x;
  const int a0 = blockIdx.x * 128;
  if (tid < 16) lcnt[tid] = 0;
  __syncthreads();
  if (tid < 128) {
    const int a = a0 + tid;
    const int e = topi[a];
    const int lrank = atomicAdd(&lcnt[e], 1);
    posArr[tid] = (e << 24) | lrank;
  }
  __syncthreads();
  if (tid < 16) {
    const int c = lcnt[tid];
    gbase[tid] = (c > 0) ? atomicAdd(&cursor[tid], c) : 0;
  }
  __syncthreads();
  if (tid < 128) {
    const int a = a0 + tid;
    const int pk = posArr[tid];
    const int e = pk >> 24, lrank = pk & 0xffffff;
    const int pos = off_pad[e] + gbase[e] + lrank;
    posArr[tid] = pos;
    slotTok[pos] = a >> 1;
    slotW[pos] = topw[a];
  }
  __syncthreads();
  const int w = tid >> 6, lane = tid & 63;
#pragma unroll 4
  for (int i = 0; i < 32; i++) {
    const int idx = w * 32 + i;
    const int pos = posArr[idx];
    const int tok = (a0 + idx) >> 1;
    const size_t sb = (size_t)tok * DIM + lane * 8;
    f4 v0 = *(const f4*)&x[sb], v1 = *(const f4*)&x[sb + 4];
    u16x8 hh;
    hh[0] = f2bf(v0[0]); hh[1] = f2bf(v0[1]); hh[2] = f2bf(v0[2]); hh[3] = f2bf(v0[3]);
    hh[4] = f2bf(v1[0]); hh[5] = f2bf(v1[1]); hh[6] = f2bf(v1[2]); hh[7] = f2bf(v1[3]);
    *(u16x8*)&Xg[(size_t)pos * DIM + lane * 8] = hh;
  }
}

// ---------------- grouped bf16 MFMA GEMM (MoE), T2 swizzle + T1 XCD swizzle ----------------
__global__ __launch_bounds__(256) void k_gemm_bf16(
    const unsigned short* __restrict__ A, int lda,
    const unsigned short* __restrict__ Wb, size_t westride, int ldw, int wrow0,
    const float* __restrict__ bias, int bstride, int brow0,
    int K, int epi,
    unsigned short* __restrict__ Hout, int ldh,
    float* __restrict__ dout,
    const int* __restrict__ slotTok, const float* __restrict__ slotW,
    const int* __restrict__ off_pad) {
  int bx = blockIdx.x;
  const int nwg = gridDim.x;
  if ((nwg & 7) == 0) bx = (bx & 7) * (nwg >> 3) + (bx >> 3);
  const int m0 = bx * BM;
  if (m0 >= off_pad[NE]) return;
  int e = 0;
  while (off_pad[e + 1] <= m0) e++;
  const unsigned short* W = Wb + (size_t)e * westride;
  const int n0 = blockIdx.y * 128;
  __shared__ unsigned short Al[128 * 64];
  __shared__ unsigned short Bl[128 * 64];
  const int tid = threadIdx.x, lane = tid & 63, wid = tid >> 6;
  const int wm = wid >> 1, wn = wid & 1;
  f32x4 acc[4][4] = {};
  const int srow = wid * 32 + (lane >> 3);
  const int scol = (((lane & 7) ^ ((lane >> 3) & 7)) << 3);
  for (int k0 = 0; k0 < K; k0 += 64) {
    const unsigned short* ga = A + (size_t)(m0 + srow) * lda + k0 + scol;
    const unsigned short* gw = W + (size_t)(wrow0 + n0 + srow) * ldw + k0 + scol;
#pragma unroll
    for (int i = 0; i < 4; i++) {
      load_lds16(ga + (size_t)i * 8 * lda, &Al[(wid * 32 + i * 8) * 64]);
      load_lds16(gw + (size_t)i * 8 * ldw, &Bl[(wid * 32 + i * 8) * 64]);
    }
    __syncthreads();
#pragma unroll
    for (int kk = 0; kk < 2; kk++) {
      short8 av[4], bv[4];
      const int ckx = (kk * 4 + (lane >> 4)) ^ (lane & 7);
#pragma unroll
      for (int mi = 0; mi < 4; mi++)
        av[mi] = *(const short8*)&Al[(wm * 64 + mi * 16 + (lane & 15)) * 64 + ckx * 8];
#pragma unroll
      for (int ni = 0; ni < 4; ni++)
        bv[ni] = *(const short8*)&Bl[(wn * 64 + ni * 16 + (lane & 15)) * 64 + ckx * 8];
#pragma unroll
      for (int mi = 0; mi < 4; mi++) {
#pragma unroll
        for (int ni = 0; ni < 4; ni++)
          acc[mi][ni] = __builtin_amdgcn_mfma_f32_16x16x32_bf16(av[mi], bv[ni], acc[mi][ni], 0, 0, 0);
      }
    }
    __syncthreads();
  }
#pragma unroll
  for (int mi = 0; mi < 4; mi++) {
    const int rb = m0 + wm * 64 + mi * 16 + ((lane >> 4) << 2);
#pragma unroll
    for (int ni = 0; ni < 4; ni++) {
      const int n = n0 + wn * 64 + ni * 16 + (lane & 15);
      const float bn = bias ? bias[(size_t)e * bstride + brow0 + n] : 0.f;
      if (epi == 0) {
#pragma unroll
        for (int r = 0; r < 4; r++) {
          float v = acc[mi][ni][r] + bn;
          v = fmaxf(v, 0.f);
          Hout[(size_t)(rb + r) * ldh + n] = f2bf(v);
        }
      } else {
#pragma unroll
        for (int r = 0; r < 4; r++) {
          const int tok = slotTok[rb + r];
          if (tok >= 0) {
            const float v = (acc[mi][ni][r] + bn) * slotW[rb + r];
            atomicAdd(&dout[(size_t)tok * DIM + n], v);
          }
        }
      }
    }
  }
}

// ---------------- launch ----------------
extern "C" void kernel_launch(void* const* d_in, const int* in_sizes, int n_in,
                              void* d_out, int out_size, void* d_ws, size_t ws_size,
                              hipStream_t stream) {
  const float* src       = (const float*)d_in[0];
  const float* pos       = (const float*)d_in[1];
  const float* in_proj_w = (const float*)d_in[2];
  const float* in_proj_b = (const float*)d_in[3];
  const float* out_w     = (const float*)d_in[4];
  const float* out_b     = (const float*)d_in[5];
  const float* norm1_g   = (const float*)d_in[6];
  const float* norm1_b   = (const float*)d_in[7];
  const float* gate_w    = (const float*)d_in[8];
  const float* gate_b    = (const float*)d_in[9];
  const float* w1        = (const float*)d_in[10];
  const float* b1        = (const float*)d_in[11];
  const float* w2        = (const float*)d_in[12];
  const float* b2        = (const float*)d_in[13];
  float* out = (float*)d_out;
  char* wsb = (char*)d_ws;

  // ---- lifetime-packed arena (~166.5 MiB, unchanged footprint) ----
  unsigned* Qp = (unsigned*)(wsb + 0);          // [B,H,S,HD] packed
  unsigned* Kp = (unsigned*)(wsb + 33554432);   // [B,H,S,HD] packed
  unsigned* Vp = (unsigned*)(wsb + 67108864);   // [B,H,HD,S] packed
  float* ob = (float*)(wsb + 100663296);
  float* proj = (float*)(wsb + 0);
  unsigned short* w1b = (unsigned short*)(wsb + 0);
  unsigned short* w2b = (unsigned short*)(wsb + 33554432);
  unsigned short* Xg  = (unsigned short*)(wsb + 67108864);
  unsigned short* Hb  = (unsigned short*)(wsb + 102760448);
  unsigned short* wih = (unsigned short*)(wsb + 134217728);  // 1.5 MiB
  unsigned short* wil = (unsigned short*)(wsb + 135790592);  // 1.5 MiB
  unsigned short* woh = (unsigned short*)(wsb + 137363456);  // 0.5 MiB (out_w hi)
  unsigned short* wol = (unsigned short*)(wsb + 137887744);  // 0.5 MiB (out_w lo)
  char* smallb = wsb + 174063616;
  int*   topi    = (int*)  (smallb + 0);
  float* topw    = (float*)(smallb + 131072);
  int*   slotTok = (int*)  (smallb + 262144);
  float* slotW   = (float*)(smallb + 401408);
  int*   counts  = (int*)  (smallb + 540672);
  int*   off_pad = (int*)  (smallb + 540736);
  int*   cursor  = (int*)  (smallb + 540864);

  // 1. routing init + weight splits
  k_init<<<(CAP + 255) / 256, 256, 0, stream>>>(slotTok, slotW, counts);
  k_split_w<<<768, 256, 0, stream>>>(in_proj_w, wih, wil, (size_t)1536 * 512);
  k_split_w<<<256, 256, 0, stream>>>(out_w, woh, wol, (size_t)512 * 512);
  // 2. Q/K projection (split MFMA, fused src+pos) -> packed planes [B,H,S,HD]
  k_gemm_split<<<dim3(128, 8), 256, 0, stream>>>(src, pos, wih, wil, in_proj_b, 0, Qp, Kp);
  // 3. V projection -> packed plane [B,H,HD,S] (LDS-bounce transposed epilogue)
  k_gemm_split<<<dim3(128, 4), 256, 0, stream>>>(src, nullptr, wih + (size_t)1024 * 512,
                                                 wil + (size_t)1024 * 512, in_proj_b + 1024,
                                                 1, Vp, nullptr);
  // 4. split-MFMA flash attention -> ob [S,B,D]
  k_attn<<<dim3(16, 128), 256, 0, stream>>>(Qp, Kp, Vp, ob);
  // 5. w2 -> bf16 (K plane dead)
  k_cvt_bf16<<<2048, 256, 0, stream>>>(w2, w2b, (size_t)NE * DIM * DFF);
  // 6. output projection (split MFMA, fp32-accurate) -> proj (over Qp)
  k_gemm_split<<<dim3(128, 4), 256, 0, stream>>>(ob, nullptr, woh, wol, out_b,
                                                 2, (unsigned*)proj, nullptr);
  // 7. layernorm(src + proj) -> d_out (= x)
  k_ln<<<4096, 256, 0, stream>>>(src, proj, norm1_g, norm1_b, out);
  // 8. w1 -> bf16 (proj dead)
  k_cvt_bf16<<<2048, 256, 0, stream>>>(w1, w1b, (size_t)NE * DFF * DIM);
  // 9. gate logits + top2 + counts
  k_gate<<<T_TOK / 64, 256, 0, stream>>>(out, gate_w, gate_b, topi, topw, counts);
  // 10. padded segment offsets
  k_offsets<<<1, 64, 0, stream>>>(counts, off_pad, cursor);
  // 11. zero only padding rows of Xg
  k_zero_pad<<<NE, 256, 0, stream>>>(counts, off_pad, Xg);
  // 12. scatter assignments + gather token rows as bf16
  k_scatter<<<256, 256, 0, stream>>>(out, topi, topw, off_pad, cursor, slotTok, slotW, Xg);
  // 13. MoE, DFF halved
  for (int p = 0; p < 2; ++p) {
    k_gemm_bf16<<<dim3(CAP / BM, 8), 256, 0, stream>>>(
        Xg, DIM, w1b, (size_t)DFF * DIM, DIM, p * 1024,
        b1, DFF, p * 1024, DIM, 0, Hb, 1024,
        nullptr, nullptr, nullptr, off_pad);
    k_gemm_bf16<<<dim3(CAP / BM, 4), 256, 0, stream>>>(
        Hb, 1024, w2b + (size_t)p * 1024, (size_t)DIM * DFF, DFF, 0,
        (p == 0 ? b2 : nullptr), DIM, 0, 1024, 1, nullptr, 0,
        out, slotTok, slotW, off_pad);
  }
}